// Round 1
// baseline (1702.774 us; speedup 1.0000x reference)
//
#include <hip/hip_runtime.h>
#include <math.h>

#define BB 2
#define NN 784
#define CC 384
#define DI 768
#define DS 64
#define DTR 24
#define ROWS (BB*NN)   // 1568

// ---------------- LayerNorm: one wave per row of 384 ----------------
__global__ void k_ln(const float* __restrict__ x, const float* __restrict__ w,
                     const float* __restrict__ b, float* __restrict__ out, int rows){
  int row = blockIdx.x;
  if (row >= rows) return;
  int lane = threadIdx.x; // blockDim = 64
  const float* xr = x + (size_t)row*CC;
  float v[6]; float s = 0.f;
#pragma unroll
  for (int i=0;i<6;i++){ v[i] = xr[lane + 64*i]; s += v[i]; }
#pragma unroll
  for (int o=32;o;o>>=1) s += __shfl_xor(s,o);
  float mu = s * (1.f/CC);
  float vs = 0.f;
#pragma unroll
  for (int i=0;i<6;i++){ float d=v[i]-mu; vs += d*d; }
#pragma unroll
  for (int o=32;o;o>>=1) vs += __shfl_xor(vs,o);
  float rstd = rsqrtf(vs*(1.f/CC) + 1e-5f);
  float* orow = out + (size_t)row*CC;
#pragma unroll
  for (int i=0;i<6;i++){ int c = lane+64*i; orow[c] = (v[i]-mu)*rstd*w[c] + b[c]; }
}

// ---------------- Generic fp32 GEMM: Y[M,N] = X[M,K] @ W[N,K]^T ----------------
// mode 0: plain; 1: softplus(Y + bias); 2: Y + res[M,N]
#define GBM 64
#define GBN 64
#define GBK 16
__global__ __launch_bounds__(256) void k_gemm(
    const float* __restrict__ X, int lda,
    const float* __restrict__ W,
    const float* __restrict__ bias,
    const float* __restrict__ res,
    float* __restrict__ Y,
    int M, int N, int K, int mode)
{
  __shared__ float As[GBK][GBM+1];
  __shared__ float Bs[GBK][GBN+1];
  int m0 = blockIdx.y*GBM, n0 = blockIdx.x*GBN;
  int tid = threadIdx.x;
  int ty = tid>>4, tx = tid&15;
  float acc[4][4] = {{0.f}};
  for (int k0=0;k0<K;k0+=GBK){
#pragma unroll
    for (int l=0;l<4;l++){
      int e = tid + 256*l;
      int m = e>>4, kk = e&15;
      int gm = m0+m, gk = k0+kk;
      As[kk][m] = (gm<M && gk<K) ? X[(size_t)gm*lda+gk] : 0.f;
      int gn = n0+m;
      Bs[kk][m] = (gn<N && gk<K) ? W[(size_t)gn*K+gk] : 0.f;
    }
    __syncthreads();
#pragma unroll
    for (int kk=0;kk<GBK;kk++){
      float a[4], bv[4];
#pragma unroll
      for (int i=0;i<4;i++) a[i] = As[kk][ty*4+i];
#pragma unroll
      for (int j=0;j<4;j++) bv[j] = Bs[kk][tx*4+j];
#pragma unroll
      for (int i=0;i<4;i++)
#pragma unroll
        for (int j=0;j<4;j++) acc[i][j] += a[i]*bv[j];
    }
    __syncthreads();
  }
#pragma unroll
  for (int i=0;i<4;i++){
    int gm = m0+ty*4+i; if (gm>=M) continue;
#pragma unroll
    for (int j=0;j<4;j++){
      int gn = n0+tx*4+j; if (gn>=N) continue;
      float v = acc[i][j];
      if (mode==1){ v += bias[gn]; v = (v>20.f)? v : log1pf(expf(v)); }
      else if (mode==2){ v += res[(size_t)gm*N+gn]; }
      Y[(size_t)gm*N+gn] = v;
    }
  }
}

// ---------------- causal depthwise conv1d + silu ----------------
__global__ void k_conv(const float* __restrict__ xz, const float* __restrict__ cw,
                       const float* __restrict__ cb, float* __restrict__ xc){
  int idx = blockIdx.x*256 + threadIdx.x;
  if (idx >= ROWS*DI) return;
  int d = idx % DI;
  int r = idx / DI;
  int b = r / NN, l = r % NN;
  float acc = cb[d];
#pragma unroll
  for (int t=0;t<4;t++){
    int ls = l-3+t;
    if (ls>=0) acc += cw[d*4+t] * xz[((size_t)(b*NN+ls))*1536 + d];
  }
  xc[(size_t)r*DI + d] = acc / (1.f + expf(-acc)); // silu
}

// ---------------- selective scan: one wave per (b,d), lane = state s ----------------
__global__ __launch_bounds__(256) void k_scan(
    const float* __restrict__ dbl, const float* __restrict__ dtb,
    const float* __restrict__ xc, const float* __restrict__ xz,
    const float* __restrict__ A_log, const float* __restrict__ Dp,
    float* __restrict__ y)
{
  int wid = (blockIdx.x*256 + threadIdx.x) >> 6;
  int lane = threadIdx.x & 63;
  if (wid >= BB*DI) return;
  int b = wid / DI, d = wid % DI;
  float A = -expf(A_log[d*DS + lane]);
  float Dv = Dp[d];
  float h = 0.f;
  const float* dbr = dbl + (size_t)b*NN*152;
  const float* dtr = dtb + (size_t)b*NN*DI + d;
  const float* ur  = xc  + (size_t)b*NN*DI + d;
  const float* zr  = xz  + (size_t)b*NN*1536 + DI + d;
  float* yr = y + (size_t)b*NN*DI + d;
  for (int t=0;t<NN;t++){
    const float* row = dbr + (size_t)t*152;
    float Bv = row[DTR + lane];
    float Cv = row[DTR + DS + lane];
    float dt = dtr[(size_t)t*DI];
    float u  = ur[(size_t)t*DI];
    h = h*__expf(dt*A) + (dt*u)*Bv;
    float p = h*Cv;
#pragma unroll
    for (int o=32;o;o>>=1) p += __shfl_xor(p,o);
    if (lane==0){
      float z = zr[(size_t)t*1536];
      yr[(size_t)t*DI] = (p + u*Dv) * (z/(1.f+__expf(-z)));
    }
  }
}

// ---------------- length-4 forward DFT along nb (real input) ----------------
__global__ void k_fft4(const float* __restrict__ x, float* __restrict__ tre, float* __restrict__ tim){
  int idx = blockIdx.x*256+threadIdx.x;
  if (idx >= ROWS*96) return;
  int k = idx % 96, r = idx / 96;
  const float* xr = x + (size_t)r*CC;
  float a0=xr[k], a1=xr[96+k], a2=xr[192+k], a3=xr[288+k];
  float* tr = tre + (size_t)r*CC;
  float* ti = tim + (size_t)r*CC;
  tr[k]     = a0+a1+a2+a3; ti[k]     = 0.f;
  tr[96+k]  = a0-a2;       ti[96+k]  = a3-a1;
  tr[192+k] = a0-a1+a2-a3; ti[192+k] = 0.f;
  tr[288+k] = a0-a2;       ti[288+k] = a1-a3;
}

// ---------------- DFT-784 twiddle table: W[f,n] = e^{-2pi i f n / 784} ----------------
__global__ void k_twiddle(float* __restrict__ wre, float* __restrict__ wim){
  int idx = blockIdx.x*256+threadIdx.x;
  if (idx >= NN*NN) return;
  int f = idx / NN, n = idx % NN;
  int m = (f*n) % NN;
  float ang = -6.283185307179586f * (float)m / (float)NN;
  float s, c;
  sincosf(ang, &s, &c);
  wre[idx] = c; wim[idx] = s;
}

// ---------------- generic complex GEMM: O = alpha*(L @ R) [+bias][act] ----------------
// L: [M,K] complex (ldL), imag scaled by imSign (for conj). R: [K,N] complex (ldR).
// per-blockIdx.z element offsets Lzs/Rzs/Ozs/bzs. mode 0: none; 1: relu; 2: softshrink(0.01)
__global__ __launch_bounds__(256) void k_cgemm(
    const float* __restrict__ Lre, const float* __restrict__ Lim, int ldL, long long Lzs, float imSign,
    const float* __restrict__ Rre, const float* __restrict__ Rim, int ldR, long long Rzs,
    const float* __restrict__ bre, const float* __restrict__ bim, long long bzs,
    float* __restrict__ Ore, float* __restrict__ Oim, int ldO, long long Ozs,
    int M, int N, int K, float alpha, int mode)
{
  __shared__ float Asr[GBK][GBM+1], Asi[GBK][GBM+1];
  __shared__ float Bsr[GBK][GBN+1], Bsi[GBK][GBN+1];
  long long z = blockIdx.z;
  Lre += z*Lzs; Lim += z*Lzs;
  Rre += z*Rzs; Rim += z*Rzs;
  Ore += z*Ozs; Oim += z*Ozs;
  if (bre){ bre += z*bzs; bim += z*bzs; }
  int m0 = blockIdx.y*GBM, n0 = blockIdx.x*GBN;
  int tid = threadIdx.x;
  int ty = tid>>4, tx = tid&15;
  float accr[4][4]={{0.f}}, acci[4][4]={{0.f}};
  for (int k0=0;k0<K;k0+=GBK){
#pragma unroll
    for (int l=0;l<4;l++){
      int e = tid + 256*l;
      { int m=e>>4, kk=e&15; int gm=m0+m, gk=k0+kk;
        bool ok = (gm<M) && (gk<K);
        Asr[kk][m] = ok ? Lre[(size_t)gm*ldL+gk] : 0.f;
        Asi[kk][m] = ok ? imSign*Lim[(size_t)gm*ldL+gk] : 0.f; }
      { int kk=e>>6, n=e&63; int gk=k0+kk, gn=n0+n;
        bool ok = (gk<K) && (gn<N);
        Bsr[kk][n] = ok ? Rre[(size_t)gk*ldR+gn] : 0.f;
        Bsi[kk][n] = ok ? Rim[(size_t)gk*ldR+gn] : 0.f; }
    }
    __syncthreads();
#pragma unroll
    for (int kk=0;kk<GBK;kk++){
      float ar[4],ai[4],br[4],bi[4];
#pragma unroll
      for (int i=0;i<4;i++){ ar[i]=Asr[kk][ty*4+i]; ai[i]=Asi[kk][ty*4+i]; }
#pragma unroll
      for (int j=0;j<4;j++){ br[j]=Bsr[kk][tx*4+j]; bi[j]=Bsi[kk][tx*4+j]; }
#pragma unroll
      for (int i=0;i<4;i++)
#pragma unroll
        for (int j=0;j<4;j++){
          accr[i][j] += ar[i]*br[j] - ai[i]*bi[j];
          acci[i][j] += ar[i]*bi[j] + ai[i]*br[j];
        }
    }
    __syncthreads();
  }
#pragma unroll
  for (int i=0;i<4;i++){
    int gm=m0+ty*4+i; if (gm>=M) continue;
#pragma unroll
    for (int j=0;j<4;j++){
      int gn=n0+tx*4+j; if (gn>=N) continue;
      float vr = accr[i][j]*alpha, vi = acci[i][j]*alpha;
      if (bre){ vr += bre[gn]; vi += bim[gn]; }
      if (mode==1){ vr=fmaxf(vr,0.f); vi=fmaxf(vi,0.f); }
      else if (mode==2){
        vr = copysignf(fmaxf(fabsf(vr)-0.01f,0.f), vr);
        vi = copysignf(fmaxf(fabsf(vi)-0.01f,0.f), vi);
      }
      Ore[(size_t)gm*ldO+gn]=vr; Oim[(size_t)gm*ldO+gn]=vi;
    }
  }
}

// ---------------- inverse length-4 DFT (real part) + final residual ----------------
__global__ void k_ifft4_real(const float* __restrict__ fre, const float* __restrict__ fim,
                             const float* __restrict__ x1, float* __restrict__ out){
  int idx = blockIdx.x*256+threadIdx.x;
  if (idx >= ROWS*96) return;
  int k = idx % 96, r = idx / 96;
  const float* fr = fre + (size_t)r*CC;
  const float* fi = fim + (size_t)r*CC;
  float r0=fr[k], r1=fr[96+k], r2=fr[192+k], r3=fr[288+k];
  float i1=fi[96+k], i3=fi[288+k];
  const float* xr = x1 + (size_t)r*CC;
  float* o = out + (size_t)r*CC;
  o[k]     = xr[k]     + (r0 + r1 + r2 + r3);
  o[96+k]  = xr[96+k]  + (r0 - i1 - r2 + i3);
  o[192+k] = xr[192+k] + (r0 - r1 + r2 - r3);
  o[288+k] = xr[288+k] + (r0 + i1 - r2 - i3);
}

extern "C" void kernel_launch(void* const* d_in, const int* in_sizes, int n_in,
                              void* d_out, int out_size, void* d_ws, size_t ws_size,
                              hipStream_t stream){
  const float* x         = (const float*)d_in[0];
  const float* ln1_w     = (const float*)d_in[3];
  const float* ln1_b     = (const float*)d_in[4];
  const float* in_proj_w = (const float*)d_in[5];
  const float* conv_w    = (const float*)d_in[6];
  const float* conv_b    = (const float*)d_in[7];
  const float* x_proj_w  = (const float*)d_in[8];
  const float* dt_proj_w = (const float*)d_in[9];
  const float* dt_proj_b = (const float*)d_in[10];
  const float* A_log     = (const float*)d_in[11];
  const float* Dp        = (const float*)d_in[12];
  const float* out_proj_w= (const float*)d_in[13];
  const float* ln2_w     = (const float*)d_in[14];
  const float* ln2_b     = (const float*)d_in[15];
  const float* cw1       = (const float*)d_in[16];
  const float* cb1       = (const float*)d_in[17];
  const float* cw2       = (const float*)d_in[18];
  const float* cb2       = (const float*)d_in[19];

  float* ws = (float*)d_ws;
  // mamba-phase buffers
  float* ln   = ws;                 // 602112 (ln1, then ln2)
  float* xz   = ln + 602112;        // 2408448
  float* xc   = xz + 2408448;       // 1204224
  float* dbl  = xc + 1204224;       // 238336
  float* dtb  = dbl + 238336;       // 1204224
  float* yb   = dtb + 1204224;      // 1204224  (ends at 6861568)
  float* x1   = yb + 1204224;       // 602112   (6861568..7463680)
  // FFT-phase buffers overlap dead xz/xc/dtb region [602112..5657344)
  float* tre  = xz;                 // 602112
  float* tim  = tre + 602112;
  float* fre  = tim + 602112;
  float* fim  = fre + 602112;
  float* r1b  = fim + 602112;
  float* i1b  = r1b + 602112;       // ends 4214784 (< dbl start? dbl=4214784, ok: exclusive)
  float* wre  = x1 + 602112;        // 7463680, 614656
  float* wim  = wre + 614656;       // ends 8692992 floats = ~34.8 MB

  // twiddle table (independent of everything else)
  k_twiddle<<<(NN*NN+255)/256,256,0,stream>>>(wre,wim);
  // ln1
  k_ln<<<ROWS,64,0,stream>>>(x, ln1_w, ln1_b, ln, ROWS);
  // in_proj: [1568,384] @ [1536,384]^T
  k_gemm<<<dim3(1536/64,(ROWS+63)/64),256,0,stream>>>(ln,384,in_proj_w,nullptr,nullptr,xz,ROWS,1536,384,0);
  // depthwise causal conv + silu
  k_conv<<<(ROWS*DI+255)/256,256,0,stream>>>(xz,conv_w,conv_b,xc);
  // x_proj: [1568,768] @ [152,768]^T
  k_gemm<<<dim3((152+63)/64,(ROWS+63)/64),256,0,stream>>>(xc,768,x_proj_w,nullptr,nullptr,dbl,ROWS,152,768,0);
  // dt_proj: [1568,24] @ [768,24]^T + bias, softplus
  k_gemm<<<dim3(768/64,(ROWS+63)/64),256,0,stream>>>(dbl,152,dt_proj_w,dt_proj_b,nullptr,dtb,ROWS,768,24,1);
  // selective scan + gating
  k_scan<<<(BB*DI)/4,256,0,stream>>>(dbl,dtb,xc,xz,A_log,Dp,yb);
  // out_proj + residual with x
  k_gemm<<<dim3(384/64,(ROWS+63)/64),256,0,stream>>>(yb,768,out_proj_w,nullptr,x,x1,ROWS,384,768,2);
  // ln2
  k_ln<<<ROWS,64,0,stream>>>(x1, ln2_w, ln2_b, ln, ROWS);
  // forward DFT-4 along nb
  k_fft4<<<(ROWS*96+255)/256,256,0,stream>>>(ln,tre,tim);
  // forward DFT-784 along N (per batch), ortho alpha 1/56
  k_cgemm<<<dim3(384/64,(NN+63)/64,2),256,0,stream>>>(
      wre,wim,NN,0,1.f,
      tre,tim,384,301056,
      nullptr,nullptr,0,
      fre,fim,384,301056,
      NN,384,NN, 1.f/56.f, 0);
  // EinFFT layer 1 (complex block matmul + bias + relu), z = block j
  k_cgemm<<<dim3((96+63)/64,(ROWS+63)/64,4),256,0,stream>>>(
      fre,fim,384,96,1.f,
      cw1,cw1+4*9216,96,9216,
      cb1,cb1+384,96,
      r1b,i1b,384,96,
      ROWS,96,96, 1.f, 1);
  // EinFFT layer 2 (+ bias + soft shrink)
  k_cgemm<<<dim3((96+63)/64,(ROWS+63)/64,4),256,0,stream>>>(
      r1b,i1b,384,96,1.f,
      cw2,cw2+4*9216,96,9216,
      cb2,cb2+384,96,
      tre,tim,384,96,
      ROWS,96,96, 1.f, 2);
  // inverse DFT-784 (conjugate table via imSign=-1), ortho alpha 1/56
  k_cgemm<<<dim3(384/64,(NN+63)/64,2),256,0,stream>>>(
      wre,wim,NN,0,-1.f,
      tre,tim,384,301056,
      nullptr,nullptr,0,
      fre,fim,384,301056,
      NN,384,NN, 1.f/56.f, 0);
  // inverse DFT-4 (real part) + final residual
  k_ifft4_real<<<(ROWS*96+255)/256,256,0,stream>>>(fre,fim,x1,(float*)d_out);
}

// Round 2
// 912.385 us; speedup vs baseline: 1.8663x; 1.8663x over previous
//
#include <hip/hip_runtime.h>
#include <math.h>

#define BB 2
#define NN 784
#define CC 384
#define DI 768
#define DS 64
#define DTR 24
#define ROWS (BB*NN)   // 1568
#define NC 8
#define LC 98          // NC*LC == NN

// ---------------- LayerNorm: one wave per row of 384 ----------------
__global__ void k_ln(const float* __restrict__ x, const float* __restrict__ w,
                     const float* __restrict__ b, float* __restrict__ out, int rows){
  int row = blockIdx.x;
  if (row >= rows) return;
  int lane = threadIdx.x; // blockDim = 64
  const float* xr = x + (size_t)row*CC;
  float v[6]; float s = 0.f;
#pragma unroll
  for (int i=0;i<6;i++){ v[i] = xr[lane + 64*i]; s += v[i]; }
#pragma unroll
  for (int o=32;o;o>>=1) s += __shfl_xor(s,o);
  float mu = s * (1.f/CC);
  float vs = 0.f;
#pragma unroll
  for (int i=0;i<6;i++){ float d=v[i]-mu; vs += d*d; }
#pragma unroll
  for (int o=32;o;o>>=1) vs += __shfl_xor(vs,o);
  float rstd = rsqrtf(vs*(1.f/CC) + 1e-5f);
  float* orow = out + (size_t)row*CC;
#pragma unroll
  for (int i=0;i<6;i++){ int c = lane+64*i; orow[c] = (v[i]-mu)*rstd*w[c] + b[c]; }
}

// ---------------- Generic fp32 GEMM: Y[M,N] = X[M,K] @ W[N,K]^T ----------------
// mode 0: plain; 1: softplus(Y + bias); 2: Y + res[M,N]
#define GBM 64
#define GBN 64
#define GBK 16
__global__ __launch_bounds__(256) void k_gemm(
    const float* __restrict__ X, int lda,
    const float* __restrict__ W,
    const float* __restrict__ bias,
    const float* __restrict__ res,
    float* __restrict__ Y,
    int M, int N, int K, int mode)
{
  __shared__ float As[GBK][GBM+4];
  __shared__ float Bs[GBK][GBN+4];
  int m0 = blockIdx.y*GBM, n0 = blockIdx.x*GBN;
  int tid = threadIdx.x;
  int ty = tid>>4, tx = tid&15;
  float acc[4][4] = {{0.f}};
  for (int k0=0;k0<K;k0+=GBK){
#pragma unroll
    for (int l=0;l<4;l++){
      int e = tid + 256*l;
      int m = e>>4, kk = e&15;
      int gm = m0+m, gk = k0+kk;
      As[kk][m] = (gm<M && gk<K) ? X[(size_t)gm*lda+gk] : 0.f;
      int gn = n0+m;
      Bs[kk][m] = (gn<N && gk<K) ? W[(size_t)gn*K+gk] : 0.f;
    }
    __syncthreads();
#pragma unroll
    for (int kk=0;kk<GBK;kk++){
      float4 av = *(const float4*)&As[kk][ty*4];
      float4 bv = *(const float4*)&Bs[kk][tx*4];
      float a[4]={av.x,av.y,av.z,av.w}, b[4]={bv.x,bv.y,bv.z,bv.w};
#pragma unroll
      for (int i=0;i<4;i++)
#pragma unroll
        for (int j=0;j<4;j++) acc[i][j] += a[i]*b[j];
    }
    __syncthreads();
  }
#pragma unroll
  for (int i=0;i<4;i++){
    int gm = m0+ty*4+i; if (gm>=M) continue;
#pragma unroll
    for (int j=0;j<4;j++){
      int gn = n0+tx*4+j; if (gn>=N) continue;
      float v = acc[i][j];
      if (mode==1){ v += bias[gn]; v = (v>20.f)? v : log1pf(expf(v)); }
      else if (mode==2){ v += res[(size_t)gm*N+gn]; }
      Y[(size_t)gm*N+gn] = v;
    }
  }
}

// ---------------- Y[M,N] = alpha * A[M,K] @ Bm[K,N] (+res), per-z strides ----------------
__global__ __launch_bounds__(256) void k_gemm_nt(
    const float* __restrict__ A, int lda,
    const float* __restrict__ Bm, long long Bzs,
    const float* __restrict__ res, long long rzs,
    float* __restrict__ Y, long long Yzs,
    int M, int N, int K, float alpha)
{
  __shared__ float As[GBK][GBM+4];
  __shared__ float Bs[GBK][GBN+4];
  long long z = blockIdx.z;
  Bm += z*Bzs; Y += z*Yzs; if (res) res += z*rzs;
  int m0 = blockIdx.y*GBM, n0 = blockIdx.x*GBN;
  int tid = threadIdx.x;
  int ty = tid>>4, tx = tid&15;
  float acc[4][4] = {{0.f}};
  for (int k0=0;k0<K;k0+=GBK){
#pragma unroll
    for (int l=0;l<4;l++){
      int e = tid + 256*l;
      { int m=e>>4, kk=e&15; int gm=m0+m, gk=k0+kk;
        As[kk][m] = (gm<M && gk<K) ? A[(size_t)gm*lda+gk] : 0.f; }
      { int kk=e>>6, n=e&63; int gk=k0+kk, gn=n0+n;
        Bs[kk][n] = (gk<K && gn<N) ? Bm[(size_t)gk*N+gn] : 0.f; }
    }
    __syncthreads();
#pragma unroll
    for (int kk=0;kk<GBK;kk++){
      float4 av = *(const float4*)&As[kk][ty*4];
      float4 bv = *(const float4*)&Bs[kk][tx*4];
      float a[4]={av.x,av.y,av.z,av.w}, b[4]={bv.x,bv.y,bv.z,bv.w};
#pragma unroll
      for (int i=0;i<4;i++)
#pragma unroll
        for (int j=0;j<4;j++) acc[i][j] += a[i]*b[j];
    }
    __syncthreads();
  }
#pragma unroll
  for (int i=0;i<4;i++){
    int gm = m0+ty*4+i; if (gm>=M) continue;
#pragma unroll
    for (int j=0;j<4;j++){
      int gn = n0+tx*4+j; if (gn>=N) continue;
      float v = acc[i][j]*alpha;
      if (res) v += res[(size_t)gm*N+gn];
      Y[(size_t)gm*N+gn] = v;
    }
  }
}

// ---------------- causal depthwise conv1d + silu ----------------
__global__ void k_conv(const float* __restrict__ xz, const float* __restrict__ cw,
                       const float* __restrict__ cb, float* __restrict__ xc){
  int idx = blockIdx.x*256 + threadIdx.x;
  if (idx >= ROWS*DI) return;
  int d = idx % DI;
  int r = idx / DI;
  int b = r / NN, l = r % NN;
  float acc = cb[d];
#pragma unroll
  for (int t=0;t<4;t++){
    int ls = l-3+t;
    if (ls>=0) acc += cw[d*4+t] * xz[((size_t)(b*NN+ls))*1536 + d];
  }
  xc[(size_t)r*DI + d] = acc / (1.f + expf(-acc)); // silu
}

// ---------------- chunked scan pass 1: per-chunk partial state + sum(dt) ----------------
__global__ __launch_bounds__(256) void k_scan1(
    const float* __restrict__ dbl, const float* __restrict__ dtb,
    const float* __restrict__ xc, const float* __restrict__ A_log,
    float* __restrict__ hpart, float* __restrict__ sdt)
{
  int wid = (blockIdx.x*256 + threadIdx.x) >> 6;
  int lane = threadIdx.x & 63;
  if (wid >= BB*DI*NC) return;
  int c = wid % NC; int bd = wid / NC;
  int d = bd % DI, b = bd / DI;
  float A = -__expf(A_log[d*DS + lane]);
  int t0 = c*LC;
  const float* dbr = dbl + ((size_t)(b*NN+t0))*152 + DTR;
  const float* dtp = dtb + ((size_t)(b*NN+t0))*DI + d;
  const float* up  = xc  + ((size_t)(b*NN+t0))*DI + d;
  float dt0v = dtp[(size_t)lane*DI];
  float dt1v = (lane+64<LC) ? dtp[(size_t)(lane+64)*DI] : 0.f;
  float u0v  = up[(size_t)lane*DI];
  float u1v  = (lane+64<LC) ? up[(size_t)(lane+64)*DI] : 0.f;
  float h = 0.f, s = 0.f;
  for (int t=0;t<LC;t++){
    float Bv = dbr[(size_t)t*152 + lane];
    float dt = (t<64) ? __shfl(dt0v, t) : __shfl(dt1v, t-64);
    float u  = (t<64) ? __shfl(u0v, t)  : __shfl(u1v, t-64);
    s += dt;
    h = h*__expf(dt*A) + (dt*u)*Bv;
  }
  hpart[((size_t)bd*NC + c)*DS + lane] = h;
  if (lane==0) sdt[bd*NC + c] = s;
}

// ---------------- chunked scan pass 2: chunk-prefix (in place: hpart -> hin) ----------------
__global__ __launch_bounds__(256) void k_scan2(
    const float* __restrict__ sdt, const float* __restrict__ A_log,
    float* __restrict__ hpart)
{
  int wid = (blockIdx.x*256 + threadIdx.x) >> 6;
  int lane = threadIdx.x & 63;
  if (wid >= BB*DI) return;
  int d = wid % DI;
  float A = -__expf(A_log[d*DS + lane]);
  float* hp = hpart + (size_t)wid*NC*DS + lane;
  const float* sp = sdt + wid*NC;
  float h = 0.f;
  for (int c=0;c<NC;c++){
    float part = hp[(size_t)c*DS];
    float pA = __expf(A*sp[c]);
    hp[(size_t)c*DS] = h;   // hin for chunk c
    h = h*pA + part;
  }
}

// ---------------- chunked scan pass 3: recompute with hin, emit gated y ----------------
__global__ __launch_bounds__(256) void k_scan3(
    const float* __restrict__ dbl, const float* __restrict__ dtb,
    const float* __restrict__ xc, const float* __restrict__ xz,
    const float* __restrict__ A_log, const float* __restrict__ Dp,
    const float* __restrict__ hin, float* __restrict__ y)
{
  int wid = (blockIdx.x*256 + threadIdx.x) >> 6;
  int lane = threadIdx.x & 63;
  if (wid >= BB*DI*NC) return;
  int c = wid % NC; int bd = wid / NC;
  int d = bd % DI, b = bd / DI;
  float A = -__expf(A_log[d*DS + lane]);
  float Dv = Dp[d];
  int t0 = c*LC;
  const float* dbr = dbl + ((size_t)(b*NN+t0))*152 + DTR;
  const float* dtp = dtb + ((size_t)(b*NN+t0))*DI + d;
  const float* up  = xc  + ((size_t)(b*NN+t0))*DI + d;
  const float* zp  = xz  + ((size_t)(b*NN+t0))*1536 + DI + d;
  float* yp = y + ((size_t)(b*NN+t0))*DI + d;
  float dt0v = dtp[(size_t)lane*DI];
  float dt1v = (lane+64<LC) ? dtp[(size_t)(lane+64)*DI] : 0.f;
  float u0v  = up[(size_t)lane*DI];
  float u1v  = (lane+64<LC) ? up[(size_t)(lane+64)*DI] : 0.f;
  float z0v  = zp[(size_t)lane*1536];
  float z1v  = (lane+64<LC) ? zp[(size_t)(lane+64)*1536] : 0.f;
  float h = hin[((size_t)bd*NC + c)*DS + lane];
  float y0v = 0.f, y1v = 0.f;
  for (int t=0;t<LC;t++){
    float Bv = dbr[(size_t)t*152 + lane];
    float Cv = dbr[(size_t)t*152 + 64 + lane];
    float dt = (t<64) ? __shfl(dt0v, t) : __shfl(dt1v, t-64);
    float u  = (t<64) ? __shfl(u0v, t)  : __shfl(u1v, t-64);
    h = h*__expf(dt*A) + (dt*u)*Bv;
    float p = h*Cv;
#pragma unroll
    for (int o=32;o;o>>=1) p += __shfl_xor(p,o);
    float res = p + u*Dv;
    if (t<64){ if (lane==t) y0v = res; }
    else     { if (lane==t-64) y1v = res; }
  }
  {
    float z = z0v;
    yp[(size_t)lane*DI] = y0v * (z/(1.f+__expf(-z)));
  }
  if (lane+64 < LC){
    float z = z1v;
    yp[(size_t)(lane+64)*DI] = y1v * (z/(1.f+__expf(-z)));
  }
}

// ---------------- twiddle tables ----------------
// Wcat [1568,784]: f<784 -> cos(2pi f n/784); f>=784 -> -sin(2pi (f-784) n/784)
__global__ void k_twA(float* __restrict__ Wcat){
  int idx = blockIdx.x*256+threadIdx.x;
  if (idx >= 1568*784) return;
  int f = idx / 784, n = idx % 784;
  int ff = (f<784)? f : f-784;
  int m = (int)(((long long)ff*(long long)n) % 784);
  float ang = 6.283185307179586f * (float)m / 784.f;
  float s, cval; sincosf(ang, &s, &cval);
  Wcat[idx] = (f<784)? cval : -s;
}
// WT [784,1568]: k<784 -> cos(2pi n k/784); k>=784 -> -sin(2pi n (k-784)/784)
__global__ void k_twB(float* __restrict__ WT){
  int idx = blockIdx.x*256+threadIdx.x;
  if (idx >= 784*1568) return;
  int n = idx / 1568, k = idx % 1568;
  int kk = (k<784)? k : k-784;
  int m = (int)(((long long)n*(long long)kk) % 784);
  float ang = 6.283185307179586f * (float)m / 784.f;
  float s, cval; sincosf(ang, &s, &cval);
  WT[idx] = (k<784)? cval : -s;
}

// ---------------- forward length-4 DFT along nb (complex) ----------------
// Ybuf per batch: [1568,384], rows 0-783 = re, 784-1567 = im
__global__ void k_cfft4(const float* __restrict__ Ybuf, float* __restrict__ tre, float* __restrict__ tim){
  int idx = blockIdx.x*256+threadIdx.x;
  if (idx >= BB*NN*96) return;
  int k = idx % 96; int r = idx / 96;   // r = b*784+f
  int b = r / NN, f = r % NN;
  const float* fre = Ybuf + (size_t)b*602112 + (size_t)f*384;
  const float* fim = fre + 301056;
  float r0=fre[k], r1=fre[96+k], r2=fre[192+k], r3=fre[288+k];
  float i0=fim[k], i1=fim[96+k], i2=fim[192+k], i3=fim[288+k];
  float* tr = tre + (size_t)r*384; float* ti = tim + (size_t)r*384;
  tr[k]     = r0+r1+r2+r3;     ti[k]     = i0+i1+i2+i3;
  tr[96+k]  = r0+i1-r2-i3;     ti[96+k]  = i0-r1-i2+r3;
  tr[192+k] = r0-r1+r2-r3;     ti[192+k] = i0-i1+i2-i3;
  tr[288+k] = r0-i1-r2+i3;     ti[288+k] = i0+r1-i2-r3;
}

// ---------------- inverse length-4 DFT along nb (complex, unnormalized) ----------------
__global__ void k_cifft4(const float* __restrict__ tre, const float* __restrict__ tim, float* __restrict__ Ybuf){
  int idx = blockIdx.x*256+threadIdx.x;
  if (idx >= BB*NN*96) return;
  int k = idx % 96; int r = idx / 96;
  int b = r / NN, f = r % NN;
  const float* tr = tre + (size_t)r*384; const float* ti = tim + (size_t)r*384;
  float R0=tr[k], R1=tr[96+k], R2=tr[192+k], R3=tr[288+k];
  float I0=ti[k], I1=ti[96+k], I2=ti[192+k], I3=ti[288+k];
  float* gre = Ybuf + (size_t)b*602112 + (size_t)f*384;
  float* gim = gre + 301056;
  gre[k]     = R0+R1+R2+R3;    gim[k]     = I0+I1+I2+I3;
  gre[96+k]  = R0-I1-R2+I3;    gim[96+k]  = I0+R1-I2-R3;
  gre[192+k] = R0-R1+R2-R3;    gim[192+k] = I0-I1+I2-I3;
  gre[288+k] = R0+I1-R2-I3;    gim[288+k] = I0-R1-I2+R3;
}

// ---------------- complex block GEMM (EinFFT layers) ----------------
// mode 1: relu(.+bias); mode 2: softshrink(.+bias, 0.01)
__global__ __launch_bounds__(256) void k_cgemm(
    const float* __restrict__ Lre, const float* __restrict__ Lim, int ldL, long long Lzs,
    const float* __restrict__ Rre, const float* __restrict__ Rim, int ldR, long long Rzs,
    const float* __restrict__ bre, const float* __restrict__ bim, long long bzs,
    float* __restrict__ Ore, float* __restrict__ Oim, int ldO, long long Ozs,
    int M, int N, int K, int mode)
{
  __shared__ float Asr[GBK][GBM+4], Asi[GBK][GBM+4];
  __shared__ float Bsr[GBK][GBN+4], Bsi[GBK][GBN+4];
  long long z = blockIdx.z;
  Lre += z*Lzs; Lim += z*Lzs;
  Rre += z*Rzs; Rim += z*Rzs;
  Ore += z*Ozs; Oim += z*Ozs;
  bre += z*bzs; bim += z*bzs;
  int m0 = blockIdx.y*GBM, n0 = blockIdx.x*GBN;
  int tid = threadIdx.x;
  int ty = tid>>4, tx = tid&15;
  float accr[4][4]={{0.f}}, acci[4][4]={{0.f}};
  for (int k0=0;k0<K;k0+=GBK){
#pragma unroll
    for (int l=0;l<4;l++){
      int e = tid + 256*l;
      { int m=e>>4, kk=e&15; int gm=m0+m, gk=k0+kk;
        bool ok = (gm<M) && (gk<K);
        Asr[kk][m] = ok ? Lre[(size_t)gm*ldL+gk] : 0.f;
        Asi[kk][m] = ok ? Lim[(size_t)gm*ldL+gk] : 0.f; }
      { int kk=e>>6, n=e&63; int gk=k0+kk, gn=n0+n;
        bool ok = (gk<K) && (gn<N);
        Bsr[kk][n] = ok ? Rre[(size_t)gk*ldR+gn] : 0.f;
        Bsi[kk][n] = ok ? Rim[(size_t)gk*ldR+gn] : 0.f; }
    }
    __syncthreads();
#pragma unroll
    for (int kk=0;kk<GBK;kk++){
      float4 arv = *(const float4*)&Asr[kk][ty*4];
      float4 aiv = *(const float4*)&Asi[kk][ty*4];
      float4 brv = *(const float4*)&Bsr[kk][tx*4];
      float4 biv = *(const float4*)&Bsi[kk][tx*4];
      float ar[4]={arv.x,arv.y,arv.z,arv.w}, ai[4]={aiv.x,aiv.y,aiv.z,aiv.w};
      float br[4]={brv.x,brv.y,brv.z,brv.w}, bi[4]={biv.x,biv.y,biv.z,biv.w};
#pragma unroll
      for (int i=0;i<4;i++)
#pragma unroll
        for (int j=0;j<4;j++){
          accr[i][j] += ar[i]*br[j] - ai[i]*bi[j];
          acci[i][j] += ar[i]*bi[j] + ai[i]*br[j];
        }
    }
    __syncthreads();
  }
#pragma unroll
  for (int i=0;i<4;i++){
    int gm=m0+ty*4+i; if (gm>=M) continue;
#pragma unroll
    for (int j=0;j<4;j++){
      int gn=n0+tx*4+j; if (gn>=N) continue;
      float vr = accr[i][j] + bre[gn];
      float vi = acci[i][j] + bim[gn];
      if (mode==1){ vr=fmaxf(vr,0.f); vi=fmaxf(vi,0.f); }
      else {
        vr = copysignf(fmaxf(fabsf(vr)-0.01f,0.f), vr);
        vi = copysignf(fmaxf(fabsf(vi)-0.01f,0.f), vi);
      }
      Ore[(size_t)gm*ldO+gn]=vr; Oim[(size_t)gm*ldO+gn]=vi;
    }
  }
}

extern "C" void kernel_launch(void* const* d_in, const int* in_sizes, int n_in,
                              void* d_out, int out_size, void* d_ws, size_t ws_size,
                              hipStream_t stream){
  const float* x         = (const float*)d_in[0];
  const float* ln1_w     = (const float*)d_in[3];
  const float* ln1_b     = (const float*)d_in[4];
  const float* in_proj_w = (const float*)d_in[5];
  const float* conv_w    = (const float*)d_in[6];
  const float* conv_b    = (const float*)d_in[7];
  const float* x_proj_w  = (const float*)d_in[8];
  const float* dt_proj_w = (const float*)d_in[9];
  const float* dt_proj_b = (const float*)d_in[10];
  const float* A_log     = (const float*)d_in[11];
  const float* Dp        = (const float*)d_in[12];
  const float* out_proj_w= (const float*)d_in[13];
  const float* ln2_w     = (const float*)d_in[14];
  const float* ln2_b     = (const float*)d_in[15];
  const float* cw1       = (const float*)d_in[16];
  const float* cb1       = (const float*)d_in[17];
  const float* cw2       = (const float*)d_in[18];
  const float* cb2       = (const float*)d_in[19];

  float* ws = (float*)d_ws;
  // ---- phase A (mamba) layout ----
  float* ln   = ws;                  // [0, 602112)
  float* xz   = ws + 602112;         // [602112, 3010560)
  float* xc   = ws + 3010560;        // [3010560, 4214784)
  float* dbl  = ws + 4214784;        // [4214784, 4453120)
  float* dtb  = ws + 4453120;        // [4453120, 5657344)
  float* yb   = ws + 5657344;        // [5657344, 6861568)
  float* x1   = ws + 6861568;        // [6861568, 7463680)
  float* hpart= ws + 7463680;        // [7463680, 8250112)  2*768*8*64
  float* sdt  = ws + 8250112;        // [8250112, 8262400)
  // ---- phase B (einfft) aliases into dead phase-A region [602112, 6861568) ----
  float* Wcat = ws + 602112;         // 1229312 floats [602112, 1831424)
  float* WT   = ws + 1831424;        // 1229312 floats [1831424, 3060736)
  float* Ybuf = ws + 3060736;        // 1204224 floats [3060736, 4264960)
  float* tre  = ws + 4264960;        // 602112 [4264960, 4867072)
  float* tim  = ws + 4867072;        // 602112 [4867072, 5469184)
  float* r1b  = ws + 5469184;        // 602112 [5469184, 6071296)
  float* i1b  = ws + 6071296;        // 602112 [6071296, 6673408)

  // ---- mamba path ----
  k_ln<<<ROWS,64,0,stream>>>(x, ln1_w, ln1_b, ln, ROWS);
  k_gemm<<<dim3(24,25),256,0,stream>>>(ln,384,in_proj_w,nullptr,nullptr,xz,ROWS,1536,384,0);
  k_conv<<<(ROWS*DI+255)/256,256,0,stream>>>(xz,conv_w,conv_b,xc);
  k_gemm<<<dim3(3,25),256,0,stream>>>(xc,768,x_proj_w,nullptr,nullptr,dbl,ROWS,152,768,0);
  k_gemm<<<dim3(12,25),256,0,stream>>>(dbl,152,dt_proj_w,dt_proj_b,nullptr,dtb,ROWS,768,24,1);
  k_scan1<<<(BB*DI*NC)/4,256,0,stream>>>(dbl,dtb,xc,A_log,hpart,sdt);
  k_scan2<<<(BB*DI)/4,256,0,stream>>>(sdt,A_log,hpart);
  k_scan3<<<(BB*DI*NC)/4,256,0,stream>>>(dbl,dtb,xc,xz,A_log,Dp,hpart,yb);
  k_gemm<<<dim3(6,25),256,0,stream>>>(yb,768,out_proj_w,nullptr,x,x1,ROWS,384,768,2);

  // ---- einfft path ----
  k_twA<<<(1568*784+255)/256,256,0,stream>>>(Wcat);
  k_twB<<<(784*1568+255)/256,256,0,stream>>>(WT);
  k_ln<<<ROWS,64,0,stream>>>(x1, ln2_w, ln2_b, ln, ROWS);
  // forward DFT-784 on real input: [Yre;Yim] = Wcat @ ln_b, alpha = 1/56
  k_gemm_nt<<<dim3(6,25,2),256,0,stream>>>(
      Wcat,784, ln,301056, nullptr,0, Ybuf,602112, 1568,384,784, 1.f/56.f);
  // forward DFT-4 along nb (complex butterflies)
  k_cfft4<<<(BB*NN*96+255)/256,256,0,stream>>>(Ybuf,tre,tim);
  // EinFFT layer 1 (relu)
  k_cgemm<<<dim3(2,25,4),256,0,stream>>>(
      tre,tim,384,96, cw1,cw1+4*9216,96,9216, cb1,cb1+384,96,
      r1b,i1b,384,96, ROWS,96,96, 1);
  // EinFFT layer 2 (soft shrink)
  k_cgemm<<<dim3(2,25,4),256,0,stream>>>(
      r1b,i1b,384,96, cw2,cw2+4*9216,96,9216, cb2,cb2+384,96,
      tre,tim,384,96, ROWS,96,96, 2);
  // inverse DFT-4 along nb
  k_cifft4<<<(BB*NN*96+255)/256,256,0,stream>>>(tre,tim,Ybuf);
  // inverse DFT-784, real part only + residual: out = x1 + (1/56) WT @ [Zre;Zim]
  k_gemm_nt<<<dim3(6,13,2),256,0,stream>>>(
      WT,1568, Ybuf,602112, x1,301056, (float*)d_out,301056, 784,384,1568, 1.f/56.f);
}

// Round 4
// 408.601 us; speedup vs baseline: 4.1673x; 2.2330x over previous
//
#include <hip/hip_runtime.h>
#include <math.h>

#define BB 2
#define NN 784
#define CC 384
#define DI 768
#define DS 64
#define DTR 24
#define ROWS (BB*NN)   // 1568
#define NC 8
#define LC 98          // NC*LC == NN

typedef __attribute__((ext_vector_type(8))) short bf16x8;
typedef __attribute__((ext_vector_type(4))) float f32x4;

static __device__ inline short f2bf(float f){
  unsigned u = __float_as_uint(f);
  unsigned r = (u + 0x7fffu + ((u>>16)&1u)) >> 16;
  return (short)r;
}

// ---------------- LayerNorm: one wave per row of 384 ----------------
__global__ void k_ln(const float* __restrict__ x, const float* __restrict__ w,
                     const float* __restrict__ b, float* __restrict__ out, int rows){
  int row = blockIdx.x;
  if (row >= rows) return;
  int lane = threadIdx.x; // blockDim = 64
  const float* xr = x + (size_t)row*CC;
  float v[6]; float s = 0.f;
#pragma unroll
  for (int i=0;i<6;i++){ v[i] = xr[lane + 64*i]; s += v[i]; }
#pragma unroll
  for (int o=32;o;o>>=1) s += __shfl_xor(s,o);
  float mu = s * (1.f/CC);
  float vs = 0.f;
#pragma unroll
  for (int i=0;i<6;i++){ float d=v[i]-mu; vs += d*d; }
#pragma unroll
  for (int o=32;o;o>>=1) vs += __shfl_xor(vs,o);
  float rstd = rsqrtf(vs*(1.f/CC) + 1e-5f);
  float* orow = out + (size_t)row*CC;
#pragma unroll
  for (int i=0;i<6;i++){ int c = lane+64*i; orow[c] = (v[i]-mu)*rstd*w[c] + b[c]; }
}

// ---------------- LayerNorm with transposed output: lnT[b][c][n] ----------------
__global__ void k_lnT(const float* __restrict__ x, const float* __restrict__ w,
                      const float* __restrict__ b, float* __restrict__ out){
  int row = blockIdx.x;      // b*784 + n
  if (row >= ROWS) return;
  int bb = row / NN, n = row % NN;
  int lane = threadIdx.x;
  const float* xr = x + (size_t)row*CC;
  float v[6]; float s = 0.f;
#pragma unroll
  for (int i=0;i<6;i++){ v[i] = xr[lane + 64*i]; s += v[i]; }
#pragma unroll
  for (int o=32;o;o>>=1) s += __shfl_xor(s,o);
  float mu = s * (1.f/CC);
  float vs = 0.f;
#pragma unroll
  for (int i=0;i<6;i++){ float d=v[i]-mu; vs += d*d; }
#pragma unroll
  for (int o=32;o;o>>=1) vs += __shfl_xor(vs,o);
  float rstd = rsqrtf(vs*(1.f/CC) + 1e-5f);
  float* ob = out + (size_t)bb*301056 + n;
#pragma unroll
  for (int i=0;i<6;i++){ int c = lane+64*i; ob[(size_t)c*NN] = (v[i]-mu)*rstd*w[c] + b[c]; }
}

// ---------------- bf16 MFMA GEMM: Y = alpha*(A[M,K] @ Bw[N,K]^T) + epi ----------------
// EPI 0: alpha*acc ; 1: alpha*acc + aux[row*ldaux+col] ; 2: relu(acc+aux[col]) ; 3: shrink(acc+aux[col],0.01)
template<int EPI>
__global__ __launch_bounds__(256) void k_mgemm(
    const float* __restrict__ A, int lda, long long Azs,
    const float* __restrict__ Bw, int ldb, long long Bzs,
    const float* __restrict__ aux, int ldaux, long long auxzs,
    float* __restrict__ Y, int ldo, long long Ozs,
    int M, int N, int K, float alpha)
{
  __shared__ __align__(16) short As[64*32];
  __shared__ __align__(16) short Bs[64*32];
  int z = blockIdx.z;
  A  += (size_t)z*Azs; Bw += (size_t)z*Bzs; Y += (size_t)z*Ozs;
  if (EPI != 0) aux += (size_t)z*auxzs;
  int m0 = blockIdx.y*64, n0 = blockIdx.x*64;
  int t = threadIdx.x;
  int srow = t>>2, skg = t&3;                 // staging: row 0..63, k-group 0..3 (8 elems)
  int w = t>>6, lane = t&63;
  int wr = (w>>1)*32, wc = (w&1)*32;
  int l15 = lane&15, lh = lane>>4;
  f32x4 acc[2][2] = {};
  int sslot = skg ^ ((srow>>1)&3);
  for (int k0=0; k0<K; k0+=32){
    // ---- stage A ----
    {
      int gm = m0 + srow, gk = k0 + skg*8;
      float4 v0 = {0,0,0,0}, v1 = {0,0,0,0};
      if (gm < M && gk < K){
        const float* p = A + (size_t)gm*lda + gk;
        v0 = *(const float4*)p; v1 = *(const float4*)(p+4);
      }
      union { short s[8]; bf16x8 v; } pk;
      pk.s[0]=f2bf(v0.x); pk.s[1]=f2bf(v0.y); pk.s[2]=f2bf(v0.z); pk.s[3]=f2bf(v0.w);
      pk.s[4]=f2bf(v1.x); pk.s[5]=f2bf(v1.y); pk.s[6]=f2bf(v1.z); pk.s[7]=f2bf(v1.w);
      *(bf16x8*)(As + srow*32 + sslot*8) = pk.v;
    }
    // ---- stage B (W-form [N][K]) ----
    {
      int gn = n0 + srow, gk = k0 + skg*8;
      float4 v0 = {0,0,0,0}, v1 = {0,0,0,0};
      if (gn < N && gk < K){
        const float* p = Bw + (size_t)gn*ldb + gk;
        v0 = *(const float4*)p; v1 = *(const float4*)(p+4);
      }
      union { short s[8]; bf16x8 v; } pk;
      pk.s[0]=f2bf(v0.x); pk.s[1]=f2bf(v0.y); pk.s[2]=f2bf(v0.z); pk.s[3]=f2bf(v0.w);
      pk.s[4]=f2bf(v1.x); pk.s[5]=f2bf(v1.y); pk.s[6]=f2bf(v1.z); pk.s[7]=f2bf(v1.w);
      *(bf16x8*)(Bs + srow*32 + sslot*8) = pk.v;
    }
    __syncthreads();
    bf16x8 af[2], bfr[2];
#pragma unroll
    for (int mi=0; mi<2; mi++){
      int row = wr + mi*16 + l15;
      af[mi] = *(const bf16x8*)(As + row*32 + ((lh ^ ((row>>1)&3))<<3));
    }
#pragma unroll
    for (int ni=0; ni<2; ni++){
      int col = wc + ni*16 + l15;
      bfr[ni] = *(const bf16x8*)(Bs + col*32 + ((lh ^ ((col>>1)&3))<<3));
    }
#pragma unroll
    for (int mi=0; mi<2; mi++)
#pragma unroll
      for (int ni=0; ni<2; ni++)
        acc[mi][ni] = __builtin_amdgcn_mfma_f32_16x16x32_bf16(af[mi], bfr[ni], acc[mi][ni], 0, 0, 0);
    __syncthreads();
  }
  // ---- epilogue ----
#pragma unroll
  for (int mi=0; mi<2; mi++){
#pragma unroll
    for (int ni=0; ni<2; ni++){
      int col = n0 + wc + ni*16 + l15;
      if (col >= N) continue;
#pragma unroll
      for (int j=0; j<4; j++){
        int row = m0 + wr + mi*16 + lh*4 + j;
        if (row >= M) continue;
        float v = acc[mi][ni][j];
        if (EPI == 0){ v *= alpha; }
        else if (EPI == 1){ v = v*alpha + aux[(size_t)row*ldaux + col]; }
        else if (EPI == 2){ v += aux[col]; v = fmaxf(v, 0.f); }
        else { v += aux[col]; v = copysignf(fmaxf(fabsf(v)-0.01f, 0.f), v); }
        Y[(size_t)row*ldo + col] = v;
      }
    }
  }
}

// ---------------- fp32 GEMM (dt_proj only): Y = softplus(X@W^T + bias) ----------------
#define GBM 64
#define GBN 64
#define GBK 16
__global__ __launch_bounds__(256) void k_gemm(
    const float* __restrict__ X, int lda,
    const float* __restrict__ W,
    const float* __restrict__ bias,
    float* __restrict__ Y,
    int M, int N, int K)
{
  __shared__ float As[GBK][GBM+4];
  __shared__ float Bs[GBK][GBN+4];
  int m0 = blockIdx.y*GBM, n0 = blockIdx.x*GBN;
  int tid = threadIdx.x;
  int ty = tid>>4, tx = tid&15;
  float acc[4][4] = {{0.f}};
  for (int k0=0;k0<K;k0+=GBK){
#pragma unroll
    for (int l=0;l<4;l++){
      int e = tid + 256*l;
      int m = e>>4, kk = e&15;
      int gm = m0+m, gk = k0+kk;
      As[kk][m] = (gm<M && gk<K) ? X[(size_t)gm*lda+gk] : 0.f;
      int gn = n0+m;
      Bs[kk][m] = (gn<N && gk<K) ? W[(size_t)gn*K+gk] : 0.f;
    }
    __syncthreads();
#pragma unroll
    for (int kk=0;kk<GBK;kk++){
      float4 av = *(const float4*)&As[kk][ty*4];
      float4 bv = *(const float4*)&Bs[kk][tx*4];
      float a[4]={av.x,av.y,av.z,av.w}, b[4]={bv.x,bv.y,bv.z,bv.w};
#pragma unroll
      for (int i=0;i<4;i++)
#pragma unroll
        for (int j=0;j<4;j++) acc[i][j] += a[i]*b[j];
    }
    __syncthreads();
  }
#pragma unroll
  for (int i=0;i<4;i++){
    int gm = m0+ty*4+i; if (gm>=M) continue;
#pragma unroll
    for (int j=0;j<4;j++){
      int gn = n0+tx*4+j; if (gn>=N) continue;
      float v = acc[i][j] + bias[gn];
      v = (v>20.f)? v : log1pf(expf(v));
      Y[(size_t)gm*N+gn] = v;
    }
  }
}

// ---------------- causal depthwise conv1d + silu ----------------
__global__ void k_conv(const float* __restrict__ xz, const float* __restrict__ cw,
                       const float* __restrict__ cb, float* __restrict__ xc){
  int idx = blockIdx.x*256 + threadIdx.x;
  if (idx >= ROWS*DI) return;
  int d = idx % DI;
  int r = idx / DI;
  int b = r / NN, l = r % NN;
  float acc = cb[d];
#pragma unroll
  for (int t=0;t<4;t++){
    int ls = l-3+t;
    if (ls>=0) acc += cw[d*4+t] * xz[((size_t)(b*NN+ls))*1536 + d];
  }
  xc[(size_t)r*DI + d] = acc / (1.f + expf(-acc)); // silu
}

// ---------------- chunked scan pass 1 ----------------
__global__ __launch_bounds__(256) void k_scan1(
    const float* __restrict__ dbl, const float* __restrict__ dtb,
    const float* __restrict__ xc, const float* __restrict__ A_log,
    float* __restrict__ hpart, float* __restrict__ sdt)
{
  int wid = (blockIdx.x*256 + threadIdx.x) >> 6;
  int lane = threadIdx.x & 63;
  if (wid >= BB*DI*NC) return;
  int c = wid % NC; int bd = wid / NC;
  int d = bd % DI, b = bd / DI;
  float A = -__expf(A_log[d*DS + lane]);
  int t0 = c*LC;
  const float* dbr = dbl + ((size_t)(b*NN+t0))*152 + DTR;
  const float* dtp = dtb + ((size_t)(b*NN+t0))*DI + d;
  const float* up  = xc  + ((size_t)(b*NN+t0))*DI + d;
  float dt0v = dtp[(size_t)lane*DI];
  float dt1v = (lane+64<LC) ? dtp[(size_t)(lane+64)*DI] : 0.f;
  float u0v  = up[(size_t)lane*DI];
  float u1v  = (lane+64<LC) ? up[(size_t)(lane+64)*DI] : 0.f;
  float h = 0.f, s = 0.f;
  for (int t=0;t<LC;t++){
    float Bv = dbr[(size_t)t*152 + lane];
    float dt = (t<64) ? __shfl(dt0v, t) : __shfl(dt1v, t-64);
    float u  = (t<64) ? __shfl(u0v, t)  : __shfl(u1v, t-64);
    s += dt;
    h = h*__expf(dt*A) + (dt*u)*Bv;
  }
  hpart[((size_t)bd*NC + c)*DS + lane] = h;
  if (lane==0) sdt[bd*NC + c] = s;
}

// ---------------- chunked scan pass 2 ----------------
__global__ __launch_bounds__(256) void k_scan2(
    const float* __restrict__ sdt, const float* __restrict__ A_log,
    float* __restrict__ hpart)
{
  int wid = (blockIdx.x*256 + threadIdx.x) >> 6;
  int lane = threadIdx.x & 63;
  if (wid >= BB*DI) return;
  int d = wid % DI;
  float A = -__expf(A_log[d*DS + lane]);
  float* hp = hpart + (size_t)wid*NC*DS + lane;
  const float* sp = sdt + wid*NC;
  float h = 0.f;
  for (int c=0;c<NC;c++){
    float part = hp[(size_t)c*DS];
    float pA = __expf(A*sp[c]);
    hp[(size_t)c*DS] = h;   // hin for chunk c
    h = h*pA + part;
  }
}

// ---------------- chunked scan pass 3 ----------------
__global__ __launch_bounds__(256) void k_scan3(
    const float* __restrict__ dbl, const float* __restrict__ dtb,
    const float* __restrict__ xc, const float* __restrict__ xz,
    const float* __restrict__ A_log, const float* __restrict__ Dp,
    const float* __restrict__ hin, float* __restrict__ y)
{
  int wid = (blockIdx.x*256 + threadIdx.x) >> 6;
  int lane = threadIdx.x & 63;
  if (wid >= BB*DI*NC) return;
  int c = wid % NC; int bd = wid / NC;
  int d = bd % DI, b = bd / DI;
  float A = -__expf(A_log[d*DS + lane]);
  float Dv = Dp[d];
  int t0 = c*LC;
  const float* dbr = dbl + ((size_t)(b*NN+t0))*152 + DTR;
  const float* dtp = dtb + ((size_t)(b*NN+t0))*DI + d;
  const float* up  = xc  + ((size_t)(b*NN+t0))*DI + d;
  const float* zp  = xz  + ((size_t)(b*NN+t0))*1536 + DI + d;
  float* yp = y + ((size_t)(b*NN+t0))*DI + d;
  float dt0v = dtp[(size_t)lane*DI];
  float dt1v = (lane+64<LC) ? dtp[(size_t)(lane+64)*DI] : 0.f;
  float u0v  = up[(size_t)lane*DI];
  float u1v  = (lane+64<LC) ? up[(size_t)(lane+64)*DI] : 0.f;
  float z0v  = zp[(size_t)lane*1536];
  float z1v  = (lane+64<LC) ? zp[(size_t)(lane+64)*1536] : 0.f;
  float h = hin[((size_t)bd*NC + c)*DS + lane];
  float y0v = 0.f, y1v = 0.f;
  for (int t=0;t<LC;t++){
    float Bv = dbr[(size_t)t*152 + lane];
    float Cv = dbr[(size_t)t*152 + 64 + lane];
    float dt = (t<64) ? __shfl(dt0v, t) : __shfl(dt1v, t-64);
    float u  = (t<64) ? __shfl(u0v, t)  : __shfl(u1v, t-64);
    h = h*__expf(dt*A) + (dt*u)*Bv;
    float p = h*Cv;
#pragma unroll
    for (int o=32;o;o>>=1) p += __shfl_xor(p,o);
    float res = p + u*Dv;
    if (t<64){ if (lane==t) y0v = res; }
    else     { if (lane==t-64) y1v = res; }
  }
  {
    float z = z0v;
    yp[(size_t)lane*DI] = y0v * (z/(1.f+__expf(-z)));
  }
  if (lane+64 < LC){
    float z = z1v;
    yp[(size_t)(lane+64)*DI] = y1v * (z/(1.f+__expf(-z)));
  }
}

// ---------------- twiddle tables ----------------
__global__ void k_twA(float* __restrict__ Wcat){
  int idx = blockIdx.x*256+threadIdx.x;
  if (idx >= 1568*784) return;
  int f = idx / 784, n = idx % 784;
  int ff = (f<784)? f : f-784;
  int m = (int)(((long long)ff*(long long)n) % 784);
  float ang = 6.283185307179586f * (float)m / 784.f;
  float s, cval; sincosf(ang, &s, &cval);
  Wcat[idx] = (f<784)? cval : -s;
}
__global__ void k_twB(float* __restrict__ WT){
  int idx = blockIdx.x*256+threadIdx.x;
  if (idx >= 784*1568) return;
  int n = idx / 1568, k = idx % 1568;
  int kk = (k<784)? k : k-784;
  int m = (int)(((long long)n*(long long)kk) % 784);
  float ang = 6.283185307179586f * (float)m / 784.f;
  float s, cval; sincosf(ang, &s, &cval);
  WT[idx] = (k<784)? cval : -s;
}

// ---------------- build stacked real weights for complex block layers ----------------
// Wc[bl][j][d] (192x192 per bl), bc[bl][j]
__global__ void k_prepw(const float* __restrict__ cw, const float* __restrict__ cb,
                        float* __restrict__ Wc, float* __restrict__ bc){
  int idx = blockIdx.x*256+threadIdx.x;
  if (idx < 4*192*192){
    int d = idx % 192; int j = (idx/192) % 192; int bl = idx/(192*192);
    int jj = j % 96, dd = d % 96;
    const float* w0 = cw + bl*9216;           // cw[0][bl]
    const float* w1 = cw + 4*9216 + bl*9216;  // cw[1][bl]
    float v;
    if (j < 96) v = (d < 96) ? w0[dd*96+jj] : -w1[dd*96+jj];
    else        v = (d < 96) ? w1[dd*96+jj] :  w0[dd*96+jj];
    Wc[idx] = v;
  }
  if (idx < 4*192){
    int j = idx % 192; int bl = idx/192;
    bc[idx] = (j<96) ? cb[bl*96 + j] : cb[384 + bl*96 + (j-96)];
  }
}

// ---------------- forward length-4 DFT along nb -> tcat[r][q*192 + {0:re,96:im} + k] ----------------
__global__ void k_cfft4(const float* __restrict__ Ybuf, float* __restrict__ tcat){
  int idx = blockIdx.x*256+threadIdx.x;
  if (idx >= BB*NN*96) return;
  int k = idx % 96; int r = idx / 96;
  int b = r / NN, f = r % NN;
  const float* fre = Ybuf + (size_t)b*602112 + (size_t)f*384;
  const float* fim = fre + 301056;
  float R0=fre[k], R1=fre[96+k], R2=fre[192+k], R3=fre[288+k];
  float I0=fim[k], I1=fim[96+k], I2=fim[192+k], I3=fim[288+k];
  float* tr = tcat + (size_t)r*768;
  tr[k]       = R0+R1+R2+R3;  tr[96+k]    = I0+I1+I2+I3;
  tr[192+k]   = R0+I1-R2-I3;  tr[192+96+k]= I0-R1-I2+R3;
  tr[384+k]   = R0-R1+R2-R3;  tr[384+96+k]= I0-I1+I2-I3;
  tr[576+k]   = R0-I1-R2+I3;  tr[576+96+k]= I0+R1-I2-R3;
}

// ---------------- inverse length-4 DFT -> YbufT[b][c][fcat] (transposed for inv GEMM) ----------------
__global__ void k_cifft4(const float* __restrict__ t2cat, float* __restrict__ YbufT){
  int idx = blockIdx.x*256+threadIdx.x;
  if (idx >= BB*NN*96) return;
  int k = idx % 96; int r = idx / 96;
  int b = r / NN, f = r % NN;
  const float* tr = t2cat + (size_t)r*768;
  float R0=tr[k],     I0=tr[96+k];
  float R1=tr[192+k], I1=tr[192+96+k];
  float R2=tr[384+k], I2=tr[384+96+k];
  float R3=tr[576+k], I3=tr[576+96+k];
  float* YT = YbufT + (size_t)b*602112;
  float gr[4], gi[4];
  gr[0]=R0+R1+R2+R3; gi[0]=I0+I1+I2+I3;
  gr[1]=R0-I1-R2+I3; gi[1]=I0+R1-I2-R3;
  gr[2]=R0-R1+R2-R3; gi[2]=I0-I1+I2-I3;
  gr[3]=R0+I1-R2-I3; gi[3]=I0-R1-I2+R3;
#pragma unroll
  for (int n=0;n<4;n++){
    int c = n*96 + k;
    YT[(size_t)c*1568 + f]       = gr[n];
    YT[(size_t)c*1568 + 784 + f] = gi[n];
  }
}

extern "C" void kernel_launch(void* const* d_in, const int* in_sizes, int n_in,
                              void* d_out, int out_size, void* d_ws, size_t ws_size,
                              hipStream_t stream){
  const float* x         = (const float*)d_in[0];
  const float* ln1_w     = (const float*)d_in[3];
  const float* ln1_b     = (const float*)d_in[4];
  const float* in_proj_w = (const float*)d_in[5];
  const float* conv_w    = (const float*)d_in[6];
  const float* conv_b    = (const float*)d_in[7];
  const float* x_proj_w  = (const float*)d_in[8];
  const float* dt_proj_w = (const float*)d_in[9];
  const float* dt_proj_b = (const float*)d_in[10];
  const float* A_log     = (const float*)d_in[11];
  const float* Dp        = (const float*)d_in[12];
  const float* out_proj_w= (const float*)d_in[13];
  const float* ln2_w     = (const float*)d_in[14];
  const float* ln2_b     = (const float*)d_in[15];
  const float* cw1       = (const float*)d_in[16];
  const float* cb1       = (const float*)d_in[17];
  const float* cw2       = (const float*)d_in[18];
  const float* cb2       = (const float*)d_in[19];

  float* ws = (float*)d_ws;
  // ---- phase A (mamba) ----
  float* ln   = ws;                  // [0, 602112)
  float* xz   = ws + 602112;         // [602112, 3010560)
  float* xc   = ws + 3010560;        // [3010560, 4214784)
  float* dbl  = ws + 4214784;        // [4214784, 4453120)
  float* dtb  = ws + 4453120;        // [4453120, 5657344)
  float* yb   = ws + 5657344;        // [5657344, 6861568)
  float* x1   = ws + 6861568;        // [6861568, 7463680)  persists to end
  float* hpart= ws + 7463680;        // [7463680, 8250112)
  float* sdt  = ws + 8250112;        // [8250112, 8262400)
  // ---- phase B (einfft) — every launch below happens AFTER the mamba path
  //      has fully consumed the region it overlays (single stream = serial) ----
  float* Wcat = ws + 602112;         // [602112, 1831424)  over dead xz-head
  float* lnT  = ws + 1831424;        // [1831424, 2433536) over dead xz
  float* Ybuf = ws + 2433536;        // [2433536, 3637760) over dead xz-tail/xc-head
  float* WT   = ws + 4453120;        // [4453120, 5682432) over dead dtb + yb-head
  float* tcat = ws + 602112;         // [602112, 1806336)  over dead Wcat (after fwd GEMM)
  float* o1cat= ws + 1806336;        // [1806336, 3010560) over dead lnT/Ybuf-head
  float* t2cat= ws + 3010560;        // [3010560, 4214784) over dead Ybuf-tail/xc (< WT start)
  float* YbufT= ws + 602112;         // [602112, 1806336)  over dead tcat
  float* W1c  = ws + 7463680;        // [7463680, 7537152) over dead hpart
  float* W2c  = ws + 7611136;        // [7611136, 7684608) over dead hpart
  float* b1c  = ws + 7758592;        // 768
  float* b2c  = ws + 7759360;        // 768

  // ---- mamba path ----
  k_ln<<<ROWS,64,0,stream>>>(x, ln1_w, ln1_b, ln, ROWS);
  k_mgemm<0><<<dim3(24,25,1),256,0,stream>>>(ln,384,0, in_proj_w,384,0, nullptr,0,0,
                                             xz,1536,0, ROWS,1536,384, 1.f);
  k_conv<<<(ROWS*DI+255)/256,256,0,stream>>>(xz,conv_w,conv_b,xc);
  k_mgemm<0><<<dim3(3,25,1),256,0,stream>>>(xc,768,0, x_proj_w,768,0, nullptr,0,0,
                                            dbl,152,0, ROWS,152,768, 1.f);
  k_gemm<<<dim3(12,25),256,0,stream>>>(dbl,152,dt_proj_w,dt_proj_b,dtb,ROWS,768,24);
  k_scan1<<<(BB*DI*NC)/4,256,0,stream>>>(dbl,dtb,xc,A_log,hpart,sdt);
  k_scan2<<<(BB*DI)/4,256,0,stream>>>(sdt,A_log,hpart);
  k_scan3<<<(BB*DI*NC)/4,256,0,stream>>>(dbl,dtb,xc,xz,A_log,Dp,hpart,yb);
  k_mgemm<1><<<dim3(6,25,1),256,0,stream>>>(yb,768,0, out_proj_w,768,0, x,384,0,
                                            x1,384,0, ROWS,384,768, 1.f);

  // ---- einfft path (all prep AFTER mamba: overlaid regions now dead) ----
  k_twA<<<(1568*784+255)/256,256,0,stream>>>(Wcat);
  k_twB<<<(784*1568+255)/256,256,0,stream>>>(WT);
  k_prepw<<<(4*192*192+255)/256,256,0,stream>>>(cw1,cb1,W1c,b1c);
  k_prepw<<<(4*192*192+255)/256,256,0,stream>>>(cw2,cb2,W2c,b2c);
  k_lnT<<<ROWS,64,0,stream>>>(x1, ln2_w, ln2_b, lnT);
  // forward DFT-784 (real input): Ybuf[fcat][c] = (1/56) * Wcat @ lnT^T
  k_mgemm<0><<<dim3(6,25,2),256,0,stream>>>(Wcat,784,0, lnT,784,301056, nullptr,0,0,
                                            Ybuf,384,602112, 1568,384,784, 1.f/56.f);
  // forward DFT-4 along nb -> tcat
  k_cfft4<<<(BB*NN*96+255)/256,256,0,stream>>>(Ybuf,tcat);
  // EinFFT layer 1 (relu)
  k_mgemm<2><<<dim3(3,25,4),256,0,stream>>>(tcat,768,192, W1c,192,36864, b1c,0,192,
                                            o1cat,768,192, ROWS,192,192, 1.f);
  // EinFFT layer 2 (soft shrink)
  k_mgemm<3><<<dim3(3,25,4),256,0,stream>>>(o1cat,768,192, W2c,192,36864, b2c,0,192,
                                            t2cat,768,192, ROWS,192,192, 1.f);
  // inverse DFT-4 -> YbufT[b][c][fcat]
  k_cifft4<<<(BB*NN*96+255)/256,256,0,stream>>>(t2cat,YbufT);
  // inverse DFT-784 + residual: out = x1 + (1/56) WT @ YbufT^T
  k_mgemm<1><<<dim3(6,13,2),256,0,stream>>>(WT,1568,0, YbufT,1568,602112, x1,384,301056,
                                            (float*)d_out,384,301056, 784,384,1568, 1.f/56.f);
}

// Round 5
// 358.475 us; speedup vs baseline: 4.7501x; 1.1398x over previous
//
#include <hip/hip_runtime.h>
#include <math.h>

#define BB 2
#define NN 784
#define CC 384
#define DI 768
#define DS 64
#define DTR 24
#define ROWS (BB*NN)   // 1568
#define NC 8
#define LC 98          // NC*LC == NN

typedef __attribute__((ext_vector_type(8))) short bf16x8;
typedef __attribute__((ext_vector_type(4))) float f32x4;

static __device__ inline short f2bf(float f){
  unsigned u = __float_as_uint(f);
  unsigned r = (u + 0x7fffu + ((u>>16)&1u)) >> 16;
  return (short)r;
}
static __device__ inline float rdlane(float v, int t){
  return __uint_as_float(__builtin_amdgcn_readlane(__float_as_uint(v), t));
}

// ---------------- LayerNorm: one wave per row of 384 ----------------
__global__ void k_ln(const float* __restrict__ x, const float* __restrict__ w,
                     const float* __restrict__ b, float* __restrict__ out, int rows){
  int row = blockIdx.x;
  if (row >= rows) return;
  int lane = threadIdx.x; // blockDim = 64
  const float* xr = x + (size_t)row*CC;
  float v[6]; float s = 0.f;
#pragma unroll
  for (int i=0;i<6;i++){ v[i] = xr[lane + 64*i]; s += v[i]; }
#pragma unroll
  for (int o=32;o;o>>=1) s += __shfl_xor(s,o);
  float mu = s * (1.f/CC);
  float vs = 0.f;
#pragma unroll
  for (int i=0;i<6;i++){ float d=v[i]-mu; vs += d*d; }
#pragma unroll
  for (int o=32;o;o>>=1) vs += __shfl_xor(vs,o);
  float rstd = rsqrtf(vs*(1.f/CC) + 1e-5f);
  float* orow = out + (size_t)row*CC;
#pragma unroll
  for (int i=0;i<6;i++){ int c = lane+64*i; orow[c] = (v[i]-mu)*rstd*w[c] + b[c]; }
}

// ---------------- LayerNorm with transposed output: lnT[b][c][n] ----------------
__global__ void k_lnT(const float* __restrict__ x, const float* __restrict__ w,
                      const float* __restrict__ b, float* __restrict__ out){
  int row = blockIdx.x;      // b*784 + n
  if (row >= ROWS) return;
  int bb = row / NN, n = row % NN;
  int lane = threadIdx.x;
  const float* xr = x + (size_t)row*CC;
  float v[6]; float s = 0.f;
#pragma unroll
  for (int i=0;i<6;i++){ v[i] = xr[lane + 64*i]; s += v[i]; }
#pragma unroll
  for (int o=32;o;o>>=1) s += __shfl_xor(s,o);
  float mu = s * (1.f/CC);
  float vs = 0.f;
#pragma unroll
  for (int i=0;i<6;i++){ float d=v[i]-mu; vs += d*d; }
#pragma unroll
  for (int o=32;o;o>>=1) vs += __shfl_xor(vs,o);
  float rstd = rsqrtf(vs*(1.f/CC) + 1e-5f);
  float* ob = out + (size_t)bb*301056 + n;
#pragma unroll
  for (int i=0;i<6;i++){ int c = lane+64*i; ob[(size_t)c*NN] = (v[i]-mu)*rstd*w[c] + b[c]; }
}

// ---------------- bf16 MFMA GEMM: Y = alpha*(A[M,K] @ Bw[N,K]^T) + epi ----------------
// EPI 0: alpha*acc ; 1: alpha*acc + aux[row*ldaux+col] ; 2: relu(acc+aux[col]) ; 3: shrink(acc+aux[col],0.01)
template<int EPI>
__global__ __launch_bounds__(256) void k_mgemm(
    const float* __restrict__ A, int lda, long long Azs,
    const float* __restrict__ Bw, int ldb, long long Bzs,
    const float* __restrict__ aux, int ldaux, long long auxzs,
    float* __restrict__ Y, int ldo, long long Ozs,
    int M, int N, int K, float alpha)
{
  __shared__ __align__(16) short As[64*32];
  __shared__ __align__(16) short Bs[64*32];
  int z = blockIdx.z;
  A  += (size_t)z*Azs; Bw += (size_t)z*Bzs; Y += (size_t)z*Ozs;
  if (EPI != 0) aux += (size_t)z*auxzs;
  int m0 = blockIdx.y*64, n0 = blockIdx.x*64;
  int t = threadIdx.x;
  int srow = t>>2, skg = t&3;                 // staging: row 0..63, k-group 0..3 (8 elems)
  int w = t>>6, lane = t&63;
  int wr = (w>>1)*32, wc = (w&1)*32;
  int l15 = lane&15, lh = lane>>4;
  f32x4 acc[2][2] = {};
  int sslot = skg ^ ((srow>>1)&3);
  for (int k0=0; k0<K; k0+=32){
    // ---- stage A ----
    {
      int gm = m0 + srow, gk = k0 + skg*8;
      float4 v0 = {0,0,0,0}, v1 = {0,0,0,0};
      if (gm < M && gk < K){
        const float* p = A + (size_t)gm*lda + gk;
        v0 = *(const float4*)p; v1 = *(const float4*)(p+4);
      }
      union { short s[8]; bf16x8 v; } pk;
      pk.s[0]=f2bf(v0.x); pk.s[1]=f2bf(v0.y); pk.s[2]=f2bf(v0.z); pk.s[3]=f2bf(v0.w);
      pk.s[4]=f2bf(v1.x); pk.s[5]=f2bf(v1.y); pk.s[6]=f2bf(v1.z); pk.s[7]=f2bf(v1.w);
      *(bf16x8*)(As + srow*32 + sslot*8) = pk.v;
    }
    // ---- stage B (W-form [N][K]) ----
    {
      int gn = n0 + srow, gk = k0 + skg*8;
      float4 v0 = {0,0,0,0}, v1 = {0,0,0,0};
      if (gn < N && gk < K){
        const float* p = Bw + (size_t)gn*ldb + gk;
        v0 = *(const float4*)p; v1 = *(const float4*)(p+4);
      }
      union { short s[8]; bf16x8 v; } pk;
      pk.s[0]=f2bf(v0.x); pk.s[1]=f2bf(v0.y); pk.s[2]=f2bf(v0.z); pk.s[3]=f2bf(v0.w);
      pk.s[4]=f2bf(v1.x); pk.s[5]=f2bf(v1.y); pk.s[6]=f2bf(v1.z); pk.s[7]=f2bf(v1.w);
      *(bf16x8*)(Bs + srow*32 + sslot*8) = pk.v;
    }
    __syncthreads();
    bf16x8 af[2], bfr[2];
#pragma unroll
    for (int mi=0; mi<2; mi++){
      int row = wr + mi*16 + l15;
      af[mi] = *(const bf16x8*)(As + row*32 + ((lh ^ ((row>>1)&3))<<3));
    }
#pragma unroll
    for (int ni=0; ni<2; ni++){
      int col = wc + ni*16 + l15;
      bfr[ni] = *(const bf16x8*)(Bs + col*32 + ((lh ^ ((col>>1)&3))<<3));
    }
#pragma unroll
    for (int mi=0; mi<2; mi++)
#pragma unroll
      for (int ni=0; ni<2; ni++)
        acc[mi][ni] = __builtin_amdgcn_mfma_f32_16x16x32_bf16(af[mi], bfr[ni], acc[mi][ni], 0, 0, 0);
    __syncthreads();
  }
  // ---- epilogue ----
#pragma unroll
  for (int mi=0; mi<2; mi++){
#pragma unroll
    for (int ni=0; ni<2; ni++){
      int col = n0 + wc + ni*16 + l15;
      if (col >= N) continue;
#pragma unroll
      for (int j=0; j<4; j++){
        int row = m0 + wr + mi*16 + lh*4 + j;
        if (row >= M) continue;
        float v = acc[mi][ni][j];
        if (EPI == 0){ v *= alpha; }
        else if (EPI == 1){ v = v*alpha + aux[(size_t)row*ldaux + col]; }
        else if (EPI == 2){ v += aux[col]; v = fmaxf(v, 0.f); }
        else { v += aux[col]; v = copysignf(fmaxf(fabsf(v)-0.01f, 0.f), v); }
        Y[(size_t)row*ldo + col] = v;
      }
    }
  }
}

// ---------------- fp32 GEMM (dt_proj only): Y = softplus(X@W^T + bias) ----------------
#define GBM 64
#define GBN 64
#define GBK 16
__global__ __launch_bounds__(256) void k_gemm(
    const float* __restrict__ X, int lda,
    const float* __restrict__ W,
    const float* __restrict__ bias,
    float* __restrict__ Y,
    int M, int N, int K)
{
  __shared__ float As[GBK][GBM+4];
  __shared__ float Bs[GBK][GBN+4];
  int m0 = blockIdx.y*GBM, n0 = blockIdx.x*GBN;
  int tid = threadIdx.x;
  int ty = tid>>4, tx = tid&15;
  float acc[4][4] = {{0.f}};
  for (int k0=0;k0<K;k0+=GBK){
#pragma unroll
    for (int l=0;l<4;l++){
      int e = tid + 256*l;
      int m = e>>4, kk = e&15;
      int gm = m0+m, gk = k0+kk;
      As[kk][m] = (gm<M && gk<K) ? X[(size_t)gm*lda+gk] : 0.f;
      int gn = n0+m;
      Bs[kk][m] = (gn<N && gk<K) ? W[(size_t)gn*K+gk] : 0.f;
    }
    __syncthreads();
#pragma unroll
    for (int kk=0;kk<GBK;kk++){
      float4 av = *(const float4*)&As[kk][ty*4];
      float4 bv = *(const float4*)&Bs[kk][tx*4];
      float a[4]={av.x,av.y,av.z,av.w}, b[4]={bv.x,bv.y,bv.z,bv.w};
#pragma unroll
      for (int i=0;i<4;i++)
#pragma unroll
        for (int j=0;j<4;j++) acc[i][j] += a[i]*b[j];
    }
    __syncthreads();
  }
#pragma unroll
  for (int i=0;i<4;i++){
    int gm = m0+ty*4+i; if (gm>=M) continue;
#pragma unroll
    for (int j=0;j<4;j++){
      int gn = n0+tx*4+j; if (gn>=N) continue;
      float v = acc[i][j] + bias[gn];
      v = (v>20.f)? v : log1pf(expf(v));
      Y[(size_t)gm*N+gn] = v;
    }
  }
}

// ---------------- causal depthwise conv1d + silu ----------------
__global__ void k_conv(const float* __restrict__ xz, const float* __restrict__ cw,
                       const float* __restrict__ cb, float* __restrict__ xc){
  int idx = blockIdx.x*256 + threadIdx.x;
  if (idx >= ROWS*DI) return;
  int d = idx % DI;
  int r = idx / DI;
  int b = r / NN, l = r % NN;
  float acc = cb[d];
#pragma unroll
  for (int t=0;t<4;t++){
    int ls = l-3+t;
    if (ls>=0) acc += cw[d*4+t] * xz[((size_t)(b*NN+ls))*1536 + d];
  }
  xc[(size_t)r*DI + d] = acc / (1.f + expf(-acc)); // silu
}

// ---------------- chunked scan pass 1: per-chunk partial state + sum(dt) ----------------
__global__ __launch_bounds__(256) void k_scan1(
    const float* __restrict__ dbl, const float* __restrict__ dtb,
    const float* __restrict__ xc, const float* __restrict__ A_log,
    float* __restrict__ hpart, float* __restrict__ sdt)
{
  int wid = (blockIdx.x*256 + threadIdx.x) >> 6;
  int lane = threadIdx.x & 63;
  if (wid >= BB*DI*NC) return;
  int c = wid % NC; int bd = wid / NC;
  int d = bd % DI, b = bd / DI;
  float A = -__expf(A_log[d*DS + lane]);
  int t0 = c*LC;
  const float* dbr = dbl + ((size_t)(b*NN+t0))*152 + DTR;
  const float* dtp = dtb + ((size_t)(b*NN+t0))*DI + d;
  const float* up  = xc  + ((size_t)(b*NN+t0))*DI + d;
  float dt0v = dtp[(size_t)lane*DI];
  float dt1v = (lane+64<LC) ? dtp[(size_t)(lane+64)*DI] : 0.f;
  float u0v  = up[(size_t)lane*DI];
  float u1v  = (lane+64<LC) ? up[(size_t)(lane+64)*DI] : 0.f;
  float h = 0.f;
  for (int t=0;t<64;t++){
    float Bv = dbr[(size_t)t*152 + lane];
    float dt = rdlane(dt0v, t);
    float u  = rdlane(u0v, t);
    h = h*__expf(dt*A) + (dt*u)*Bv;
  }
  for (int j=0;j<LC-64;j++){
    float Bv = dbr[(size_t)(64+j)*152 + lane];
    float dt = rdlane(dt1v, j);
    float u  = rdlane(u1v, j);
    h = h*__expf(dt*A) + (dt*u)*Bv;
  }
  hpart[((size_t)bd*NC + c)*DS + lane] = h;
  // sum(dt) over the chunk via one butterfly (dt values live one-per-lane)
  float s = dt0v + dt1v;
#pragma unroll
  for (int o=32;o;o>>=1) s += __shfl_xor(s,o);
  if (lane==0) sdt[bd*NC + c] = s;
}

// ---------------- chunked scan pass 2: chunk-prefix (in place: hpart -> hin) ----------------
__global__ __launch_bounds__(256) void k_scan2(
    const float* __restrict__ sdt, const float* __restrict__ A_log,
    float* __restrict__ hpart)
{
  int wid = (blockIdx.x*256 + threadIdx.x) >> 6;
  int lane = threadIdx.x & 63;
  if (wid >= BB*DI) return;
  int d = wid % DI;
  float A = -__expf(A_log[d*DS + lane]);
  float* hp = hpart + (size_t)wid*NC*DS + lane;
  const float* sp = sdt + wid*NC;
  float h = 0.f;
  for (int c=0;c<NC;c++){
    float part = hp[(size_t)c*DS];
    float pA = __expf(A*sp[c]);
    hp[(size_t)c*DS] = h;   // hin for chunk c
    h = h*pA + part;
  }
}

// ---------------- chunked scan pass 3: recompute with hin, emit gated y ----------------
// Per step: 2-level partial butterfly -> 16 partials to LDS; batched row-sum per phase.
__global__ __launch_bounds__(256) void k_scan3(
    const float* __restrict__ dbl, const float* __restrict__ dtb,
    const float* __restrict__ xc, const float* __restrict__ xz,
    const float* __restrict__ A_log, const float* __restrict__ Dp,
    const float* __restrict__ hin, float* __restrict__ y)
{
  __shared__ float red[4][64*17];
  int wv = threadIdx.x >> 6;
  int wid = (blockIdx.x*256 + threadIdx.x) >> 6;
  int lane = threadIdx.x & 63;
  if (wid >= BB*DI*NC) return;
  int c = wid % NC; int bd = wid / NC;
  int d = bd % DI, b = bd / DI;
  float A = -__expf(A_log[d*DS + lane]);
  float Dv = Dp[d];
  int t0 = c*LC;
  const float* dbr = dbl + ((size_t)(b*NN+t0))*152 + DTR;
  const float* dtp = dtb + ((size_t)(b*NN+t0))*DI + d;
  const float* up  = xc  + ((size_t)(b*NN+t0))*DI + d;
  const float* zp  = xz  + ((size_t)(b*NN+t0))*1536 + DI + d;
  float* yp = y + ((size_t)(b*NN+t0))*DI + d;
  float dt0v = dtp[(size_t)lane*DI];
  float dt1v = (lane+64<LC) ? dtp[(size_t)(lane+64)*DI] : 0.f;
  float u0v  = up[(size_t)lane*DI];
  float u1v  = (lane+64<LC) ? up[(size_t)(lane+64)*DI] : 0.f;
  float z0v  = zp[(size_t)lane*1536];
  float z1v  = (lane+64<LC) ? zp[(size_t)(lane+64)*1536] : 0.f;
  float h = hin[((size_t)bd*NC + c)*DS + lane];
  float* rw = red[wv];
  int g = lane>>2;
  bool gl = (lane&3)==0;
  // ---- phase 1: t = 0..63 ----
  for (int t=0;t<64;t++){
    float Bv = dbr[(size_t)t*152 + lane];
    float Cv = dbr[(size_t)t*152 + 64 + lane];
    float dt = rdlane(dt0v, t);
    float u  = rdlane(u0v, t);
    h = h*__expf(dt*A) + (dt*u)*Bv;
    float p = h*Cv;
    p += __shfl_xor(p,1);
    p += __shfl_xor(p,2);
    if (gl) rw[t*17 + g] = p;
  }
  {
    const float* rr = rw + lane*17;
    float a0 = rr[0]+rr[4]+rr[8] +rr[12];
    float a1 = rr[1]+rr[5]+rr[9] +rr[13];
    float a2 = rr[2]+rr[6]+rr[10]+rr[14];
    float a3 = rr[3]+rr[7]+rr[11]+rr[15];
    float yv = (a0+a1)+(a2+a3) + u0v*Dv;     // lane == t
    float z = z0v;
    yp[(size_t)lane*DI] = yv * (z/(1.f+__expf(-z)));
  }
  // ---- phase 2: t = 64..97 ----
  for (int j=0;j<LC-64;j++){
    float Bv = dbr[(size_t)(64+j)*152 + lane];
    float Cv = dbr[(size_t)(64+j)*152 + 64 + lane];
    float dt = rdlane(dt1v, j);
    float u  = rdlane(u1v, j);
    h = h*__expf(dt*A) + (dt*u)*Bv;
    float p = h*Cv;
    p += __shfl_xor(p,1);
    p += __shfl_xor(p,2);
    if (gl) rw[j*17 + g] = p;
  }
  if (lane < LC-64){
    const float* rr = rw + lane*17;
    float a0 = rr[0]+rr[4]+rr[8] +rr[12];
    float a1 = rr[1]+rr[5]+rr[9] +rr[13];
    float a2 = rr[2]+rr[6]+rr[10]+rr[14];
    float a3 = rr[3]+rr[7]+rr[11]+rr[15];
    float yv = (a0+a1)+(a2+a3) + u1v*Dv;     // lane == t-64
    float z = z1v;
    yp[(size_t)(lane+64)*DI] = yv * (z/(1.f+__expf(-z)));
  }
}

// ---------------- twiddle tables (one sincos pass -> both layouts) ----------------
// Wcat[f][n] (1568x784) and WT[n][f] (784x1568); WT == Wcat^T elementwise.
__global__ void k_tw(float* __restrict__ Wcat, float* __restrict__ WT){
  int idx = blockIdx.x*256+threadIdx.x;
  if (idx >= 784*1568) return;
  int n = idx / 1568, f = idx % 1568;
  int ff = (f<784)? f : f-784;
  int m = (int)(((long long)ff*(long long)n) % 784);
  float ang = 6.283185307179586f * (float)m / 784.f;
  float s, cval; sincosf(ang, &s, &cval);
  float v = (f<784)? cval : -s;
  WT[(size_t)n*1568 + f] = v;
  Wcat[(size_t)f*784 + n] = v;
}

// ---------------- build stacked real weights for complex block layers ----------------
__global__ void k_prepw(const float* __restrict__ cw, const float* __restrict__ cb,
                        float* __restrict__ Wc, float* __restrict__ bc){
  int idx = blockIdx.x*256+threadIdx.x;
  if (idx < 4*192*192){
    int d = idx % 192; int j = (idx/192) % 192; int bl = idx/(192*192);
    int jj = j % 96, dd = d % 96;
    const float* w0 = cw + bl*9216;           // cw[0][bl]
    const float* w1 = cw + 4*9216 + bl*9216;  // cw[1][bl]
    float v;
    if (j < 96) v = (d < 96) ? w0[dd*96+jj] : -w1[dd*96+jj];
    else        v = (d < 96) ? w1[dd*96+jj] :  w0[dd*96+jj];
    Wc[idx] = v;
  }
  if (idx < 4*192){
    int j = idx % 192; int bl = idx/192;
    bc[idx] = (j<96) ? cb[bl*96 + j] : cb[384 + bl*96 + (j-96)];
  }
}

// ---------------- forward length-4 DFT along nb -> tcat[r][q*192 + {0:re,96:im} + k] ----------------
__global__ void k_cfft4(const float* __restrict__ Ybuf, float* __restrict__ tcat){
  int idx = blockIdx.x*256+threadIdx.x;
  if (idx >= BB*NN*96) return;
  int k = idx % 96; int r = idx / 96;
  int b = r / NN, f = r % NN;
  const float* fre = Ybuf + (size_t)b*602112 + (size_t)f*384;
  const float* fim = fre + 301056;
  float R0=fre[k], R1=fre[96+k], R2=fre[192+k], R3=fre[288+k];
  float I0=fim[k], I1=fim[96+k], I2=fim[192+k], I3=fim[288+k];
  float* tr = tcat + (size_t)r*768;
  tr[k]       = R0+R1+R2+R3;  tr[96+k]    = I0+I1+I2+I3;
  tr[192+k]   = R0+I1-R2-I3;  tr[192+96+k]= I0-R1-I2+R3;
  tr[384+k]   = R0-R1+R2-R3;  tr[384+96+k]= I0-I1+I2-I3;
  tr[576+k]   = R0-I1-R2+I3;  tr[576+96+k]= I0+R1-I2-R3;
}

// ---------------- inverse length-4 DFT -> YbufT[b][c][fcat] (coalesced stores) ----------------
__global__ void k_cifft4(const float* __restrict__ t2cat, float* __restrict__ YbufT){
  int idx = blockIdx.x*256+threadIdx.x;
  if (idx >= BB*NN*96) return;
  int f = idx % 784;
  int rest = idx / 784;
  int k = rest % 96;
  int b = rest / 96;
  const float* tr = t2cat + ((size_t)(b*NN+f))*768;
  float R0=tr[k],     I0=tr[96+k];
  float R1=tr[192+k], I1=tr[192+96+k];
  float R2=tr[384+k], I2=tr[384+96+k];
  float R3=tr[576+k], I3=tr[576+96+k];
  float* YT = YbufT + (size_t)b*602112;
  float gr[4], gi[4];
  gr[0]=R0+R1+R2+R3; gi[0]=I0+I1+I2+I3;
  gr[1]=R0-I1-R2+I3; gi[1]=I0+R1-I2-R3;
  gr[2]=R0-R1+R2-R3; gi[2]=I0-I1+I2-I3;
  gr[3]=R0+I1-R2-I3; gi[3]=I0-R1-I2+R3;
#pragma unroll
  for (int n=0;n<4;n++){
    int c = n*96 + k;
    YT[(size_t)c*1568 + f]       = gr[n];
    YT[(size_t)c*1568 + 784 + f] = gi[n];
  }
}

extern "C" void kernel_launch(void* const* d_in, const int* in_sizes, int n_in,
                              void* d_out, int out_size, void* d_ws, size_t ws_size,
                              hipStream_t stream){
  const float* x         = (const float*)d_in[0];
  const float* ln1_w     = (const float*)d_in[3];
  const float* ln1_b     = (const float*)d_in[4];
  const float* in_proj_w = (const float*)d_in[5];
  const float* conv_w    = (const float*)d_in[6];
  const float* conv_b    = (const float*)d_in[7];
  const float* x_proj_w  = (const float*)d_in[8];
  const float* dt_proj_w = (const float*)d_in[9];
  const float* dt_proj_b = (const float*)d_in[10];
  const float* A_log     = (const float*)d_in[11];
  const float* Dp        = (const float*)d_in[12];
  const float* out_proj_w= (const float*)d_in[13];
  const float* ln2_w     = (const float*)d_in[14];
  const float* ln2_b     = (const float*)d_in[15];
  const float* cw1       = (const float*)d_in[16];
  const float* cb1       = (const float*)d_in[17];
  const float* cw2       = (const float*)d_in[18];
  const float* cb2       = (const float*)d_in[19];

  float* ws = (float*)d_ws;
  // ---- phase A (mamba) ----
  float* ln   = ws;                  // [0, 602112)
  float* xz   = ws + 602112;         // [602112, 3010560)
  float* xc   = ws + 3010560;        // [3010560, 4214784)
  float* dbl  = ws + 4214784;        // [4214784, 4453120)
  float* dtb  = ws + 4453120;        // [4453120, 5657344)
  float* yb   = ws + 5657344;        // [5657344, 6861568)
  float* x1   = ws + 6861568;        // [6861568, 7463680)  persists to end
  float* hpart= ws + 7463680;        // [7463680, 8250112)
  float* sdt  = ws + 8250112;        // [8250112, 8262400)
  // ---- phase B (einfft) — launched AFTER the mamba path has fully consumed
  //      each overlaid region (single stream = serial) ----
  float* Wcat = ws + 602112;         // [602112, 1831424)  over dead xz-head
  float* lnT  = ws + 1831424;        // [1831424, 2433536) over dead xz
  float* Ybuf = ws + 2433536;        // [2433536, 3637760) over dead xz-tail/xc-head
  float* WT   = ws + 4453120;        // [4453120, 5682432) over dead dtb + yb-head
  float* tcat = ws + 602112;         // [602112, 1806336)  over dead Wcat (after fwd GEMM)
  float* o1cat= ws + 1806336;        // [1806336, 3010560) over dead lnT/Ybuf-head
  float* t2cat= ws + 3010560;        // [3010560, 4214784) over dead Ybuf-tail/xc (< WT start)
  float* YbufT= ws + 602112;         // [602112, 1806336)  over dead tcat
  float* W1c  = ws + 7463680;        // over dead hpart
  float* W2c  = ws + 7611136;        // over dead hpart
  float* b1c  = ws + 7758592;        // 768
  float* b2c  = ws + 7759360;        // 768

  // ---- mamba path ----
  k_ln<<<ROWS,64,0,stream>>>(x, ln1_w, ln1_b, ln, ROWS);
  k_mgemm<0><<<dim3(24,25,1),256,0,stream>>>(ln,384,0, in_proj_w,384,0, nullptr,0,0,
                                             xz,1536,0, ROWS,1536,384, 1.f);
  k_conv<<<(ROWS*DI+255)/256,256,0,stream>>>(xz,conv_w,conv_b,xc);
  k_mgemm<0><<<dim3(3,25,1),256,0,stream>>>(xc,768,0, x_proj_w,768,0, nullptr,0,0,
                                            dbl,152,0, ROWS,152,768, 1.f);
  k_gemm<<<dim3(12,25),256,0,stream>>>(dbl,152,dt_proj_w,dt_proj_b,dtb,ROWS,768,24);
  k_scan1<<<(BB*DI*NC)/4,256,0,stream>>>(dbl,dtb,xc,A_log,hpart,sdt);
  k_scan2<<<(BB*DI)/4,256,0,stream>>>(sdt,A_log,hpart);
  k_scan3<<<(BB*DI*NC)/4,256,0,stream>>>(dbl,dtb,xc,xz,A_log,Dp,hpart,yb);
  k_mgemm<1><<<dim3(6,25,1),256,0,stream>>>(yb,768,0, out_proj_w,768,0, x,384,0,
                                            x1,384,0, ROWS,384,768, 1.f);

  // ---- einfft path (all prep AFTER mamba: overlaid regions now dead) ----
  k_tw<<<(784*1568+255)/256,256,0,stream>>>(Wcat,WT);
  k_prepw<<<(4*192*192+255)/256,256,0,stream>>>(cw1,cb1,W1c,b1c);
  k_prepw<<<(4*192*192+255)/256,256,0,stream>>>(cw2,cb2,W2c,b2c);
  k_lnT<<<ROWS,64,0,stream>>>(x1, ln2_w, ln2_b, lnT);
  // forward DFT-784 (real input): Ybuf[fcat][c] = (1/56) * Wcat @ lnT^T
  k_mgemm<0><<<dim3(6,25,2),256,0,stream>>>(Wcat,784,0, lnT,784,301056, nullptr,0,0,
                                            Ybuf,384,602112, 1568,384,784, 1.f/56.f);
  // forward DFT-4 along nb -> tcat
  k_cfft4<<<(BB*NN*96+255)/256,256,0,stream>>>(Ybuf,tcat);
  // EinFFT layer 1 (relu)
  k_mgemm<2><<<dim3(3,25,4),256,0,stream>>>(tcat,768,192, W1c,192,36864, b1c,0,192,
                                            o1cat,768,192, ROWS,192,192, 1.f);
  // EinFFT layer 2 (soft shrink)
  k_mgemm<3><<<dim3(3,25,4),256,0,stream>>>(o1cat,768,192, W2c,192,36864, b2c,0,192,
                                            t2cat,768,192, ROWS,192,192, 1.f);
  // inverse DFT-4 -> YbufT[b][c][fcat]
  k_cifft4<<<(BB*NN*96+255)/256,256,0,stream>>>(t2cat,YbufT);
  // inverse DFT-784 + residual: out = x1 + (1/56) WT @ YbufT^T
  k_mgemm<1><<<dim3(6,13,2),256,0,stream>>>(WT,1568,0, YbufT,1568,602112, x1,384,301056,
                                            (float*)d_out,384,301056, 784,384,1568, 1.f/56.f);
}

// Round 7
// 327.072 us; speedup vs baseline: 5.2061x; 1.0960x over previous
//
#include <hip/hip_runtime.h>
#include <math.h>

#define BB 2
#define NN 784
#define CC 384
#define DI 768
#define DS 64
#define DTR 24
#define ROWS (BB*NN)   // 1568
#define NC 16
#define LC 49          // NC*LC == NN

typedef __attribute__((ext_vector_type(8))) short bf16x8;
typedef __attribute__((ext_vector_type(4))) float f32x4;

static __device__ inline short f2bf(float f){
  unsigned u = __float_as_uint(f);
  unsigned r = (u + 0x7fffu + ((u>>16)&1u)) >> 16;
  return (short)r;
}
static __device__ inline float bf2f(short v){
  return __uint_as_float(((unsigned)(unsigned short)v)<<16);
}
static __device__ inline float rdlane(float v, int t){
  return __uint_as_float(__builtin_amdgcn_readlane(__float_as_uint(v), t));
}

// ---------------- LayerNorm: one wave per row of 384 ----------------
__global__ void k_ln(const float* __restrict__ x, const float* __restrict__ w,
                     const float* __restrict__ b, float* __restrict__ out, int rows){
  int row = blockIdx.x;
  if (row >= rows) return;
  int lane = threadIdx.x; // blockDim = 64
  const float* xr = x + (size_t)row*CC;
  float v[6]; float s = 0.f;
#pragma unroll
  for (int i=0;i<6;i++){ v[i] = xr[lane + 64*i]; s += v[i]; }
#pragma unroll
  for (int o=32;o;o>>=1) s += __shfl_xor(s,o);
  float mu = s * (1.f/CC);
  float vs = 0.f;
#pragma unroll
  for (int i=0;i<6;i++){ float d=v[i]-mu; vs += d*d; }
#pragma unroll
  for (int o=32;o;o>>=1) vs += __shfl_xor(vs,o);
  float rstd = rsqrtf(vs*(1.f/CC) + 1e-5f);
  float* orow = out + (size_t)row*CC;
#pragma unroll
  for (int i=0;i<6;i++){ int c = lane+64*i; orow[c] = (v[i]-mu)*rstd*w[c] + b[c]; }
}

// ---------------- LayerNorm with transposed output: lnT[b][c][n] ----------------
__global__ void k_lnT(const float* __restrict__ x, const float* __restrict__ w,
                      const float* __restrict__ b, float* __restrict__ out){
  int row = blockIdx.x;      // b*784 + n
  if (row >= ROWS) return;
  int bb = row / NN, n = row % NN;
  int lane = threadIdx.x;
  const float* xr = x + (size_t)row*CC;
  float v[6]; float s = 0.f;
#pragma unroll
  for (int i=0;i<6;i++){ v[i] = xr[lane + 64*i]; s += v[i]; }
#pragma unroll
  for (int o=32;o;o>>=1) s += __shfl_xor(s,o);
  float mu = s * (1.f/CC);
  float vs = 0.f;
#pragma unroll
  for (int i=0;i<6;i++){ float d=v[i]-mu; vs += d*d; }
#pragma unroll
  for (int o=32;o;o>>=1) vs += __shfl_xor(vs,o);
  float rstd = rsqrtf(vs*(1.f/CC) + 1e-5f);
  float* ob = out + (size_t)bb*301056 + n;
#pragma unroll
  for (int i=0;i<6;i++){ int c = lane+64*i; ob[(size_t)c*NN] = (v[i]-mu)*rstd*w[c] + b[c]; }
}

// ---------------- bf16 MFMA GEMM: Y = alpha*(A[M,K] @ Bw[N,K]^T) + epi ----------------
// EPI 0: alpha*acc ; 1: alpha*acc + aux[row*ldaux+col] ; 2: relu(acc+aux[col]) ; 3: shrink(acc+aux[col],0.01)
// ABF/BBF: operand already bf16 (lda/ldb in elements of that type)
template<int EPI, int ABF, int BBF>
__global__ __launch_bounds__(256) void k_mgemm(
    const void* __restrict__ Ap, int lda, long long Azs,
    const void* __restrict__ Bp, int ldb, long long Bzs,
    const float* __restrict__ aux, int ldaux, long long auxzs,
    float* __restrict__ Y, int ldo, long long Ozs,
    int M, int N, int K, float alpha)
{
  __shared__ __align__(16) short As[64*32];
  __shared__ __align__(16) short Bs[64*32];
  int z = blockIdx.z;
  if (EPI != 0) aux += (size_t)z*auxzs;
  Y += (size_t)z*Ozs;
  int m0 = blockIdx.y*64, n0 = blockIdx.x*64;
  int t = threadIdx.x;
  int srow = t>>2, skg = t&3;                 // staging: row 0..63, k-group 0..3 (8 elems)
  int w = t>>6, lane = t&63;
  int wr = (w>>1)*32, wc = (w&1)*32;
  int l15 = lane&15, lh = lane>>4;
  f32x4 acc[2][2] = {};
  int sslot = skg ^ ((srow>>1)&3);
  for (int k0=0; k0<K; k0+=32){
    // ---- stage A ----
    {
      int gm = m0 + srow, gk = k0 + skg*8;
      if (ABF){
        bf16x8 v = {};
        if (gm < M && gk < K) v = *(const bf16x8*)((const short*)Ap + (size_t)z*Azs + (size_t)gm*lda + gk);
        *(bf16x8*)(As + srow*32 + sslot*8) = v;
      } else {
        const float* Af = (const float*)Ap + (size_t)z*Azs;
        float4 v0 = {0,0,0,0}, v1 = {0,0,0,0};
        if (gm < M && gk < K){
          const float* p = Af + (size_t)gm*lda + gk;
          v0 = *(const float4*)p; v1 = *(const float4*)(p+4);
        }
        union { short s[8]; bf16x8 v; } pk;
        pk.s[0]=f2bf(v0.x); pk.s[1]=f2bf(v0.y); pk.s[2]=f2bf(v0.z); pk.s[3]=f2bf(v0.w);
        pk.s[4]=f2bf(v1.x); pk.s[5]=f2bf(v1.y); pk.s[6]=f2bf(v1.z); pk.s[7]=f2bf(v1.w);
        *(bf16x8*)(As + srow*32 + sslot*8) = pk.v;
      }
    }
    // ---- stage B (W-form [N][K]) ----
    {
      int gn = n0 + srow, gk = k0 + skg*8;
      if (BBF){
        bf16x8 v = {};
        if (gn < N && gk < K) v = *(const bf16x8*)((const short*)Bp + (size_t)z*Bzs + (size_t)gn*ldb + gk);
        *(bf16x8*)(Bs + srow*32 + sslot*8) = v;
      } else {
        const float* Bf = (const float*)Bp + (size_t)z*Bzs;
        float4 v0 = {0,0,0,0}, v1 = {0,0,0,0};
        if (gn < N && gk < K){
          const float* p = Bf + (size_t)gn*ldb + gk;
          v0 = *(const float4*)p; v1 = *(const float4*)(p+4);
        }
        union { short s[8]; bf16x8 v; } pk;
        pk.s[0]=f2bf(v0.x); pk.s[1]=f2bf(v0.y); pk.s[2]=f2bf(v0.z); pk.s[3]=f2bf(v0.w);
        pk.s[4]=f2bf(v1.x); pk.s[5]=f2bf(v1.y); pk.s[6]=f2bf(v1.z); pk.s[7]=f2bf(v1.w);
        *(bf16x8*)(Bs + srow*32 + sslot*8) = pk.v;
      }
    }
    __syncthreads();
    bf16x8 af[2], bfr[2];
#pragma unroll
    for (int mi=0; mi<2; mi++){
      int row = wr + mi*16 + l15;
      af[mi] = *(const bf16x8*)(As + row*32 + ((lh ^ ((row>>1)&3))<<3));
    }
#pragma unroll
    for (int ni=0; ni<2; ni++){
      int col = wc + ni*16 + l15;
      bfr[ni] = *(const bf16x8*)(Bs + col*32 + ((lh ^ ((col>>1)&3))<<3));
    }
#pragma unroll
    for (int mi=0; mi<2; mi++)
#pragma unroll
      for (int ni=0; ni<2; ni++)
        acc[mi][ni] = __builtin_amdgcn_mfma_f32_16x16x32_bf16(af[mi], bfr[ni], acc[mi][ni], 0, 0, 0);
    __syncthreads();
  }
  // ---- epilogue ----
#pragma unroll
  for (int mi=0; mi<2; mi++){
#pragma unroll
    for (int ni=0; ni<2; ni++){
      int col = n0 + wc + ni*16 + l15;
      if (col >= N) continue;
#pragma unroll
      for (int j=0; j<4; j++){
        int row = m0 + wr + mi*16 + lh*4 + j;
        if (row >= M) continue;
        float v = acc[mi][ni][j];
        if (EPI == 0){ v *= alpha; }
        else if (EPI == 1){ v = v*alpha + aux[(size_t)row*ldaux + col]; }
        else if (EPI == 2){ v += aux[col]; v = fmaxf(v, 0.f); }
        else { v += aux[col]; v = copysignf(fmaxf(fabsf(v)-0.01f, 0.f), v); }
        Y[(size_t)row*ldo + col] = v;
      }
    }
  }
}

// ---------------- fp32 GEMM (dt_proj only): Y = softplus(X@W^T + bias) ----------------
#define GBM 64
#define GBN 64
#define GBK 16
__global__ __launch_bounds__(256) void k_gemm(
    const float* __restrict__ X, int lda,
    const float* __restrict__ W,
    const float* __restrict__ bias,
    float* __restrict__ Y,
    int M, int N, int K)
{
  __shared__ float As[GBK][GBM+4];
  __shared__ float Bs[GBK][GBN+4];
  int m0 = blockIdx.y*GBM, n0 = blockIdx.x*GBN;
  int tid = threadIdx.x;
  int ty = tid>>4, tx = tid&15;
  float acc[4][4] = {{0.f}};
  for (int k0=0;k0<K;k0+=GBK){
#pragma unroll
    for (int l=0;l<4;l++){
      int e = tid + 256*l;
      int m = e>>4, kk = e&15;
      int gm = m0+m, gk = k0+kk;
      As[kk][m] = (gm<M && gk<K) ? X[(size_t)gm*lda+gk] : 0.f;
      int gn = n0+m;
      Bs[kk][m] = (gn<N && gk<K) ? W[(size_t)gn*K+gk] : 0.f;
    }
    __syncthreads();
#pragma unroll
    for (int kk=0;kk<GBK;kk++){
      float4 av = *(const float4*)&As[kk][ty*4];
      float4 bv = *(const float4*)&Bs[kk][tx*4];
      float a[4]={av.x,av.y,av.z,av.w}, b[4]={bv.x,bv.y,bv.z,bv.w};
#pragma unroll
      for (int i=0;i<4;i++)
#pragma unroll
        for (int j=0;j<4;j++) acc[i][j] += a[i]*b[j];
    }
    __syncthreads();
  }
#pragma unroll
  for (int i=0;i<4;i++){
    int gm = m0+ty*4+i; if (gm>=M) continue;
#pragma unroll
    for (int j=0;j<4;j++){
      int gn = n0+tx*4+j; if (gn>=N) continue;
      float v = acc[i][j] + bias[gn];
      v = (v>20.f)? v : log1pf(expf(v));
      Y[(size_t)gm*N+gn] = v;
    }
  }
}

// ---------------- causal depthwise conv1d + silu ----------------
__global__ void k_conv(const float* __restrict__ xz, const float* __restrict__ cw,
                       const float* __restrict__ cb, float* __restrict__ xc){
  int idx = blockIdx.x*256 + threadIdx.x;
  if (idx >= ROWS*DI) return;
  int d = idx % DI;
  int r = idx / DI;
  int b = r / NN, l = r % NN;
  float acc = cb[d];
#pragma unroll
  for (int t=0;t<4;t++){
    int ls = l-3+t;
    if (ls>=0) acc += cw[d*4+t] * xz[((size_t)(b*NN+ls))*1536 + d];
  }
  xc[(size_t)r*DI + d] = acc / (1.f + expf(-acc)); // silu
}

// ---------------- chunked scan pass 1: per-chunk partial state + sum(dt) ----------------
// block = one (b,chunk) x 4 consecutive d; B-rows staged in LDS (shared by the 4 waves)
__global__ __launch_bounds__(256) void k_scan1(
    const float* __restrict__ dbl, const float* __restrict__ dtb,
    const float* __restrict__ xc, const float* __restrict__ A_log,
    short* __restrict__ hpart, float* __restrict__ sdt)
{
  __shared__ float Sb[LC*64];
  int gx = blockIdx.x;                 // 32 * 192
  int bc = gx & 31, dgrp = gx >> 5;
  int b = bc >> 4, c = bc & 15;
  int wv = threadIdx.x >> 6, lane = threadIdx.x & 63;
  int d = dgrp*4 + wv;
  int t0 = c*LC;
  const float* dbr = dbl + ((size_t)(b*NN+t0))*152 + DTR;
  for (int i = threadIdx.x; i < LC*64; i += 256){
    int r = i >> 6, col = i & 63;
    Sb[i] = dbr[(size_t)r*152 + col];
  }
  __syncthreads();
  float A = -__expf(A_log[d*DS + lane]);
  const float* dtp = dtb + ((size_t)(b*NN+t0))*DI + d;
  const float* up  = xc  + ((size_t)(b*NN+t0))*DI + d;
  float dt0v = (lane<LC) ? dtp[(size_t)lane*DI] : 0.f;
  float u0v  = (lane<LC) ? up[(size_t)lane*DI]  : 0.f;
  float h = 0.f;
  for (int t=0;t<LC;t++){
    float Bv = Sb[t*64 + lane];
    float dt = rdlane(dt0v, t);
    float u  = rdlane(u0v, t);
    h = h*__expf(dt*A) + (dt*u)*Bv;
  }
  int bd = b*DI + d;
  hpart[((size_t)bd*NC + c)*DS + lane] = f2bf(h);
  float s = dt0v;
#pragma unroll
  for (int o=32;o;o>>=1) s += __shfl_xor(s,o);
  if (lane==0) sdt[bd*NC + c] = s;
}

// ---------------- chunked scan pass 2: chunk-prefix (in place, bf16) ----------------
__global__ __launch_bounds__(256) void k_scan2(
    const float* __restrict__ sdt, const float* __restrict__ A_log,
    short* __restrict__ hpart)
{
  int wid = (blockIdx.x*256 + threadIdx.x) >> 6;
  int lane = threadIdx.x & 63;
  if (wid >= BB*DI) return;
  int d = wid % DI;
  float A = -__expf(A_log[d*DS + lane]);
  short* hp = hpart + (size_t)wid*NC*DS + lane;
  const float* sp = sdt + wid*NC;
  float h = 0.f;
  for (int c=0;c<NC;c++){
    float part = bf2f(hp[(size_t)c*DS]);
    float pA = __expf(A*sp[c]);
    hp[(size_t)c*DS] = f2bf(h);   // hin for chunk c
    h = h*pA + part;
  }
}

// ---------------- chunked scan pass 3: recompute with hin, emit gated y ----------------
__global__ __launch_bounds__(256) void k_scan3(
    const float* __restrict__ dbl, const float* __restrict__ dtb,
    const float* __restrict__ xc, const float* __restrict__ xz,
    const float* __restrict__ A_log, const float* __restrict__ Dp,
    const short* __restrict__ hin, float* __restrict__ y)
{
  __shared__ float S[LC*128];          // B|C rows, 25088B
  __shared__ float red[4][LC*17];      // 13328B
  int gx = blockIdx.x;
  int bc = gx & 31, dgrp = gx >> 5;
  int b = bc >> 4, c = bc & 15;
  int wv = threadIdx.x >> 6, lane = threadIdx.x & 63;
  int d = dgrp*4 + wv;
  int t0 = c*LC;
  const float* dbr = dbl + ((size_t)(b*NN+t0))*152 + DTR;
  for (int i = threadIdx.x; i < LC*128; i += 256){
    int r = i >> 7, col = i & 127;
    S[i] = dbr[(size_t)r*152 + col];
  }
  __syncthreads();
  float A = -__expf(A_log[d*DS + lane]);
  float Dv = Dp[d];
  const float* dtp = dtb + ((size_t)(b*NN+t0))*DI + d;
  const float* up  = xc  + ((size_t)(b*NN+t0))*DI + d;
  const float* zp  = xz  + ((size_t)(b*NN+t0))*1536 + DI + d;
  float* yp = y + ((size_t)(b*NN+t0))*DI + d;
  float dt0v = (lane<LC) ? dtp[(size_t)lane*DI]  : 0.f;
  float u0v  = (lane<LC) ? up[(size_t)lane*DI]   : 0.f;
  float z0v  = (lane<LC) ? zp[(size_t)lane*1536] : 0.f;
  int bd = b*DI + d;
  float h = bf2f(hin[((size_t)bd*NC + c)*DS + lane]);
  float* rw = red[wv];
  int g = lane>>2;
  bool gl = (lane&3)==0;
  for (int t=0;t<LC;t++){
    float Bv = S[t*128 + lane];
    float Cv = S[t*128 + 64 + lane];
    float dt = rdlane(dt0v, t);
    float u  = rdlane(u0v, t);
    h = h*__expf(dt*A) + (dt*u)*Bv;
    float p = h*Cv;
    p += __shfl_xor(p,1);
    p += __shfl_xor(p,2);
    if (gl) rw[t*17 + g] = p;
  }
  if (lane < LC){
    const float* rr = rw + lane*17;
    float a0 = rr[0]+rr[4]+rr[8] +rr[12];
    float a1 = rr[1]+rr[5]+rr[9] +rr[13];
    float a2 = rr[2]+rr[6]+rr[10]+rr[14];
    float a3 = rr[3]+rr[7]+rr[11]+rr[15];
    float yv = (a0+a1)+(a2+a3) + u0v*Dv;      // lane == t
    float z = z0v;
    yp[(size_t)lane*DI] = yv * (z/(1.f+__expf(-z)));
  }
}

// ---------------- twiddle tables (bf16, one sincos pass -> both layouts) ----------------
__global__ void k_tw(short* __restrict__ Wcat, short* __restrict__ WT){
  int idx = blockIdx.x*256+threadIdx.x;
  if (idx >= 784*1568) return;
  int n = idx / 1568, f = idx % 1568;
  int ff = (f<784)? f : f-784;
  int m = (int)(((long long)ff*(long long)n) % 784);
  float ang = 6.283185307179586f * (float)m / 784.f;
  float s, cval; sincosf(ang, &s, &cval);
  short v = f2bf((f<784)? cval : -s);
  WT[(size_t)n*1568 + f] = v;
  Wcat[(size_t)f*784 + n] = v;
}

// ---------------- build stacked real bf16 weights for both complex block layers ----------------
__global__ void k_prepw(const float* __restrict__ cw1, const float* __restrict__ cb1,
                        const float* __restrict__ cw2, const float* __restrict__ cb2,
                        short* __restrict__ W1, short* __restrict__ W2,
                        float* __restrict__ b1, float* __restrict__ b2){
  int idx = blockIdx.x*256+threadIdx.x;
  if (idx < 2*4*192*192){
    int l = idx / (4*192*192);
    int r = idx % (4*192*192);
    int d = r % 192; int j = (r/192) % 192; int bl = r/(192*192);
    int jj = j % 96, dd = d % 96;
    const float* cw = l ? cw2 : cw1;
    const float* w0 = cw + bl*9216;
    const float* w1 = cw + 4*9216 + bl*9216;
    float v;
    if (j < 96) v = (d < 96) ? w0[dd*96+jj] : -w1[dd*96+jj];
    else        v = (d < 96) ? w1[dd*96+jj] :  w0[dd*96+jj];
    (l ? W2 : W1)[r] = f2bf(v);
  }
  if (idx < 2*4*192){
    int l = idx / (4*192);
    int r = idx % (4*192);
    int j = r % 192; int bl = r/192;
    const float* cb = l ? cb2 : cb1;
    (l ? b2 : b1)[r] = (j<96) ? cb[bl*96 + j] : cb[384 + bl*96 + (j-96)];
  }
}

// ---------------- forward length-4 DFT along nb -> tcat[r][q*192 + {0:re,96:im} + k] ----------------
__global__ void k_cfft4(const float* __restrict__ Ybuf, float* __restrict__ tcat){
  int idx = blockIdx.x*256+threadIdx.x;
  if (idx >= BB*NN*96) return;
  int k = idx % 96; int r = idx / 96;
  int b = r / NN, f = r % NN;
  const float* fre = Ybuf + (size_t)b*602112 + (size_t)f*384;
  const float* fim = fre + 301056;
  float R0=fre[k], R1=fre[96+k], R2=fre[192+k], R3=fre[288+k];
  float I0=fim[k], I1=fim[96+k], I2=fim[192+k], I3=fim[288+k];
  float* tr = tcat + (size_t)r*768;
  tr[k]       = R0+R1+R2+R3;  tr[96+k]    = I0+I1+I2+I3;
  tr[192+k]   = R0+I1-R2-I3;  tr[192+96+k]= I0-R1-I2+R3;
  tr[384+k]   = R0-R1+R2-R3;  tr[384+96+k]= I0-I1+I2-I3;
  tr[576+k]   = R0-I1-R2+I3;  tr[576+96+k]= I0+R1-I2-R3;
}

// ---------------- inverse length-4 DFT -> YbufT[b][c][fcat] ----------------
__global__ void k_cifft4(const float* __restrict__ t2cat, float* __restrict__ YbufT){
  int idx = blockIdx.x*256+threadIdx.x;
  if (idx >= BB*NN*96) return;
  int f = idx % 784;
  int rest = idx / 784;
  int k = rest % 96;
  int b = rest / 96;
  const float* tr = t2cat + ((size_t)(b*NN+f))*768;
  float R0=tr[k],     I0=tr[96+k];
  float R1=tr[192+k], I1=tr[192+96+k];
  float R2=tr[384+k], I2=tr[384+96+k];
  float R3=tr[576+k], I3=tr[576+96+k];
  float* YT = YbufT + (size_t)b*602112;
  float gr[4], gi[4];
  gr[0]=R0+R1+R2+R3; gi[0]=I0+I1+I2+I3;
  gr[1]=R0-I1-R2+I3; gi[1]=I0+R1-I2-R3;
  gr[2]=R0-R1+R2-R3; gi[2]=I0-I1+I2-I3;
  gr[3]=R0+I1-R2-I3; gi[3]=I0-R1-I2+R3;
#pragma unroll
  for (int n=0;n<4;n++){
    int c = n*96 + k;
    YT[(size_t)c*1568 + f]       = gr[n];
    YT[(size_t)c*1568 + 784 + f] = gi[n];
  }
}

extern "C" void kernel_launch(void* const* d_in, const int* in_sizes, int n_in,
                              void* d_out, int out_size, void* d_ws, size_t ws_size,
                              hipStream_t stream){
  const float* x         = (const float*)d_in[0];
  const float* ln1_w     = (const float*)d_in[3];
  const float* ln1_b     = (const float*)d_in[4];
  const float* in_proj_w = (const float*)d_in[5];
  const float* conv_w    = (const float*)d_in[6];
  const float* conv_b    = (const float*)d_in[7];
  const float* x_proj_w  = (const float*)d_in[8];
  const float* dt_proj_w = (const float*)d_in[9];
  const float* dt_proj_b = (const float*)d_in[10];
  const float* A_log     = (const float*)d_in[11];
  const float* Dp        = (const float*)d_in[12];
  const float* out_proj_w= (const float*)d_in[13];
  const float* ln2_w     = (const float*)d_in[14];
  const float* ln2_b     = (const float*)d_in[15];
  const float* cw1       = (const float*)d_in[16];
  const float* cb1       = (const float*)d_in[17];
  const float* cw2       = (const float*)d_in[18];
  const float* cb2       = (const float*)d_in[19];

  float* ws = (float*)d_ws;
  // ---- phase A (mamba) ----
  float* ln   = ws;                  // [0, 602112)
  float* xz   = ws + 602112;         // [602112, 3010560)
  float* xc   = ws + 3010560;        // [3010560, 4214784)
  float* dbl  = ws + 4214784;        // [4214784, 4453120)
  float* dtb  = ws + 4453120;        // [4453120, 5657344)
  float* yb   = ws + 5657344;        // [5657344, 6861568)
  float* x1   = ws + 6861568;        // [6861568, 7463680)  persists to end
  short* hpart= (short*)(ws + 7463680); // bf16: 1572864 shorts = floats [7463680, 8250112)
  float* sdt  = ws + 8250112;        // [8250112, 8274688)
  // ---- phase B (einfft), overlaid on regions dead by launch order ----
  short* Wcat = (short*)(ws + 602112);   // 1229312 shorts -> floats [602112, 1216768)
  float* lnT  = ws + 1831424;            // [1831424, 2433536)
  float* Ybuf = ws + 2433536;            // [2433536, 3637760)
  short* WT   = (short*)(ws + 4453120);  // 1229312 shorts -> floats [4453120, 5067776) over dead dtb
  float* tcat = ws + 602112;             // [602112, 1806336)  over dead Wcat
  float* o1cat= ws + 1806336;            // [1806336, 3010560)
  float* t2cat= ws + 3010560;            // [3010560, 4214784)
  float* YbufT= ws + 602112;             // [602112, 1806336)  over dead tcat
  // FIXED layout (round-6 bug: these overlapped each other inside W1c):
  short* W1c  = (short*)(ws + 7463680);  // 147456 shorts -> floats [7463680, 7537408) over dead hpart
  short* W2c  = (short*)(ws + 7537408);  // 147456 shorts -> floats [7537408, 7611136)
  float* b1c  = ws + 7611136;            // [7611136, 7611904)
  float* b2c  = ws + 7611904;            // [7611904, 7612672)

  // ---- mamba path ----
  k_ln<<<ROWS,64,0,stream>>>(x, ln1_w, ln1_b, ln, ROWS);
  k_mgemm<0,0,0><<<dim3(24,25,1),256,0,stream>>>(ln,384,0, in_proj_w,384,0, nullptr,0,0,
                                                 xz,1536,0, ROWS,1536,384, 1.f);
  k_conv<<<(ROWS*DI+255)/256,256,0,stream>>>(xz,conv_w,conv_b,xc);
  k_mgemm<0,0,0><<<dim3(3,25,1),256,0,stream>>>(xc,768,0, x_proj_w,768,0, nullptr,0,0,
                                                dbl,152,0, ROWS,152,768, 1.f);
  k_gemm<<<dim3(12,25),256,0,stream>>>(dbl,152,dt_proj_w,dt_proj_b,dtb,ROWS,768,24);
  k_scan1<<<32*192,256,0,stream>>>(dbl,dtb,xc,A_log,hpart,sdt);
  k_scan2<<<(BB*DI)/4,256,0,stream>>>(sdt,A_log,hpart);
  k_scan3<<<32*192,256,0,stream>>>(dbl,dtb,xc,xz,A_log,Dp,hpart,yb);
  k_mgemm<1,0,0><<<dim3(6,25,1),256,0,stream>>>(yb,768,0, out_proj_w,768,0, x,384,0,
                                                x1,384,0, ROWS,384,768, 1.f);

  // ---- einfft path (prep after mamba: overlaid regions now dead) ----
  k_tw<<<(784*1568+255)/256,256,0,stream>>>(Wcat,WT);
  k_prepw<<<(2*4*192*192+255)/256,256,0,stream>>>(cw1,cb1,cw2,cb2,W1c,W2c,b1c,b2c);
  k_lnT<<<ROWS,64,0,stream>>>(x1, ln2_w, ln2_b, lnT);
  // forward DFT-784 (real input): Ybuf[fcat][c] = (1/56) * Wcat @ lnT^T
  k_mgemm<0,1,0><<<dim3(6,25,2),256,0,stream>>>(Wcat,784,0, lnT,784,301056, nullptr,0,0,
                                                Ybuf,384,602112, 1568,384,784, 1.f/56.f);
  // forward DFT-4 along nb -> tcat
  k_cfft4<<<(BB*NN*96+255)/256,256,0,stream>>>(Ybuf,tcat);
  // EinFFT layer 1 (relu)
  k_mgemm<2,0,1><<<dim3(3,25,4),256,0,stream>>>(tcat,768,192, W1c,192,36864, b1c,0,192,
                                                o1cat,768,192, ROWS,192,192, 1.f);
  // EinFFT layer 2 (soft shrink)
  k_mgemm<3,0,1><<<dim3(3,25,4),256,0,stream>>>(o1cat,768,192, W2c,192,36864, b2c,0,192,
                                                t2cat,768,192, ROWS,192,192, 1.f);
  // inverse DFT-4 -> YbufT[b][c][fcat]
  k_cifft4<<<(BB*NN*96+255)/256,256,0,stream>>>(t2cat,YbufT);
  // inverse DFT-784 + residual: out = x1 + (1/56) WT @ YbufT^T
  k_mgemm<1,1,0><<<dim3(6,13,2),256,0,stream>>>(WT,1568,0, YbufT,1568,602112, x1,384,301056,
                                                (float*)d_out,384,301056, 784,384,1568, 1.f/56.f);
}

// Round 8
// 318.917 us; speedup vs baseline: 5.3392x; 1.0256x over previous
//
#include <hip/hip_runtime.h>
#include <math.h>

#define BB 2
#define NN 784
#define CC 384
#define DI 768
#define DS 64
#define DTR 24
#define ROWS (BB*NN)   // 1568
#define NC 16
#define LC 49          // NC*LC == NN

typedef __attribute__((ext_vector_type(8))) short bf16x8;
typedef __attribute__((ext_vector_type(4))) float f32x4;

static __device__ inline short f2bf(float f){
  unsigned u = __float_as_uint(f);
  unsigned r = (u + 0x7fffu + ((u>>16)&1u)) >> 16;
  return (short)r;
}
static __device__ inline float bf2f(short v){
  return __uint_as_float(((unsigned)(unsigned short)v)<<16);
}
static __device__ inline float rdlane(float v, int t){
  return __uint_as_float(__builtin_amdgcn_readlane(__float_as_uint(v), t));
}

// ---------------- LayerNorm: one wave per row of 384 ----------------
__global__ void k_ln(const float* __restrict__ x, const float* __restrict__ w,
                     const float* __restrict__ b, float* __restrict__ out, int rows){
  int row = blockIdx.x;
  if (row >= rows) return;
  int lane = threadIdx.x; // blockDim = 64
  const float* xr = x + (size_t)row*CC;
  float v[6]; float s = 0.f;
#pragma unroll
  for (int i=0;i<6;i++){ v[i] = xr[lane + 64*i]; s += v[i]; }
#pragma unroll
  for (int o=32;o;o>>=1) s += __shfl_xor(s,o);
  float mu = s * (1.f/CC);
  float vs = 0.f;
#pragma unroll
  for (int i=0;i<6;i++){ float d=v[i]-mu; vs += d*d; }
#pragma unroll
  for (int o=32;o;o>>=1) vs += __shfl_xor(vs,o);
  float rstd = rsqrtf(vs*(1.f/CC) + 1e-5f);
  float* orow = out + (size_t)row*CC;
#pragma unroll
  for (int i=0;i<6;i++){ int c = lane+64*i; orow[c] = (v[i]-mu)*rstd*w[c] + b[c]; }
}

// ---------------- LayerNorm with transposed output: lnT[b][c][n] ----------------
__global__ void k_lnT(const float* __restrict__ x, const float* __restrict__ w,
                      const float* __restrict__ b, float* __restrict__ out){
  int row = blockIdx.x;      // b*784 + n
  if (row >= ROWS) return;
  int bb = row / NN, n = row % NN;
  int lane = threadIdx.x;
  const float* xr = x + (size_t)row*CC;
  float v[6]; float s = 0.f;
#pragma unroll
  for (int i=0;i<6;i++){ v[i] = xr[lane + 64*i]; s += v[i]; }
#pragma unroll
  for (int o=32;o;o>>=1) s += __shfl_xor(s,o);
  float mu = s * (1.f/CC);
  float vs = 0.f;
#pragma unroll
  for (int i=0;i<6;i++){ float d=v[i]-mu; vs += d*d; }
#pragma unroll
  for (int o=32;o;o>>=1) vs += __shfl_xor(vs,o);
  float rstd = rsqrtf(vs*(1.f/CC) + 1e-5f);
  float* ob = out + (size_t)bb*301056 + n;
#pragma unroll
  for (int i=0;i<6;i++){ int c = lane+64*i; ob[(size_t)c*NN] = (v[i]-mu)*rstd*w[c] + b[c]; }
}

// ---------------- bf16 MFMA GEMM: Y = alpha*(A[M,K] @ Bw[N,K]^T) + epi ----------------
// EPI 0: alpha*acc ; 1: alpha*acc + aux[row*ldaux+col] ; 2: relu(acc+aux[col]) ; 3: shrink(acc+aux[col],0.01)
// ABF/BBF: operand already bf16 (lda/ldb in elements of that type)
template<int EPI, int ABF, int BBF>
__global__ __launch_bounds__(256) void k_mgemm(
    const void* __restrict__ Ap, int lda, long long Azs,
    const void* __restrict__ Bp, int ldb, long long Bzs,
    const float* __restrict__ aux, int ldaux, long long auxzs,
    float* __restrict__ Y, int ldo, long long Ozs,
    int M, int N, int K, float alpha)
{
  __shared__ __align__(16) short As[64*32];
  __shared__ __align__(16) short Bs[64*32];
  int z = blockIdx.z;
  if (EPI != 0) aux += (size_t)z*auxzs;
  Y += (size_t)z*Ozs;
  int m0 = blockIdx.y*64, n0 = blockIdx.x*64;
  int t = threadIdx.x;
  int srow = t>>2, skg = t&3;                 // staging: row 0..63, k-group 0..3 (8 elems)
  int w = t>>6, lane = t&63;
  int wr = (w>>1)*32, wc = (w&1)*32;
  int l15 = lane&15, lh = lane>>4;
  f32x4 acc[2][2] = {};
  int sslot = skg ^ ((srow>>1)&3);
  for (int k0=0; k0<K; k0+=32){
    // ---- stage A ----
    {
      int gm = m0 + srow, gk = k0 + skg*8;
      if (ABF){
        bf16x8 v = {};
        if (gm < M && gk < K) v = *(const bf16x8*)((const short*)Ap + (size_t)z*Azs + (size_t)gm*lda + gk);
        *(bf16x8*)(As + srow*32 + sslot*8) = v;
      } else {
        const float* Af = (const float*)Ap + (size_t)z*Azs;
        float4 v0 = {0,0,0,0}, v1 = {0,0,0,0};
        if (gm < M && gk < K){
          const float* p = Af + (size_t)gm*lda + gk;
          v0 = *(const float4*)p; v1 = *(const float4*)(p+4);
        }
        union { short s[8]; bf16x8 v; } pk;
        pk.s[0]=f2bf(v0.x); pk.s[1]=f2bf(v0.y); pk.s[2]=f2bf(v0.z); pk.s[3]=f2bf(v0.w);
        pk.s[4]=f2bf(v1.x); pk.s[5]=f2bf(v1.y); pk.s[6]=f2bf(v1.z); pk.s[7]=f2bf(v1.w);
        *(bf16x8*)(As + srow*32 + sslot*8) = pk.v;
      }
    }
    // ---- stage B (W-form [N][K]) ----
    {
      int gn = n0 + srow, gk = k0 + skg*8;
      if (BBF){
        bf16x8 v = {};
        if (gn < N && gk < K) v = *(const bf16x8*)((const short*)Bp + (size_t)z*Bzs + (size_t)gn*ldb + gk);
        *(bf16x8*)(Bs + srow*32 + sslot*8) = v;
      } else {
        const float* Bf = (const float*)Bp + (size_t)z*Bzs;
        float4 v0 = {0,0,0,0}, v1 = {0,0,0,0};
        if (gn < N && gk < K){
          const float* p = Bf + (size_t)gn*ldb + gk;
          v0 = *(const float4*)p; v1 = *(const float4*)(p+4);
        }
        union { short s[8]; bf16x8 v; } pk;
        pk.s[0]=f2bf(v0.x); pk.s[1]=f2bf(v0.y); pk.s[2]=f2bf(v0.z); pk.s[3]=f2bf(v0.w);
        pk.s[4]=f2bf(v1.x); pk.s[5]=f2bf(v1.y); pk.s[6]=f2bf(v1.z); pk.s[7]=f2bf(v1.w);
        *(bf16x8*)(Bs + srow*32 + sslot*8) = pk.v;
      }
    }
    __syncthreads();
    bf16x8 af[2], bfr[2];
#pragma unroll
    for (int mi=0; mi<2; mi++){
      int row = wr + mi*16 + l15;
      af[mi] = *(const bf16x8*)(As + row*32 + ((lh ^ ((row>>1)&3))<<3));
    }
#pragma unroll
    for (int ni=0; ni<2; ni++){
      int col = wc + ni*16 + l15;
      bfr[ni] = *(const bf16x8*)(Bs + col*32 + ((lh ^ ((col>>1)&3))<<3));
    }
#pragma unroll
    for (int mi=0; mi<2; mi++)
#pragma unroll
      for (int ni=0; ni<2; ni++)
        acc[mi][ni] = __builtin_amdgcn_mfma_f32_16x16x32_bf16(af[mi], bfr[ni], acc[mi][ni], 0, 0, 0);
    __syncthreads();
  }
  // ---- epilogue ----
#pragma unroll
  for (int mi=0; mi<2; mi++){
#pragma unroll
    for (int ni=0; ni<2; ni++){
      int col = n0 + wc + ni*16 + l15;
      if (col >= N) continue;
#pragma unroll
      for (int j=0; j<4; j++){
        int row = m0 + wr + mi*16 + lh*4 + j;
        if (row >= M) continue;
        float v = acc[mi][ni][j];
        if (EPI == 0){ v *= alpha; }
        else if (EPI == 1){ v = v*alpha + aux[(size_t)row*ldaux + col]; }
        else if (EPI == 2){ v += aux[col]; v = fmaxf(v, 0.f); }
        else { v += aux[col]; v = copysignf(fmaxf(fabsf(v)-0.01f, 0.f), v); }
        Y[(size_t)row*ldo + col] = v;
      }
    }
  }
}

// ---------------- fp32 GEMM (dt_proj only): Y = softplus(X@W^T + bias) ----------------
#define GBM 64
#define GBN 64
#define GBK 16
__global__ __launch_bounds__(256) void k_gemm(
    const float* __restrict__ X, int lda,
    const float* __restrict__ W,
    const float* __restrict__ bias,
    float* __restrict__ Y,
    int M, int N, int K)
{
  __shared__ float As[GBK][GBM+4];
  __shared__ float Bs[GBK][GBN+4];
  int m0 = blockIdx.y*GBM, n0 = blockIdx.x*GBN;
  int tid = threadIdx.x;
  int ty = tid>>4, tx = tid&15;
  float acc[4][4] = {{0.f}};
  for (int k0=0;k0<K;k0+=GBK){
#pragma unroll
    for (int l=0;l<4;l++){
      int e = tid + 256*l;
      int m = e>>4, kk = e&15;
      int gm = m0+m, gk = k0+kk;
      As[kk][m] = (gm<M && gk<K) ? X[(size_t)gm*lda+gk] : 0.f;
      int gn = n0+m;
      Bs[kk][m] = (gn<N && gk<K) ? W[(size_t)gn*K+gk] : 0.f;
    }
    __syncthreads();
#pragma unroll
    for (int kk=0;kk<GBK;kk++){
      float4 av = *(const float4*)&As[kk][ty*4];
      float4 bv = *(const float4*)&Bs[kk][tx*4];
      float a[4]={av.x,av.y,av.z,av.w}, b[4]={bv.x,bv.y,bv.z,bv.w};
#pragma unroll
      for (int i=0;i<4;i++)
#pragma unroll
        for (int j=0;j<4;j++) acc[i][j] += a[i]*b[j];
    }
    __syncthreads();
  }
#pragma unroll
  for (int i=0;i<4;i++){
    int gm = m0+ty*4+i; if (gm>=M) continue;
#pragma unroll
    for (int j=0;j<4;j++){
      int gn = n0+tx*4+j; if (gn>=N) continue;
      float v = acc[i][j] + bias[gn];
      v = (v>20.f)? v : log1pf(expf(v));
      Y[(size_t)gm*N+gn] = v;
    }
  }
}

// ---------------- causal depthwise conv1d + silu ----------------
__global__ void k_conv(const float* __restrict__ xz, const float* __restrict__ cw,
                       const float* __restrict__ cb, float* __restrict__ xc){
  int idx = blockIdx.x*256 + threadIdx.x;
  if (idx >= ROWS*DI) return;
  int d = idx % DI;
  int r = idx / DI;
  int b = r / NN, l = r % NN;
  float acc = cb[d];
#pragma unroll
  for (int t=0;t<4;t++){
    int ls = l-3+t;
    if (ls>=0) acc += cw[d*4+t] * xz[((size_t)(b*NN+ls))*1536 + d];
  }
  xc[(size_t)r*DI + d] = acc / (1.f + expf(-acc)); // silu
}

// ---------------- chunked scan pass 1: per-chunk partial state + sum(dt) ----------------
// block = one (b,chunk) x 4 consecutive d; B-rows staged in LDS (shared by the 4 waves)
__global__ __launch_bounds__(256) void k_scan1(
    const float* __restrict__ dbl, const float* __restrict__ dtb,
    const float* __restrict__ xc, const float* __restrict__ A_log,
    short* __restrict__ hpart, float* __restrict__ sdt)
{
  __shared__ float Sb[LC*64];
  int gx = blockIdx.x;                 // 32 * 192
  int bc = gx & 31, dgrp = gx >> 5;
  int b = bc >> 4, c = bc & 15;
  int wv = threadIdx.x >> 6, lane = threadIdx.x & 63;
  int d = dgrp*4 + wv;
  int t0 = c*LC;
  const float* dbr = dbl + ((size_t)(b*NN+t0))*152 + DTR;
  for (int i = threadIdx.x; i < LC*64; i += 256){
    int r = i >> 6, col = i & 63;
    Sb[i] = dbr[(size_t)r*152 + col];
  }
  __syncthreads();
  float A = -__expf(A_log[d*DS + lane]);
  const float* dtp = dtb + ((size_t)(b*NN+t0))*DI + d;
  const float* up  = xc  + ((size_t)(b*NN+t0))*DI + d;
  float dt0v = (lane<LC) ? dtp[(size_t)lane*DI] : 0.f;
  float u0v  = (lane<LC) ? up[(size_t)lane*DI]  : 0.f;
  float h = 0.f;
#pragma unroll 7
  for (int t=0;t<LC;t++){
    float Bv = Sb[t*64 + lane];
    float dt = rdlane(dt0v, t);
    float u  = rdlane(u0v, t);
    h = h*__expf(dt*A) + (dt*u)*Bv;
  }
  int bd = b*DI + d;
  hpart[((size_t)bd*NC + c)*DS + lane] = f2bf(h);
  float s = dt0v;
#pragma unroll
  for (int o=32;o;o>>=1) s += __shfl_xor(s,o);
  if (lane==0) sdt[bd*NC + c] = s;
}

// ---------------- chunked scan pass 2: chunk-prefix (in place, bf16) ----------------
__global__ __launch_bounds__(256) void k_scan2(
    const float* __restrict__ sdt, const float* __restrict__ A_log,
    short* __restrict__ hpart)
{
  int wid = (blockIdx.x*256 + threadIdx.x) >> 6;
  int lane = threadIdx.x & 63;
  if (wid >= BB*DI) return;
  int d = wid % DI;
  float A = -__expf(A_log[d*DS + lane]);
  short* hp = hpart + (size_t)wid*NC*DS + lane;
  const float* sp = sdt + wid*NC;
  // independent loads first (all in flight), then the serial chain
  float part[NC], pA[NC];
#pragma unroll
  for (int c=0;c<NC;c++){ part[c] = bf2f(hp[(size_t)c*DS]); pA[c] = __expf(A*sp[c]); }
  float h = 0.f;
#pragma unroll
  for (int c=0;c<NC;c++){
    hp[(size_t)c*DS] = f2bf(h);   // hin for chunk c
    h = h*pA[c] + part[c];
  }
}

// ---------------- chunked scan pass 3: recompute with hin, emit gated y ----------------
__global__ __launch_bounds__(256) void k_scan3(
    const float* __restrict__ dbl, const float* __restrict__ dtb,
    const float* __restrict__ xc, const float* __restrict__ xz,
    const float* __restrict__ A_log, const float* __restrict__ Dp,
    const short* __restrict__ hin, float* __restrict__ y)
{
  __shared__ float S[LC*128];          // B|C rows, 25088B
  __shared__ float red[4][LC*17];      // 13328B
  int gx = blockIdx.x;
  int bc = gx & 31, dgrp = gx >> 5;
  int b = bc >> 4, c = bc & 15;
  int wv = threadIdx.x >> 6, lane = threadIdx.x & 63;
  int d = dgrp*4 + wv;
  int t0 = c*LC;
  const float* dbr = dbl + ((size_t)(b*NN+t0))*152 + DTR;
  for (int i = threadIdx.x; i < LC*128; i += 256){
    int r = i >> 7, col = i & 127;
    S[i] = dbr[(size_t)r*152 + col];
  }
  __syncthreads();
  float A = -__expf(A_log[d*DS + lane]);
  float Dv = Dp[d];
  const float* dtp = dtb + ((size_t)(b*NN+t0))*DI + d;
  const float* up  = xc  + ((size_t)(b*NN+t0))*DI + d;
  const float* zp  = xz  + ((size_t)(b*NN+t0))*1536 + DI + d;
  float* yp = y + ((size_t)(b*NN+t0))*DI + d;
  float dt0v = (lane<LC) ? dtp[(size_t)lane*DI]  : 0.f;
  float u0v  = (lane<LC) ? up[(size_t)lane*DI]   : 0.f;
  float z0v  = (lane<LC) ? zp[(size_t)lane*1536] : 0.f;
  int bd = b*DI + d;
  float h = bf2f(hin[((size_t)bd*NC + c)*DS + lane]);
  float* rw = red[wv];
  int g = lane>>2;
  bool gl = (lane&3)==0;
#pragma unroll 7
  for (int t=0;t<LC;t++){
    float Bv = S[t*128 + lane];
    float Cv = S[t*128 + 64 + lane];
    float dt = rdlane(dt0v, t);
    float u  = rdlane(u0v, t);
    h = h*__expf(dt*A) + (dt*u)*Bv;
    float p = h*Cv;
    p += __shfl_xor(p,1);
    p += __shfl_xor(p,2);
    if (gl) rw[t*17 + g] = p;
  }
  if (lane < LC){
    const float* rr = rw + lane*17;
    float a0 = rr[0]+rr[4]+rr[8] +rr[12];
    float a1 = rr[1]+rr[5]+rr[9] +rr[13];
    float a2 = rr[2]+rr[6]+rr[10]+rr[14];
    float a3 = rr[3]+rr[7]+rr[11]+rr[15];
    float yv = (a0+a1)+(a2+a3) + u0v*Dv;      // lane == t
    float z = z0v;
    yp[(size_t)lane*DI] = yv * (z/(1.f+__expf(-z)));
  }
}

// ---------------- twiddle tables (bf16, two coalesced passes) ----------------
__global__ void k_tw(short* __restrict__ Wcat, short* __restrict__ WT){
  int idx = blockIdx.x*256+threadIdx.x;
  if (idx >= 2*784*1568) return;
  if (idx < 784*1568){
    int n = idx / 1568, f = idx % 1568;       // f fastest -> WT store coalesced
    int ff = (f<784)? f : f-784;
    int m = (int)(((long long)ff*(long long)n) % 784);
    float ang = 6.283185307179586f * (float)m / 784.f;
    float s, cval; sincosf(ang, &s, &cval);
    WT[(size_t)n*1568 + f] = f2bf((f<784)? cval : -s);
  } else {
    int r = idx - 784*1568;
    int f = r / 784, n = r % 784;             // n fastest -> Wcat store coalesced
    int ff = (f<784)? f : f-784;
    int m = (int)(((long long)ff*(long long)n) % 784);
    float ang = 6.283185307179586f * (float)m / 784.f;
    float s, cval; sincosf(ang, &s, &cval);
    Wcat[(size_t)f*784 + n] = f2bf((f<784)? cval : -s);
  }
}

// ---------------- build stacked real bf16 weights for both complex block layers ----------------
__global__ void k_prepw(const float* __restrict__ cw1, const float* __restrict__ cb1,
                        const float* __restrict__ cw2, const float* __restrict__ cb2,
                        short* __restrict__ W1, short* __restrict__ W2,
                        float* __restrict__ b1, float* __restrict__ b2){
  int idx = blockIdx.x*256+threadIdx.x;
  if (idx < 2*4*192*192){
    int l = idx / (4*192*192);
    int r = idx % (4*192*192);
    int d = r % 192; int j = (r/192) % 192; int bl = r/(192*192);
    int jj = j % 96, dd = d % 96;
    const float* cw = l ? cw2 : cw1;
    const float* w0 = cw + bl*9216;
    const float* w1 = cw + 4*9216 + bl*9216;
    float v;
    if (j < 96) v = (d < 96) ? w0[dd*96+jj] : -w1[dd*96+jj];
    else        v = (d < 96) ? w1[dd*96+jj] :  w0[dd*96+jj];
    (l ? W2 : W1)[r] = f2bf(v);
  }
  if (idx < 2*4*192){
    int l = idx / (4*192);
    int r = idx % (4*192);
    int j = r % 192; int bl = r/192;
    const float* cb = l ? cb2 : cb1;
    (l ? b2 : b1)[r] = (j<96) ? cb[bl*96 + j] : cb[384 + bl*96 + (j-96)];
  }
}

// ---------------- forward length-4 DFT along nb -> tcat[r][q*192 + {0:re,96:im} + k] ----------------
__global__ void k_cfft4(const float* __restrict__ Ybuf, float* __restrict__ tcat){
  int idx = blockIdx.x*256+threadIdx.x;
  if (idx >= BB*NN*96) return;
  int k = idx % 96; int r = idx / 96;
  int b = r / NN, f = r % NN;
  const float* fre = Ybuf + (size_t)b*602112 + (size_t)f*384;
  const float* fim = fre + 301056;
  float R0=fre[k], R1=fre[96+k], R2=fre[192+k], R3=fre[288+k];
  float I0=fim[k], I1=fim[96+k], I2=fim[192+k], I3=fim[288+k];
  float* tr = tcat + (size_t)r*768;
  tr[k]       = R0+R1+R2+R3;  tr[96+k]    = I0+I1+I2+I3;
  tr[192+k]   = R0+I1-R2-I3;  tr[192+96+k]= I0-R1-I2+R3;
  tr[384+k]   = R0-R1+R2-R3;  tr[384+96+k]= I0-I1+I2-I3;
  tr[576+k]   = R0-I1-R2+I3;  tr[576+96+k]= I0+R1-I2-R3;
}

// ---------------- inverse length-4 DFT -> YbufT[b][c][fcat] ----------------
__global__ void k_cifft4(const float* __restrict__ t2cat, float* __restrict__ YbufT){
  int idx = blockIdx.x*256+threadIdx.x;
  if (idx >= BB*NN*96) return;
  int f = idx % 784;
  int rest = idx / 784;
  int k = rest % 96;
  int b = rest / 96;
  const float* tr = t2cat + ((size_t)(b*NN+f))*768;
  float R0=tr[k],     I0=tr[96+k];
  float R1=tr[192+k], I1=tr[192+96+k];
  float R2=tr[384+k], I2=tr[384+96+k];
  float R3=tr[576+k], I3=tr[576+96+k];
  float* YT = YbufT + (size_t)b*602112;
  float gr[4], gi[4];
  gr[0]=R0+R1+R2+R3; gi[0]=I0+I1+I2+I3;
  gr[1]=R0-I1-R2+I3; gi[1]=I0+R1-I2-R3;
  gr[2]=R0-R1+R2-R3; gi[2]=I0-I1+I2-I3;
  gr[3]=R0+I1-R2-I3; gi[3]=I0-R1-I2+R3;
#pragma unroll
  for (int n=0;n<4;n++){
    int c = n*96 + k;
    YT[(size_t)c*1568 + f]       = gr[n];
    YT[(size_t)c*1568 + 784 + f] = gi[n];
  }
}

extern "C" void kernel_launch(void* const* d_in, const int* in_sizes, int n_in,
                              void* d_out, int out_size, void* d_ws, size_t ws_size,
                              hipStream_t stream){
  const float* x         = (const float*)d_in[0];
  const float* ln1_w     = (const float*)d_in[3];
  const float* ln1_b     = (const float*)d_in[4];
  const float* in_proj_w = (const float*)d_in[5];
  const float* conv_w    = (const float*)d_in[6];
  const float* conv_b    = (const float*)d_in[7];
  const float* x_proj_w  = (const float*)d_in[8];
  const float* dt_proj_w = (const float*)d_in[9];
  const float* dt_proj_b = (const float*)d_in[10];
  const float* A_log     = (const float*)d_in[11];
  const float* Dp        = (const float*)d_in[12];
  const float* out_proj_w= (const float*)d_in[13];
  const float* ln2_w     = (const float*)d_in[14];
  const float* ln2_b     = (const float*)d_in[15];
  const float* cw1       = (const float*)d_in[16];
  const float* cb1       = (const float*)d_in[17];
  const float* cw2       = (const float*)d_in[18];
  const float* cb2       = (const float*)d_in[19];

  float* ws = (float*)d_ws;
  // ---- phase A (mamba) ----
  float* ln   = ws;                  // [0, 602112)
  float* xz   = ws + 602112;         // [602112, 3010560)
  float* xc   = ws + 3010560;        // [3010560, 4214784)
  float* dbl  = ws + 4214784;        // [4214784, 4453120)
  float* dtb  = ws + 4453120;        // [4453120, 5657344)
  float* yb   = ws + 5657344;        // [5657344, 6861568)
  float* x1   = ws + 6861568;        // [6861568, 7463680)  persists to end
  short* hpart= (short*)(ws + 7463680); // bf16: 1572864 shorts = floats [7463680, 8250112)
  float* sdt  = ws + 8250112;        // [8250112, 8274688)
  // ---- phase B (einfft), overlaid on regions dead by launch order ----
  short* Wcat = (short*)(ws + 602112);   // 1229312 shorts -> floats [602112, 1216768)
  float* lnT  = ws + 1831424;            // [1831424, 2433536)
  float* Ybuf = ws + 2433536;            // [2433536, 3637760)
  short* WT   = (short*)(ws + 4453120);  // 1229312 shorts -> floats [4453120, 5067776) over dead dtb
  float* tcat = ws + 602112;             // [602112, 1806336)  over dead Wcat
  float* o1cat= ws + 1806336;            // [1806336, 3010560)
  float* t2cat= ws + 3010560;            // [3010560, 4214784)
  float* YbufT= ws + 602112;             // [602112, 1806336)  over dead tcat
  short* W1c  = (short*)(ws + 7463680);  // 147456 shorts -> floats [7463680, 7537408) over dead hpart
  short* W2c  = (short*)(ws + 7537408);  // 147456 shorts -> floats [7537408, 7611136)
  float* b1c  = ws + 7611136;            // [7611136, 7611904)
  float* b2c  = ws + 7611904;            // [7611904, 7612672)

  // ---- mamba path ----
  k_ln<<<ROWS,64,0,stream>>>(x, ln1_w, ln1_b, ln, ROWS);
  k_mgemm<0,0,0><<<dim3(24,25,1),256,0,stream>>>(ln,384,0, in_proj_w,384,0, nullptr,0,0,
                                                 xz,1536,0, ROWS,1536,384, 1.f);
  k_conv<<<(ROWS*DI+255)/256,256,0,stream>>>(xz,conv_w,conv_b,xc);
  k_mgemm<0,0,0><<<dim3(3,25,1),256,0,stream>>>(xc,768,0, x_proj_w,768,0, nullptr,0,0,
                                                dbl,152,0, ROWS,152,768, 1.f);
  k_gemm<<<dim3(12,25),256,0,stream>>>(dbl,152,dt_proj_w,dt_proj_b,dtb,ROWS,768,24);
  k_scan1<<<32*192,256,0,stream>>>(dbl,dtb,xc,A_log,hpart,sdt);
  k_scan2<<<(BB*DI)/4,256,0,stream>>>(sdt,A_log,hpart);
  k_scan3<<<32*192,256,0,stream>>>(dbl,dtb,xc,xz,A_log,Dp,hpart,yb);
  k_mgemm<1,0,0><<<dim3(6,25,1),256,0,stream>>>(yb,768,0, out_proj_w,768,0, x,384,0,
                                                x1,384,0, ROWS,384,768, 1.f);

  // ---- einfft path (prep after mamba: overlaid regions now dead) ----
  k_tw<<<(2*784*1568+255)/256,256,0,stream>>>(Wcat,WT);
  k_prepw<<<(2*4*192*192+255)/256,256,0,stream>>>(cw1,cb1,cw2,cb2,W1c,W2c,b1c,b2c);
  k_lnT<<<ROWS,64,0,stream>>>(x1, ln2_w, ln2_b, lnT);
  // forward DFT-784 (real input): Ybuf[fcat][c] = (1/56) * Wcat @ lnT^T
  k_mgemm<0,1,0><<<dim3(6,25,2),256,0,stream>>>(Wcat,784,0, lnT,784,301056, nullptr,0,0,
                                                Ybuf,384,602112, 1568,384,784, 1.f/56.f);
  // forward DFT-4 along nb -> tcat
  k_cfft4<<<(BB*NN*96+255)/256,256,0,stream>>>(Ybuf,tcat);
  // EinFFT layer 1 (relu)
  k_mgemm<2,0,1><<<dim3(3,25,4),256,0,stream>>>(tcat,768,192, W1c,192,36864, b1c,0,192,
                                                o1cat,768,192, ROWS,192,192, 1.f);
  // EinFFT layer 2 (soft shrink)
  k_mgemm<3,0,1><<<dim3(3,25,4),256,0,stream>>>(o1cat,768,192, W2c,192,36864, b2c,0,192,
                                                t2cat,768,192, ROWS,192,192, 1.f);
  // inverse DFT-4 -> YbufT[b][c][fcat]
  k_cifft4<<<(BB*NN*96+255)/256,256,0,stream>>>(t2cat,YbufT);
  // inverse DFT-784 + residual: out = x1 + (1/56) WT @ YbufT^T
  k_mgemm<1,1,0><<<dim3(6,13,2),256,0,stream>>>(WT,1568,0, YbufT,1568,602112, x1,384,301056,
                                                (float*)d_out,384,301056, 784,384,1568, 1.f/56.f);
}

// Round 10
// 300.353 us; speedup vs baseline: 5.6692x; 1.0618x over previous
//
#include <hip/hip_runtime.h>
#include <math.h>

#define BB 2
#define NN 784
#define CC 384
#define DI 768
#define DS 64
#define DTR 24
#define ROWS (BB*NN)   // 1568
#define NC 16
#define LC 49          // NC*LC == NN

typedef __attribute__((ext_vector_type(8))) short bf16x8;
typedef __attribute__((ext_vector_type(4))) float f32x4;

static __device__ inline short f2bf(float f){
  unsigned u = __float_as_uint(f);
  unsigned r = (u + 0x7fffu + ((u>>16)&1u)) >> 16;
  return (short)r;
}
static __device__ inline float bf2f(short v){
  return __uint_as_float(((unsigned)(unsigned short)v)<<16);
}
static __device__ inline float rdlane(float v, int t){
  return __uint_as_float(__builtin_amdgcn_readlane(__float_as_uint(v), t));
}
// DPP quad-perm add: x + x[lane ^ k] within each 4-lane quad (VALU, no LDS traffic)
// CTRL must be a compile-time constant (template param) for the builtin.
template<int CTRL>
static __device__ inline float qp_add(float x){
  int t = __builtin_amdgcn_update_dpp(0, __float_as_int(x), CTRL, 0xf, 0xf, false);
  return x + __int_as_float(t);
}
#define QP_XOR1 0xB1   // quad_perm [1,0,3,2]
#define QP_XOR2 0x4E   // quad_perm [2,3,0,1]

// ---------------- LayerNorm: one wave per row of 384 ----------------
__global__ void k_ln(const float* __restrict__ x, const float* __restrict__ w,
                     const float* __restrict__ b, float* __restrict__ out, int rows){
  int row = blockIdx.x;
  if (row >= rows) return;
  int lane = threadIdx.x; // blockDim = 64
  const float* xr = x + (size_t)row*CC;
  float v[6]; float s = 0.f;
#pragma unroll
  for (int i=0;i<6;i++){ v[i] = xr[lane + 64*i]; s += v[i]; }
#pragma unroll
  for (int o=32;o;o>>=1) s += __shfl_xor(s,o);
  float mu = s * (1.f/CC);
  float vs = 0.f;
#pragma unroll
  for (int i=0;i<6;i++){ float d=v[i]-mu; vs += d*d; }
#pragma unroll
  for (int o=32;o;o>>=1) vs += __shfl_xor(vs,o);
  float rstd = rsqrtf(vs*(1.f/CC) + 1e-5f);
  float* orow = out + (size_t)row*CC;
#pragma unroll
  for (int i=0;i<6;i++){ int c = lane+64*i; orow[c] = (v[i]-mu)*rstd*w[c] + b[c]; }
}

// ---------------- LayerNorm with transposed output: lnT[b][c][n] ----------------
__global__ void k_lnT(const float* __restrict__ x, const float* __restrict__ w,
                      const float* __restrict__ b, float* __restrict__ out){
  int row = blockIdx.x;      // b*784 + n
  if (row >= ROWS) return;
  int bb = row / NN, n = row % NN;
  int lane = threadIdx.x;
  const float* xr = x + (size_t)row*CC;
  float v[6]; float s = 0.f;
#pragma unroll
  for (int i=0;i<6;i++){ v[i] = xr[lane + 64*i]; s += v[i]; }
#pragma unroll
  for (int o=32;o;o>>=1) s += __shfl_xor(s,o);
  float mu = s * (1.f/CC);
  float vs = 0.f;
#pragma unroll
  for (int i=0;i<6;i++){ float d=v[i]-mu; vs += d*d; }
#pragma unroll
  for (int o=32;o;o>>=1) vs += __shfl_xor(vs,o);
  float rstd = rsqrtf(vs*(1.f/CC) + 1e-5f);
  float* ob = out + (size_t)bb*301056 + n;
#pragma unroll
  for (int i=0;i<6;i++){ int c = lane+64*i; ob[(size_t)c*NN] = (v[i]-mu)*rstd*w[c] + b[c]; }
}

// ---------------- bf16 MFMA GEMM: Y = alpha*(A[M,K] @ Bw[N,K]^T) + epi ----------------
// EPI 0: alpha*acc ; 1: alpha*acc + aux[row*ldaux+col] ; 2: relu(acc+aux[col]) ; 3: shrink(acc+aux[col],0.01)
// ABF/BBF: operand already bf16 (lda/ldb in elements of that type)
template<int EPI, int ABF, int BBF>
__global__ __launch_bounds__(256) void k_mgemm(
    const void* __restrict__ Ap, int lda, long long Azs,
    const void* __restrict__ Bp, int ldb, long long Bzs,
    const float* __restrict__ aux, int ldaux, long long auxzs,
    float* __restrict__ Y, int ldo, long long Ozs,
    int M, int N, int K, float alpha)
{
  __shared__ __align__(16) short As[64*32];
  __shared__ __align__(16) short Bs[64*32];
  int z = blockIdx.z;
  if (EPI != 0) aux += (size_t)z*auxzs;
  Y += (size_t)z*Ozs;
  int m0 = blockIdx.y*64, n0 = blockIdx.x*64;
  int t = threadIdx.x;
  int srow = t>>2, skg = t&3;                 // staging: row 0..63, k-group 0..3 (8 elems)
  int w = t>>6, lane = t&63;
  int wr = (w>>1)*32, wc = (w&1)*32;
  int l15 = lane&15, lh = lane>>4;
  f32x4 acc[2][2] = {};
  int sslot = skg ^ ((srow>>1)&3);
  for (int k0=0; k0<K; k0+=32){
    // ---- stage A ----
    {
      int gm = m0 + srow, gk = k0 + skg*8;
      if (ABF){
        bf16x8 v = {};
        if (gm < M && gk < K) v = *(const bf16x8*)((const short*)Ap + (size_t)z*Azs + (size_t)gm*lda + gk);
        *(bf16x8*)(As + srow*32 + sslot*8) = v;
      } else {
        const float* Af = (const float*)Ap + (size_t)z*Azs;
        float4 v0 = {0,0,0,0}, v1 = {0,0,0,0};
        if (gm < M && gk < K){
          const float* p = Af + (size_t)gm*lda + gk;
          v0 = *(const float4*)p; v1 = *(const float4*)(p+4);
        }
        union { short s[8]; bf16x8 v; } pk;
        pk.s[0]=f2bf(v0.x); pk.s[1]=f2bf(v0.y); pk.s[2]=f2bf(v0.z); pk.s[3]=f2bf(v0.w);
        pk.s[4]=f2bf(v1.x); pk.s[5]=f2bf(v1.y); pk.s[6]=f2bf(v1.z); pk.s[7]=f2bf(v1.w);
        *(bf16x8*)(As + srow*32 + sslot*8) = pk.v;
      }
    }
    // ---- stage B (W-form [N][K]) ----
    {
      int gn = n0 + srow, gk = k0 + skg*8;
      if (BBF){
        bf16x8 v = {};
        if (gn < N && gk < K) v = *(const bf16x8*)((const short*)Bp + (size_t)z*Bzs + (size_t)gn*ldb + gk);
        *(bf16x8*)(Bs + srow*32 + sslot*8) = v;
      } else {
        const float* Bf = (const float*)Bp + (size_t)z*Bzs;
        float4 v0 = {0,0,0,0}, v1 = {0,0,0,0};
        if (gn < N && gk < K){
          const float* p = Bf + (size_t)gn*ldb + gk;
          v0 = *(const float4*)p; v1 = *(const float4*)(p+4);
        }
        union { short s[8]; bf16x8 v; } pk;
        pk.s[0]=f2bf(v0.x); pk.s[1]=f2bf(v0.y); pk.s[2]=f2bf(v0.z); pk.s[3]=f2bf(v0.w);
        pk.s[4]=f2bf(v1.x); pk.s[5]=f2bf(v1.y); pk.s[6]=f2bf(v1.z); pk.s[7]=f2bf(v1.w);
        *(bf16x8*)(Bs + srow*32 + sslot*8) = pk.v;
      }
    }
    __syncthreads();
    bf16x8 af[2], bfr[2];
#pragma unroll
    for (int mi=0; mi<2; mi++){
      int row = wr + mi*16 + l15;
      af[mi] = *(const bf16x8*)(As + row*32 + ((lh ^ ((row>>1)&3))<<3));
    }
#pragma unroll
    for (int ni=0; ni<2; ni++){
      int col = wc + ni*16 + l15;
      bfr[ni] = *(const bf16x8*)(Bs + col*32 + ((lh ^ ((col>>1)&3))<<3));
    }
#pragma unroll
    for (int mi=0; mi<2; mi++)
#pragma unroll
      for (int ni=0; ni<2; ni++)
        acc[mi][ni] = __builtin_amdgcn_mfma_f32_16x16x32_bf16(af[mi], bfr[ni], acc[mi][ni], 0, 0, 0);
    __syncthreads();
  }
  // ---- epilogue ----
#pragma unroll
  for (int mi=0; mi<2; mi++){
#pragma unroll
    for (int ni=0; ni<2; ni++){
      int col = n0 + wc + ni*16 + l15;
      if (col >= N) continue;
#pragma unroll
      for (int j=0; j<4; j++){
        int row = m0 + wr + mi*16 + lh*4 + j;
        if (row >= M) continue;
        float v = acc[mi][ni][j];
        if (EPI == 0){ v *= alpha; }
        else if (EPI == 1){ v = v*alpha + aux[(size_t)row*ldaux + col]; }
        else if (EPI == 2){ v += aux[col]; v = fmaxf(v, 0.f); }
        else { v += aux[col]; v = copysignf(fmaxf(fabsf(v)-0.01f, 0.f), v); }
        Y[(size_t)row*ldo + col] = v;
      }
    }
  }
}

// ---------------- fp32 GEMM (dt_proj only): Y = softplus(X@W^T + bias) ----------------
#define GBM 64
#define GBN 64
#define GBK 16
__global__ __launch_bounds__(256) void k_gemm(
    const float* __restrict__ X, int lda,
    const float* __restrict__ W,
    const float* __restrict__ bias,
    float* __restrict__ Y,
    int M, int N, int K)
{
  __shared__ float As[GBK][GBM+4];
  __shared__ float Bs[GBK][GBN+4];
  int m0 = blockIdx.y*GBM, n0 = blockIdx.x*GBN;
  int tid = threadIdx.x;
  int ty = tid>>4, tx = tid&15;
  float acc[4][4] = {{0.f}};
  for (int k0=0;k0<K;k0+=GBK){
#pragma unroll
    for (int l=0;l<4;l++){
      int e = tid + 256*l;
      int m = e>>4, kk = e&15;
      int gm = m0+m, gk = k0+kk;
      As[kk][m] = (gm<M && gk<K) ? X[(size_t)gm*lda+gk] : 0.f;
      int gn = n0+m;
      Bs[kk][m] = (gn<N && gk<K) ? W[(size_t)gn*K+gk] : 0.f;
    }
    __syncthreads();
#pragma unroll
    for (int kk=0;kk<GBK;kk++){
      float4 av = *(const float4*)&As[kk][ty*4];
      float4 bv = *(const float4*)&Bs[kk][tx*4];
      float a[4]={av.x,av.y,av.z,av.w}, b[4]={bv.x,bv.y,bv.z,bv.w};
#pragma unroll
      for (int i=0;i<4;i++)
#pragma unroll
        for (int j=0;j<4;j++) acc[i][j] += a[i]*b[j];
    }
    __syncthreads();
  }
#pragma unroll
  for (int i=0;i<4;i++){
    int gm = m0+ty*4+i; if (gm>=M) continue;
#pragma unroll
    for (int j=0;j<4;j++){
      int gn = n0+tx*4+j; if (gn>=N) continue;
      float v = acc[i][j] + bias[gn];
      v = (v>20.f)? v : log1pf(expf(v));
      Y[(size_t)gm*N+gn] = v;
    }
  }
}

// ---------------- causal depthwise conv1d + silu ----------------
__global__ void k_conv(const float* __restrict__ xz, const float* __restrict__ cw,
                       const float* __restrict__ cb, float* __restrict__ xc){
  int idx = blockIdx.x*256 + threadIdx.x;
  if (idx >= ROWS*DI) return;
  int d = idx % DI;
  int r = idx / DI;
  int b = r / NN, l = r % NN;
  float acc = cb[d];
#pragma unroll
  for (int t=0;t<4;t++){
    int ls = l-3+t;
    if (ls>=0) acc += cw[d*4+t] * xz[((size_t)(b*NN+ls))*1536 + d];
  }
  xc[(size_t)r*DI + d] = acc / (1.f + expf(-acc)); // silu
}

// ---------------- chunked scan pass 1: per-chunk partial state + sum(dt) ----------------
// block = one (b,chunk) x 4 consecutive d; B-rows staged in LDS (shared by the 4 waves)
__global__ __launch_bounds__(256) void k_scan1(
    const float* __restrict__ dbl, const float* __restrict__ dtb,
    const float* __restrict__ xc, const float* __restrict__ A_log,
    short* __restrict__ hpart, float* __restrict__ sdt)
{
  __shared__ float Sb[LC*64];
  int gx = blockIdx.x;                 // 32 * 192
  int bc = gx & 31, dgrp = gx >> 5;
  int b = bc >> 4, c = bc & 15;
  int wv = threadIdx.x >> 6, lane = threadIdx.x & 63;
  int d = dgrp*4 + wv;
  int t0 = c*LC;
  const float* dbr = dbl + ((size_t)(b*NN+t0))*152 + DTR;
  for (int i = threadIdx.x; i < LC*64; i += 256){
    int r = i >> 6, col = i & 63;
    Sb[i] = dbr[(size_t)r*152 + col];
  }
  __syncthreads();
  float A = -__expf(A_log[d*DS + lane]);
  const float* dtp = dtb + ((size_t)(b*NN+t0))*DI + d;
  const float* up  = xc  + ((size_t)(b*NN+t0))*DI + d;
  float dt0v = (lane<LC) ? dtp[(size_t)lane*DI] : 0.f;
  float u0v  = (lane<LC) ? up[(size_t)lane*DI]  : 0.f;
  float h = 0.f;
  for (int tb=0; tb<LC; tb+=7){
    float e[7], f[7];
#pragma unroll
    for (int j=0;j<7;j++){
      int t = tb+j;
      float dt = rdlane(dt0v, t);
      float u  = rdlane(u0v, t);
      e[j] = __expf(dt*A);
      f[j] = (dt*u)*Sb[t*64 + lane];
    }
#pragma unroll
    for (int j=0;j<7;j++) h = h*e[j] + f[j];
  }
  int bd = b*DI + d;
  hpart[((size_t)bd*NC + c)*DS + lane] = f2bf(h);
  float s = dt0v;
#pragma unroll
  for (int o=32;o;o>>=1) s += __shfl_xor(s,o);
  if (lane==0) sdt[bd*NC + c] = s;
}

// ---------------- chunked scan pass 2: chunk-prefix (in place, bf16) ----------------
__global__ __launch_bounds__(256) void k_scan2(
    const float* __restrict__ sdt, const float* __restrict__ A_log,
    short* __restrict__ hpart)
{
  int wid = (blockIdx.x*256 + threadIdx.x) >> 6;
  int lane = threadIdx.x & 63;
  if (wid >= BB*DI) return;
  int d = wid % DI;
  float A = -__expf(A_log[d*DS + lane]);
  short* hp = hpart + (size_t)wid*NC*DS + lane;
  const float* sp = sdt + wid*NC;
  // independent loads first (all in flight), then the serial chain
  float part[NC], pA[NC];
#pragma unroll
  for (int c=0;c<NC;c++){ part[c] = bf2f(hp[(size_t)c*DS]); pA[c] = __expf(A*sp[c]); }
  float h = 0.f;
#pragma unroll
  for (int c=0;c<NC;c++){
    hp[(size_t)c*DS] = f2bf(h);   // hin for chunk c
    h = h*pA[c] + part[c];
  }
}

// ---------------- chunked scan pass 3: recompute with hin, emit gated y ----------------
// S interleaved {B,C} per (t,lane): one ds_read_b64/step. Reduce: 2 DPP quad adds (VALU)
// + 1 conditional LDS write; batched gather at end.
__global__ __launch_bounds__(256) void k_scan3(
    const float* __restrict__ dbl, const float* __restrict__ dtb,
    const float* __restrict__ xc, const float* __restrict__ xz,
    const float* __restrict__ A_log, const float* __restrict__ Dp,
    const short* __restrict__ hin, float* __restrict__ y)
{
  __shared__ float S[LC*128];          // interleaved {B,C}: S[t*128 + lane*2 + {0,1}]
  __shared__ float red[4][LC*17];      // 13328B
  int gx = blockIdx.x;
  int bc = gx & 31, dgrp = gx >> 5;
  int b = bc >> 4, c = bc & 15;
  int wv = threadIdx.x >> 6, lane = threadIdx.x & 63;
  int d = dgrp*4 + wv;
  int t0 = c*LC;
  const float* dbr = dbl + ((size_t)(b*NN+t0))*152 + DTR;
  for (int i = threadIdx.x; i < LC*128; i += 256){
    int r = i >> 7, col = i & 127;          // col 0..63 = B[lane], 64..127 = C[lane]
    int ln = col & 63, which = col >> 6;
    S[r*128 + ln*2 + which] = dbr[(size_t)r*152 + col];
  }
  __syncthreads();
  float A = -__expf(A_log[d*DS + lane]);
  float Dv = Dp[d];
  const float* dtp = dtb + ((size_t)(b*NN+t0))*DI + d;
  const float* up  = xc  + ((size_t)(b*NN+t0))*DI + d;
  const float* zp  = xz  + ((size_t)(b*NN+t0))*1536 + DI + d;
  float* yp = y + ((size_t)(b*NN+t0))*DI + d;
  float dt0v = (lane<LC) ? dtp[(size_t)lane*DI]  : 0.f;
  float u0v  = (lane<LC) ? up[(size_t)lane*DI]   : 0.f;
  float z0v  = (lane<LC) ? zp[(size_t)lane*1536] : 0.f;
  int bd = b*DI + d;
  float h = bf2f(hin[((size_t)bd*NC + c)*DS + lane]);
  float* rw = red[wv];
  int g = lane>>2;
  bool gl = (lane&3)==0;
  for (int tb=0; tb<LC; tb+=7){
    float e[7], f[7], Cv[7];
#pragma unroll
    for (int j=0;j<7;j++){
      int t = tb+j;
      float2 bcv = *(const float2*)&S[t*128 + lane*2];
      float dt = rdlane(dt0v, t);
      float u  = rdlane(u0v, t);
      e[j]  = __expf(dt*A);
      f[j]  = (dt*u)*bcv.x;
      Cv[j] = bcv.y;
    }
#pragma unroll
    for (int j=0;j<7;j++){
      h = h*e[j] + f[j];
      float p = h*Cv[j];
      p = qp_add<QP_XOR1>(p);
      p = qp_add<QP_XOR2>(p);
      if (gl) rw[(tb+j)*17 + g] = p;
    }
  }
  if (lane < LC){
    const float* rr = rw + lane*17;
    float a0 = rr[0]+rr[4]+rr[8] +rr[12];
    float a1 = rr[1]+rr[5]+rr[9] +rr[13];
    float a2 = rr[2]+rr[6]+rr[10]+rr[14];
    float a3 = rr[3]+rr[7]+rr[11]+rr[15];
    float yv = (a0+a1)+(a2+a3) + u0v*Dv;      // lane == t
    float z = z0v;
    yp[(size_t)lane*DI] = yv * (z/(1.f+__expf(-z)));
  }
}

// ---------------- twiddle tables (bf16, two coalesced passes) ----------------
__global__ void k_tw(short* __restrict__ Wcat, short* __restrict__ WT){
  int idx = blockIdx.x*256+threadIdx.x;
  if (idx >= 2*784*1568) return;
  if (idx < 784*1568){
    int n = idx / 1568, f = idx % 1568;       // f fastest -> WT store coalesced
    int ff = (f<784)? f : f-784;
    int m = (int)(((long long)ff*(long long)n) % 784);
    float ang = 6.283185307179586f * (float)m / 784.f;
    float s, cval; sincosf(ang, &s, &cval);
    WT[(size_t)n*1568 + f] = f2bf((f<784)? cval : -s);
  } else {
    int r = idx - 784*1568;
    int f = r / 784, n = r % 784;             // n fastest -> Wcat store coalesced
    int ff = (f<784)? f : f-784;
    int m = (int)(((long long)ff*(long long)n) % 784);
    float ang = 6.283185307179586f * (float)m / 784.f;
    float s, cval; sincosf(ang, &s, &cval);
    Wcat[(size_t)f*784 + n] = f2bf((f<784)? cval : -s);
  }
}

// ---------------- build stacked real bf16 weights for both complex block layers ----------------
__global__ void k_prepw(const float* __restrict__ cw1, const float* __restrict__ cb1,
                        const float* __restrict__ cw2, const float* __restrict__ cb2,
                        short* __restrict__ W1, short* __restrict__ W2,
                        float* __restrict__ b1, float* __restrict__ b2){
  int idx = blockIdx.x*256+threadIdx.x;
  if (idx < 2*4*192*192){
    int l = idx / (4*192*192);
    int r = idx % (4*192*192);
    int d = r % 192; int j = (r/192) % 192; int bl = r/(192*192);
    int jj = j % 96, dd = d % 96;
    const float* cw = l ? cw2 : cw1;
    const float* w0 = cw + bl*9216;
    const float* w1 = cw + 4*9216 + bl*9216;
    float v;
    if (j < 96) v = (d < 96) ? w0[dd*96+jj] : -w1[dd*96+jj];
    else        v = (d < 96) ? w1[dd*96+jj] :  w0[dd*96+jj];
    (l ? W2 : W1)[r] = f2bf(v);
  }
  if (idx < 2*4*192){
    int l = idx / (4*192);
    int r = idx % (4*192);
    int j = r % 192; int bl = r/192;
    const float* cb = l ? cb2 : cb1;
    (l ? b2 : b1)[r] = (j<96) ? cb[bl*96 + j] : cb[384 + bl*96 + (j-96)];
  }
}

// ---------------- forward length-4 DFT along nb -> tcat[r][q*192 + {0:re,96:im} + k] ----------------
__global__ void k_cfft4(const float* __restrict__ Ybuf, float* __restrict__ tcat){
  int idx = blockIdx.x*256+threadIdx.x;
  if (idx >= BB*NN*96) return;
  int k = idx % 96; int r = idx / 96;
  int b = r / NN, f = r % NN;
  const float* fre = Ybuf + (size_t)b*602112 + (size_t)f*384;
  const float* fim = fre + 301056;
  float R0=fre[k], R1=fre[96+k], R2=fre[192+k], R3=fre[288+k];
  float I0=fim[k], I1=fim[96+k], I2=fim[192+k], I3=fim[288+k];
  float* tr = tcat + (size_t)r*768;
  tr[k]       = R0+R1+R2+R3;  tr[96+k]    = I0+I1+I2+I3;
  tr[192+k]   = R0+I1-R2-I3;  tr[192+96+k]= I0-R1-I2+R3;
  tr[384+k]   = R0-R1+R2-R3;  tr[384+96+k]= I0-I1+I2-I3;
  tr[576+k]   = R0-I1-R2+I3;  tr[576+96+k]= I0+R1-I2-R3;
}

// ---------------- inverse length-4 DFT -> YbufT[b][c][fcat] ----------------
__global__ void k_cifft4(const float* __restrict__ t2cat, float* __restrict__ YbufT){
  int idx = blockIdx.x*256+threadIdx.x;
  if (idx >= BB*NN*96) return;
  int f = idx % 784;
  int rest = idx / 784;
  int k = rest % 96;
  int b = rest / 96;
  const float* tr = t2cat + ((size_t)(b*NN+f))*768;
  float R0=tr[k],     I0=tr[96+k];
  float R1=tr[192+k], I1=tr[192+96+k];
  float R2=tr[384+k], I2=tr[384+96+k];
  float R3=tr[576+k], I3=tr[576+96+k];
  float* YT = YbufT + (size_t)b*602112;
  float gr[4], gi[4];
  gr[0]=R0+R1+R2+R3; gi[0]=I0+I1+I2+I3;
  gr[1]=R0-I1-R2+I3; gi[1]=I0+R1-I2-R3;
  gr[2]=R0-R1+R2-R3; gi[2]=I0-I1+I2-I3;
  gr[3]=R0+I1-R2-I3; gi[3]=I0-R1-I2+R3;
#pragma unroll
  for (int n=0;n<4;n++){
    int c = n*96 + k;
    YT[(size_t)c*1568 + f]       = gr[n];
    YT[(size_t)c*1568 + 784 + f] = gi[n];
  }
}

extern "C" void kernel_launch(void* const* d_in, const int* in_sizes, int n_in,
                              void* d_out, int out_size, void* d_ws, size_t ws_size,
                              hipStream_t stream){
  const float* x         = (const float*)d_in[0];
  const float* ln1_w     = (const float*)d_in[3];
  const float* ln1_b     = (const float*)d_in[4];
  const float* in_proj_w = (const float*)d_in[5];
  const float* conv_w    = (const float*)d_in[6];
  const float* conv_b    = (const float*)d_in[7];
  const float* x_proj_w  = (const float*)d_in[8];
  const float* dt_proj_w = (const float*)d_in[9];
  const float* dt_proj_b = (const float*)d_in[10];
  const float* A_log     = (const float*)d_in[11];
  const float* Dp        = (const float*)d_in[12];
  const float* out_proj_w= (const float*)d_in[13];
  const float* ln2_w     = (const float*)d_in[14];
  const float* ln2_b     = (const float*)d_in[15];
  const float* cw1       = (const float*)d_in[16];
  const float* cb1       = (const float*)d_in[17];
  const float* cw2       = (const float*)d_in[18];
  const float* cb2       = (const float*)d_in[19];

  float* ws = (float*)d_ws;
  // ---- phase A (mamba) ----
  float* ln   = ws;                  // [0, 602112)
  float* xz   = ws + 602112;         // [602112, 3010560)
  float* xc   = ws + 3010560;        // [3010560, 4214784)
  float* dbl  = ws + 4214784;        // [4214784, 4453120)
  float* dtb  = ws + 4453120;        // [4453120, 5657344)
  float* yb   = ws + 5657344;        // [5657344, 6861568)
  float* x1   = ws + 6861568;        // [6861568, 7463680)  persists to end
  short* hpart= (short*)(ws + 7463680); // bf16: 1572864 shorts = floats [7463680, 8250112)
  float* sdt  = ws + 8250112;        // [8250112, 8274688)
  // ---- phase B (einfft), overlaid on regions dead by launch order ----
  short* Wcat = (short*)(ws + 602112);   // 1229312 shorts -> floats [602112, 1216768)
  float* lnT  = ws + 1831424;            // [1831424, 2433536)
  float* Ybuf = ws + 2433536;            // [2433536, 3637760)
  short* WT   = (short*)(ws + 4453120);  // 1229312 shorts -> floats [4453120, 5067776) over dead dtb
  float* tcat = ws + 602112;             // [602112, 1806336)  over dead Wcat
  float* o1cat= ws + 1806336;            // [1806336, 3010560)
  float* t2cat= ws + 3010560;            // [3010560, 4214784)
  float* YbufT= ws + 602112;             // [602112, 1806336)  over dead tcat
  short* W1c  = (short*)(ws + 7463680);  // 147456 shorts -> floats [7463680, 7537408) over dead hpart
  short* W2c  = (short*)(ws + 7537408);  // 147456 shorts -> floats [7537408, 7611136)
  float* b1c  = ws + 7611136;            // [7611136, 7611904)
  float* b2c  = ws + 7611904;            // [7611904, 7612672)

  // ---- mamba path ----
  k_ln<<<ROWS,64,0,stream>>>(x, ln1_w, ln1_b, ln, ROWS);
  k_mgemm<0,0,0><<<dim3(24,25,1),256,0,stream>>>(ln,384,0, in_proj_w,384,0, nullptr,0,0,
                                                 xz,1536,0, ROWS,1536,384, 1.f);
  k_conv<<<(ROWS*DI+255)/256,256,0,stream>>>(xz,conv_w,conv_b,xc);
  k_mgemm<0,0,0><<<dim3(3,25,1),256,0,stream>>>(xc,768,0, x_proj_w,768,0, nullptr,0,0,
                                                dbl,152,0, ROWS,152,768, 1.f);
  k_gemm<<<dim3(12,25),256,0,stream>>>(dbl,152,dt_proj_w,dt_proj_b,dtb,ROWS,768,24);
  k_scan1<<<32*192,256,0,stream>>>(dbl,dtb,xc,A_log,hpart,sdt);
  k_scan2<<<(BB*DI)/4,256,0,stream>>>(sdt,A_log,hpart);
  k_scan3<<<32*192,256,0,stream>>>(dbl,dtb,xc,xz,A_log,Dp,hpart,yb);
  k_mgemm<1,0,0><<<dim3(6,25,1),256,0,stream>>>(yb,768,0, out_proj_w,768,0, x,384,0,
                                                x1,384,0, ROWS,384,768, 1.f);

  // ---- einfft path (prep after mamba: overlaid regions now dead) ----
  k_tw<<<(2*784*1568+255)/256,256,0,stream>>>(Wcat,WT);
  k_prepw<<<(2*4*192*192+255)/256,256,0,stream>>>(cw1,cb1,cw2,cb2,W1c,W2c,b1c,b2c);
  k_lnT<<<ROWS,64,0,stream>>>(x1, ln2_w, ln2_b, lnT);
  // forward DFT-784 (real input): Ybuf[fcat][c] = (1/56) * Wcat @ lnT^T
  k_mgemm<0,1,0><<<dim3(6,25,2),256,0,stream>>>(Wcat,784,0, lnT,784,301056, nullptr,0,0,
                                                Ybuf,384,602112, 1568,384,784, 1.f/56.f);
  // forward DFT-4 along nb -> tcat
  k_cfft4<<<(BB*NN*96+255)/256,256,0,stream>>>(Ybuf,tcat);
  // EinFFT layer 1 (relu)
  k_mgemm<2,0,1><<<dim3(3,25,4),256,0,stream>>>(tcat,768,192, W1c,192,36864, b1c,0,192,
                                                o1cat,768,192, ROWS,192,192, 1.f);
  // EinFFT layer 2 (soft shrink)
  k_mgemm<3,0,1><<<dim3(3,25,4),256,0,stream>>>(o1cat,768,192, W2c,192,36864, b2c,0,192,
                                                t2cat,768,192, ROWS,192,192, 1.f);
  // inverse DFT-4 -> YbufT[b][c][fcat]
  k_cifft4<<<(BB*NN*96+255)/256,256,0,stream>>>(t2cat,YbufT);
  // inverse DFT-784 + residual: out = x1 + (1/56) WT @ YbufT^T
  k_mgemm<1,1,0><<<dim3(6,13,2),256,0,stream>>>(WT,1568,0, YbufT,1568,602112, x1,384,301056,
                                                (float*)d_out,384,301056, 784,384,1568, 1.f/56.f);
}

// Round 11
// 257.363 us; speedup vs baseline: 6.6162x; 1.1670x over previous
//
#include <hip/hip_runtime.h>
#include <math.h>

#define BB 2
#define NN 784
#define CC 384
#define DI 768
#define DS 64
#define DTR 24
#define ROWS (BB*NN)   // 1568
#define NC 16
#define LC 49          // NC*LC == NN

typedef __attribute__((ext_vector_type(8))) short bf16x8;
typedef __attribute__((ext_vector_type(4))) float f32x4;

static __device__ inline short f2bf(float f){
  unsigned u = __float_as_uint(f);
  unsigned r = (u + 0x7fffu + ((u>>16)&1u)) >> 16;
  return (short)r;
}
static __device__ inline float bf2f(short v){
  return __uint_as_float(((unsigned)(unsigned short)v)<<16);
}
static __device__ inline float rdlane(float v, int t){
  return __uint_as_float(__builtin_amdgcn_readlane(__float_as_uint(v), t));
}
template<int CTRL>
static __device__ inline float qp_add(float x){
  int t = __builtin_amdgcn_update_dpp(0, __float_as_int(x), CTRL, 0xf, 0xf, false);
  return x + __int_as_float(t);
}
#define QP_XOR1 0xB1   // quad_perm [1,0,3,2]
#define QP_XOR2 0x4E   // quad_perm [2,3,0,1]

// ---------------- zero-fill (float4) ----------------
__global__ void k_zero4(float4* __restrict__ p, int n4){
  int i = blockIdx.x*256 + threadIdx.x;
  if (i < n4) p[i] = make_float4(0.f,0.f,0.f,0.f);
}

// ---------------- LayerNorm: one wave per row of 384 ----------------
__global__ void k_ln(const float* __restrict__ x, const float* __restrict__ w,
                     const float* __restrict__ b, float* __restrict__ out, int rows){
  int row = blockIdx.x;
  if (row >= rows) return;
  int lane = threadIdx.x; // blockDim = 64
  const float* xr = x + (size_t)row*CC;
  float v[6]; float s = 0.f;
#pragma unroll
  for (int i=0;i<6;i++){ v[i] = xr[lane + 64*i]; s += v[i]; }
#pragma unroll
  for (int o=32;o;o>>=1) s += __shfl_xor(s,o);
  float mu = s * (1.f/CC);
  float vs = 0.f;
#pragma unroll
  for (int i=0;i<6;i++){ float d=v[i]-mu; vs += d*d; }
#pragma unroll
  for (int o=32;o;o>>=1) vs += __shfl_xor(vs,o);
  float rstd = rsqrtf(vs*(1.f/CC) + 1e-5f);
  float* orow = out + (size_t)row*CC;
#pragma unroll
  for (int i=0;i<6;i++){ int c = lane+64*i; orow[c] = (v[i]-mu)*rstd*w[c] + b[c]; }
}

// ---------------- LayerNorm with transposed output: lnT[b][c][n] ----------------
__global__ void k_lnT(const float* __restrict__ x, const float* __restrict__ w,
                      const float* __restrict__ b, float* __restrict__ out){
  int row = blockIdx.x;      // b*784 + n
  if (row >= ROWS) return;
  int bb = row / NN, n = row % NN;
  int lane = threadIdx.x;
  const float* xr = x + (size_t)row*CC;
  float v[6]; float s = 0.f;
#pragma unroll
  for (int i=0;i<6;i++){ v[i] = xr[lane + 64*i]; s += v[i]; }
#pragma unroll
  for (int o=32;o;o>>=1) s += __shfl_xor(s,o);
  float mu = s * (1.f/CC);
  float vs = 0.f;
#pragma unroll
  for (int i=0;i<6;i++){ float d=v[i]-mu; vs += d*d; }
#pragma unroll
  for (int o=32;o;o>>=1) vs += __shfl_xor(vs,o);
  float rstd = rsqrtf(vs*(1.f/CC) + 1e-5f);
  float* ob = out + (size_t)bb*301056 + n;
#pragma unroll
  for (int i=0;i<6;i++){ int c = lane+64*i; ob[(size_t)c*NN] = (v[i]-mu)*rstd*w[c] + b[c]; }
}

// ---------------- bf16 MFMA GEMM: Y = alpha*(A[M,K] @ Bw[N,K]^T) + epi ----------------
// EPI 0: alpha*acc ; 1: alpha*acc + aux[row*ldaux+col] ; 2: relu(acc+aux[col]) ;
// 3: shrink(acc+aux[col],0.01) ; 4: atomicAdd(Y, alpha*acc)  [Y pre-initialized]
// ABF/BBF: operand already bf16. SPLITK: blockIdx.z = z*SPLITK + ksplit.
template<int EPI, int ABF, int BBF, int SPLITK>
__global__ __launch_bounds__(256) void k_mgemm(
    const void* __restrict__ Ap, int lda, long long Azs,
    const void* __restrict__ Bp, int ldb, long long Bzs,
    const float* __restrict__ aux, int ldaux, long long auxzs,
    float* __restrict__ Y, int ldo, long long Ozs,
    int M, int N, int K, float alpha)
{
  __shared__ __align__(16) short As[64*32];
  __shared__ __align__(16) short Bs[64*32];
  int bz = blockIdx.z;
  int z  = bz / SPLITK, ks = bz % SPLITK;
  if (EPI == 1 || EPI == 2 || EPI == 3) aux += (size_t)z*auxzs;
  Y += (size_t)z*Ozs;
  int nk = (K + 31) >> 5;
  int per = (nk + SPLITK - 1) / SPLITK;
  int kbeg = ks*per*32;
  int kend = kbeg + per*32; if (kend > K) kend = K;
  int m0 = blockIdx.y*64, n0 = blockIdx.x*64;
  int t = threadIdx.x;
  int srow = t>>2, skg = t&3;                 // staging: row 0..63, k-group 0..3 (8 elems)
  int w = t>>6, lane = t&63;
  int wr = (w>>1)*32, wc = (w&1)*32;
  int l15 = lane&15, lh = lane>>4;
  f32x4 acc[2][2] = {};
  int sslot = skg ^ ((srow>>1)&3);
  for (int k0=kbeg; k0<kend; k0+=32){
    // ---- stage A ----
    {
      int gm = m0 + srow, gk = k0 + skg*8;
      if (ABF){
        bf16x8 v = {};
        if (gm < M && gk < K) v = *(const bf16x8*)((const short*)Ap + (size_t)z*Azs + (size_t)gm*lda + gk);
        *(bf16x8*)(As + srow*32 + sslot*8) = v;
      } else {
        const float* Af = (const float*)Ap + (size_t)z*Azs;
        float4 v0 = {0,0,0,0}, v1 = {0,0,0,0};
        if (gm < M && gk < K){
          const float* p = Af + (size_t)gm*lda + gk;
          v0 = *(const float4*)p; v1 = *(const float4*)(p+4);
        }
        union { short s[8]; bf16x8 v; } pk;
        pk.s[0]=f2bf(v0.x); pk.s[1]=f2bf(v0.y); pk.s[2]=f2bf(v0.z); pk.s[3]=f2bf(v0.w);
        pk.s[4]=f2bf(v1.x); pk.s[5]=f2bf(v1.y); pk.s[6]=f2bf(v1.z); pk.s[7]=f2bf(v1.w);
        *(bf16x8*)(As + srow*32 + sslot*8) = pk.v;
      }
    }
    // ---- stage B (W-form [N][K]) ----
    {
      int gn = n0 + srow, gk = k0 + skg*8;
      if (BBF){
        bf16x8 v = {};
        if (gn < N && gk < K) v = *(const bf16x8*)((const short*)Bp + (size_t)z*Bzs + (size_t)gn*ldb + gk);
        *(bf16x8*)(Bs + srow*32 + sslot*8) = v;
      } else {
        const float* Bf = (const float*)Bp + (size_t)z*Bzs;
        float4 v0 = {0,0,0,0}, v1 = {0,0,0,0};
        if (gn < N && gk < K){
          const float* p = Bf + (size_t)gn*ldb + gk;
          v0 = *(const float4*)p; v1 = *(const float4*)(p+4);
        }
        union { short s[8]; bf16x8 v; } pk;
        pk.s[0]=f2bf(v0.x); pk.s[1]=f2bf(v0.y); pk.s[2]=f2bf(v0.z); pk.s[3]=f2bf(v0.w);
        pk.s[4]=f2bf(v1.x); pk.s[5]=f2bf(v1.y); pk.s[6]=f2bf(v1.z); pk.s[7]=f2bf(v1.w);
        *(bf16x8*)(Bs + srow*32 + sslot*8) = pk.v;
      }
    }
    __syncthreads();
    bf16x8 af[2], bfr[2];
#pragma unroll
    for (int mi=0; mi<2; mi++){
      int row = wr + mi*16 + l15;
      af[mi] = *(const bf16x8*)(As + row*32 + ((lh ^ ((row>>1)&3))<<3));
    }
#pragma unroll
    for (int ni=0; ni<2; ni++){
      int col = wc + ni*16 + l15;
      bfr[ni] = *(const bf16x8*)(Bs + col*32 + ((lh ^ ((col>>1)&3))<<3));
    }
#pragma unroll
    for (int mi=0; mi<2; mi++)
#pragma unroll
      for (int ni=0; ni<2; ni++)
        acc[mi][ni] = __builtin_amdgcn_mfma_f32_16x16x32_bf16(af[mi], bfr[ni], acc[mi][ni], 0, 0, 0);
    __syncthreads();
  }
  // ---- epilogue ----
#pragma unroll
  for (int mi=0; mi<2; mi++){
#pragma unroll
    for (int ni=0; ni<2; ni++){
      int col = n0 + wc + ni*16 + l15;
      if (col >= N) continue;
#pragma unroll
      for (int j=0; j<4; j++){
        int row = m0 + wr + mi*16 + lh*4 + j;
        if (row >= M) continue;
        float v = acc[mi][ni][j];
        if (EPI == 0){ Y[(size_t)row*ldo + col] = v*alpha; }
        else if (EPI == 1){ Y[(size_t)row*ldo + col] = v*alpha + aux[(size_t)row*ldaux + col]; }
        else if (EPI == 2){ v += aux[col]; Y[(size_t)row*ldo + col] = fmaxf(v, 0.f); }
        else if (EPI == 3){ v += aux[col]; Y[(size_t)row*ldo + col] = copysignf(fmaxf(fabsf(v)-0.01f, 0.f), v); }
        else { atomicAdd(&Y[(size_t)row*ldo + col], v*alpha); }
      }
    }
  }
}

// ---------------- fp32 GEMM (dt_proj only): Y = softplus(X@W^T + bias) ----------------
#define GBM 64
#define GBN 64
#define GBK 16
__global__ __launch_bounds__(256) void k_gemm(
    const float* __restrict__ X, int lda,
    const float* __restrict__ W,
    const float* __restrict__ bias,
    float* __restrict__ Y,
    int M, int N, int K)
{
  __shared__ float As[GBK][GBM+4];
  __shared__ float Bs[GBK][GBN+4];
  int m0 = blockIdx.y*GBM, n0 = blockIdx.x*GBN;
  int tid = threadIdx.x;
  int ty = tid>>4, tx = tid&15;
  float acc[4][4] = {{0.f}};
  for (int k0=0;k0<K;k0+=GBK){
#pragma unroll
    for (int l=0;l<4;l++){
      int e = tid + 256*l;
      int m = e>>4, kk = e&15;
      int gm = m0+m, gk = k0+kk;
      As[kk][m] = (gm<M && gk<K) ? X[(size_t)gm*lda+gk] : 0.f;
      int gn = n0+m;
      Bs[kk][m] = (gn<N && gk<K) ? W[(size_t)gn*K+gk] : 0.f;
    }
    __syncthreads();
#pragma unroll
    for (int kk=0;kk<GBK;kk++){
      float4 av = *(const float4*)&As[kk][ty*4];
      float4 bv = *(const float4*)&Bs[kk][tx*4];
      float a[4]={av.x,av.y,av.z,av.w}, b[4]={bv.x,bv.y,bv.z,bv.w};
#pragma unroll
      for (int i=0;i<4;i++)
#pragma unroll
        for (int j=0;j<4;j++) acc[i][j] += a[i]*b[j];
    }
    __syncthreads();
  }
#pragma unroll
  for (int i=0;i<4;i++){
    int gm = m0+ty*4+i; if (gm>=M) continue;
#pragma unroll
    for (int j=0;j<4;j++){
      int gn = n0+tx*4+j; if (gn>=N) continue;
      float v = acc[i][j] + bias[gn];
      v = (v>20.f)? v : log1pf(expf(v));
      Y[(size_t)gm*N+gn] = v;
    }
  }
}

// ---------------- causal depthwise conv1d + silu ----------------
__global__ void k_conv(const float* __restrict__ xz, const float* __restrict__ cw,
                       const float* __restrict__ cb, float* __restrict__ xc){
  int idx = blockIdx.x*256 + threadIdx.x;
  if (idx >= ROWS*DI) return;
  int d = idx % DI;
  int r = idx / DI;
  int b = r / NN, l = r % NN;
  float acc = cb[d];
#pragma unroll
  for (int t=0;t<4;t++){
    int ls = l-3+t;
    if (ls>=0) acc += cw[d*4+t] * xz[((size_t)(b*NN+ls))*1536 + d];
  }
  xc[(size_t)r*DI + d] = acc / (1.f + expf(-acc)); // silu
}

// ---------------- chunked scan pass 1 ----------------
__global__ __launch_bounds__(256) void k_scan1(
    const float* __restrict__ dbl, const float* __restrict__ dtb,
    const float* __restrict__ xc, const float* __restrict__ A_log,
    short* __restrict__ hpart, float* __restrict__ sdt)
{
  __shared__ float Sb[LC*64];
  int gx = blockIdx.x;                 // 32 * 192
  int bc = gx & 31, dgrp = gx >> 5;
  int b = bc >> 4, c = bc & 15;
  int wv = threadIdx.x >> 6, lane = threadIdx.x & 63;
  int d = dgrp*4 + wv;
  int t0 = c*LC;
  const float* dbr = dbl + ((size_t)(b*NN+t0))*152 + DTR;
  for (int i = threadIdx.x; i < LC*64; i += 256){
    int r = i >> 6, col = i & 63;
    Sb[i] = dbr[(size_t)r*152 + col];
  }
  __syncthreads();
  float A = -__expf(A_log[d*DS + lane]);
  const float* dtp = dtb + ((size_t)(b*NN+t0))*DI + d;
  const float* up  = xc  + ((size_t)(b*NN+t0))*DI + d;
  float dt0v = (lane<LC) ? dtp[(size_t)lane*DI] : 0.f;
  float u0v  = (lane<LC) ? up[(size_t)lane*DI]  : 0.f;
  float h = 0.f;
  for (int tb=0; tb<LC; tb+=7){
    float e[7], f[7];
#pragma unroll
    for (int j=0;j<7;j++){
      int t = tb+j;
      float dt = rdlane(dt0v, t);
      float u  = rdlane(u0v, t);
      e[j] = __expf(dt*A);
      f[j] = (dt*u)*Sb[t*64 + lane];
    }
#pragma unroll
    for (int j=0;j<7;j++) h = h*e[j] + f[j];
  }
  int bd = b*DI + d;
  hpart[((size_t)bd*NC + c)*DS + lane] = f2bf(h);
  float s = dt0v;
#pragma unroll
  for (int o=32;o;o>>=1) s += __shfl_xor(s,o);
  if (lane==0) sdt[bd*NC + c] = s;
}

// ---------------- chunked scan pass 2 ----------------
__global__ __launch_bounds__(256) void k_scan2(
    const float* __restrict__ sdt, const float* __restrict__ A_log,
    short* __restrict__ hpart)
{
  int wid = (blockIdx.x*256 + threadIdx.x) >> 6;
  int lane = threadIdx.x & 63;
  if (wid >= BB*DI) return;
  int d = wid % DI;
  float A = -__expf(A_log[d*DS + lane]);
  short* hp = hpart + (size_t)wid*NC*DS + lane;
  const float* sp = sdt + wid*NC;
  float part[NC], pA[NC];
#pragma unroll
  for (int c=0;c<NC;c++){ part[c] = bf2f(hp[(size_t)c*DS]); pA[c] = __expf(A*sp[c]); }
  float h = 0.f;
#pragma unroll
  for (int c=0;c<NC;c++){
    hp[(size_t)c*DS] = f2bf(h);   // hin for chunk c
    h = h*pA[c] + part[c];
  }
}

// ---------------- chunked scan pass 3 ----------------
__global__ __launch_bounds__(256) void k_scan3(
    const float* __restrict__ dbl, const float* __restrict__ dtb,
    const float* __restrict__ xc, const float* __restrict__ xz,
    const float* __restrict__ A_log, const float* __restrict__ Dp,
    const short* __restrict__ hin, float* __restrict__ y)
{
  __shared__ float S[LC*128];          // interleaved {B,C}: S[t*128 + lane*2 + {0,1}]
  __shared__ float red[4][LC*17];
  int gx = blockIdx.x;
  int bc = gx & 31, dgrp = gx >> 5;
  int b = bc >> 4, c = bc & 15;
  int wv = threadIdx.x >> 6, lane = threadIdx.x & 63;
  int d = dgrp*4 + wv;
  int t0 = c*LC;
  const float* dbr = dbl + ((size_t)(b*NN+t0))*152 + DTR;
  for (int i = threadIdx.x; i < LC*128; i += 256){
    int r = i >> 7, col = i & 127;
    int ln = col & 63, which = col >> 6;
    S[r*128 + ln*2 + which] = dbr[(size_t)r*152 + col];
  }
  __syncthreads();
  float A = -__expf(A_log[d*DS + lane]);
  float Dv = Dp[d];
  const float* dtp = dtb + ((size_t)(b*NN+t0))*DI + d;
  const float* up  = xc  + ((size_t)(b*NN+t0))*DI + d;
  const float* zp  = xz  + ((size_t)(b*NN+t0))*1536 + DI + d;
  float* yp = y + ((size_t)(b*NN+t0))*DI + d;
  float dt0v = (lane<LC) ? dtp[(size_t)lane*DI]  : 0.f;
  float u0v  = (lane<LC) ? up[(size_t)lane*DI]   : 0.f;
  float z0v  = (lane<LC) ? zp[(size_t)lane*1536] : 0.f;
  int bd = b*DI + d;
  float h = bf2f(hin[((size_t)bd*NC + c)*DS + lane]);
  float* rw = red[wv];
  int g = lane>>2;
  bool gl = (lane&3)==0;
  for (int tb=0; tb<LC; tb+=7){
    float e[7], f[7], Cv[7];
#pragma unroll
    for (int j=0;j<7;j++){
      int t = tb+j;
      float2 bcv = *(const float2*)&S[t*128 + lane*2];
      float dt = rdlane(dt0v, t);
      float u  = rdlane(u0v, t);
      e[j]  = __expf(dt*A);
      f[j]  = (dt*u)*bcv.x;
      Cv[j] = bcv.y;
    }
#pragma unroll
    for (int j=0;j<7;j++){
      h = h*e[j] + f[j];
      float p = h*Cv[j];
      p = qp_add<QP_XOR1>(p);
      p = qp_add<QP_XOR2>(p);
      if (gl) rw[(tb+j)*17 + g] = p;
    }
  }
  if (lane < LC){
    const float* rr = rw + lane*17;
    float a0 = rr[0]+rr[4]+rr[8] +rr[12];
    float a1 = rr[1]+rr[5]+rr[9] +rr[13];
    float a2 = rr[2]+rr[6]+rr[10]+rr[14];
    float a3 = rr[3]+rr[7]+rr[11]+rr[15];
    float yv = (a0+a1)+(a2+a3) + u0v*Dv;      // lane == t
    float z = z0v;
    yp[(size_t)lane*DI] = yv * (z/(1.f+__expf(-z)));
  }
}

// ---------------- twiddle tables (bf16, two coalesced passes) ----------------
__global__ void k_tw(short* __restrict__ Wcat, short* __restrict__ WT){
  int idx = blockIdx.x*256+threadIdx.x;
  if (idx >= 2*784*1568) return;
  if (idx < 784*1568){
    int n = idx / 1568, f = idx % 1568;       // f fastest -> WT store coalesced
    int ff = (f<784)? f : f-784;
    int m = (int)(((long long)ff*(long long)n) % 784);
    float ang = 6.283185307179586f * (float)m / 784.f;
    float s, cval; sincosf(ang, &s, &cval);
    WT[(size_t)n*1568 + f] = f2bf((f<784)? cval : -s);
  } else {
    int r = idx - 784*1568;
    int f = r / 784, n = r % 784;             // n fastest -> Wcat store coalesced
    int ff = (f<784)? f : f-784;
    int m = (int)(((long long)ff*(long long)n) % 784);
    float ang = 6.283185307179586f * (float)m / 784.f;
    float s, cval; sincosf(ang, &s, &cval);
    Wcat[(size_t)f*784 + n] = f2bf((f<784)? cval : -s);
  }
}

// ---------------- build stacked real bf16 weights for both complex block layers ----------------
__global__ void k_prepw(const float* __restrict__ cw1, const float* __restrict__ cb1,
                        const float* __restrict__ cw2, const float* __restrict__ cb2,
                        short* __restrict__ W1, short* __restrict__ W2,
                        float* __restrict__ b1, float* __restrict__ b2){
  int idx = blockIdx.x*256+threadIdx.x;
  if (idx < 2*4*192*192){
    int l = idx / (4*192*192);
    int r = idx % (4*192*192);
    int d = r % 192; int j = (r/192) % 192; int bl = r/(192*192);
    int jj = j % 96, dd = d % 96;
    const float* cw = l ? cw2 : cw1;
    const float* w0 = cw + bl*9216;
    const float* w1 = cw + 4*9216 + bl*9216;
    float v;
    if (j < 96) v = (d < 96) ? w0[dd*96+jj] : -w1[dd*96+jj];
    else        v = (d < 96) ? w1[dd*96+jj] :  w0[dd*96+jj];
    (l ? W2 : W1)[r] = f2bf(v);
  }
  if (idx < 2*4*192){
    int l = idx / (4*192);
    int r = idx % (4*192);
    int j = r % 192; int bl = r/192;
    const float* cb = l ? cb2 : cb1;
    (l ? b2 : b1)[r] = (j<96) ? cb[bl*96 + j] : cb[384 + bl*96 + (j-96)];
  }
}

// ---------------- forward length-4 DFT along nb -> tcat[r][q*192 + {0:re,96:im} + k] ----------------
__global__ void k_cfft4(const float* __restrict__ Ybuf, float* __restrict__ tcat){
  int idx = blockIdx.x*256+threadIdx.x;
  if (idx >= BB*NN*96) return;
  int k = idx % 96; int r = idx / 96;
  int b = r / NN, f = r % NN;
  const float* fre = Ybuf + (size_t)b*602112 + (size_t)f*384;
  const float* fim = fre + 301056;
  float R0=fre[k], R1=fre[96+k], R2=fre[192+k], R3=fre[288+k];
  float I0=fim[k], I1=fim[96+k], I2=fim[192+k], I3=fim[288+k];
  float* tr = tcat + (size_t)r*768;
  tr[k]       = R0+R1+R2+R3;  tr[96+k]    = I0+I1+I2+I3;
  tr[192+k]   = R0+I1-R2-I3;  tr[192+96+k]= I0-R1-I2+R3;
  tr[384+k]   = R0-R1+R2-R3;  tr[384+96+k]= I0-I1+I2-I3;
  tr[576+k]   = R0-I1-R2+I3;  tr[576+96+k]= I0+R1-I2-R3;
}

// ---------------- inverse length-4 DFT -> YbufT[b][c][fcat] ----------------
__global__ void k_cifft4(const float* __restrict__ t2cat, float* __restrict__ YbufT){
  int idx = blockIdx.x*256+threadIdx.x;
  if (idx >= BB*NN*96) return;
  int f = idx % 784;
  int rest = idx / 784;
  int k = rest % 96;
  int b = rest / 96;
  const float* tr = t2cat + ((size_t)(b*NN+f))*768;
  float R0=tr[k],     I0=tr[96+k];
  float R1=tr[192+k], I1=tr[192+96+k];
  float R2=tr[384+k], I2=tr[384+96+k];
  float R3=tr[576+k], I3=tr[576+96+k];
  float* YT = YbufT + (size_t)b*602112;
  float gr[4], gi[4];
  gr[0]=R0+R1+R2+R3; gi[0]=I0+I1+I2+I3;
  gr[1]=R0-I1-R2+I3; gi[1]=I0+R1-I2-R3;
  gr[2]=R0-R1+R2-R3; gi[2]=I0-I1+I2-I3;
  gr[3]=R0+I1-R2-I3; gi[3]=I0-R1-I2+R3;
#pragma unroll
  for (int n=0;n<4;n++){
    int c = n*96 + k;
    YT[(size_t)c*1568 + f]       = gr[n];
    YT[(size_t)c*1568 + 784 + f] = gi[n];
  }
}

extern "C" void kernel_launch(void* const* d_in, const int* in_sizes, int n_in,
                              void* d_out, int out_size, void* d_ws, size_t ws_size,
                              hipStream_t stream){
  const float* x         = (const float*)d_in[0];
  const float* ln1_w     = (const float*)d_in[3];
  const float* ln1_b     = (const float*)d_in[4];
  const float* in_proj_w = (const float*)d_in[5];
  const float* conv_w    = (const float*)d_in[6];
  const float* conv_b    = (const float*)d_in[7];
  const float* x_proj_w  = (const float*)d_in[8];
  const float* dt_proj_w = (const float*)d_in[9];
  const float* dt_proj_b = (const float*)d_in[10];
  const float* A_log     = (const float*)d_in[11];
  const float* Dp        = (const float*)d_in[12];
  const float* out_proj_w= (const float*)d_in[13];
  const float* ln2_w     = (const float*)d_in[14];
  const float* ln2_b     = (const float*)d_in[15];
  const float* cw1       = (const float*)d_in[16];
  const float* cb1       = (const float*)d_in[17];
  const float* cw2       = (const float*)d_in[18];
  const float* cb2       = (const float*)d_in[19];

  float* ws = (float*)d_ws;
  // ---- phase A (mamba) ----
  float* ln   = ws;                  // [0, 602112)
  float* xz   = ws + 602112;         // [602112, 3010560)
  float* xc   = ws + 3010560;        // [3010560, 4214784)
  float* dbl  = ws + 4214784;        // [4214784, 4453120)
  float* dtb  = ws + 4453120;        // [4453120, 5657344)
  float* yb   = ws + 5657344;        // [5657344, 6861568)
  float* x1   = ws + 6861568;        // [6861568, 7463680)  persists to end
  short* hpart= (short*)(ws + 7463680); // bf16: floats [7463680, 8250112)
  float* sdt  = ws + 8250112;        // [8250112, 8274688)
  // ---- phase B (einfft), overlaid on regions dead by launch order ----
  short* Wcat = (short*)(ws + 602112);   // floats [602112, 1216768)
  float* lnT  = ws + 1831424;            // [1831424, 2433536)
  float* Ybuf = ws + 2433536;            // [2433536, 3637760)
  short* WT   = (short*)(ws + 4453120);  // floats [4453120, 5067776) over dead dtb
  float* tcat = ws + 602112;             // [602112, 1806336)  over dead Wcat
  float* o1cat= ws + 1806336;            // [1806336, 3010560)
  float* t2cat= ws + 3010560;            // [3010560, 4214784)
  float* YbufT= ws + 602112;             // [602112, 1806336)  over dead tcat
  short* W1c  = (short*)(ws + 7463680);  // floats [7463680, 7537408) over dead hpart
  short* W2c  = (short*)(ws + 7537408);  // floats [7537408, 7611136)
  float* b1c  = ws + 7611136;            // [7611136, 7611904)
  float* b2c  = ws + 7611904;            // [7611904, 7612672)

  // ---- mamba path ----
  k_ln<<<ROWS,64,0,stream>>>(x, ln1_w, ln1_b, ln, ROWS);
  // in_proj (600 blocks, adequate parallelism): plain store
  k_mgemm<0,0,0,1><<<dim3(24,25,1),256,0,stream>>>(ln,384,0, in_proj_w,384,0, nullptr,0,0,
                                                   xz,1536,0, ROWS,1536,384, 1.f);
  k_conv<<<(ROWS*DI+255)/256,256,0,stream>>>(xz,conv_w,conv_b,xc);
  // x_proj: split-K 8 (24 k-iters -> 3 each), atomic into zeroed dbl
  k_zero4<<<(238336/4+255)/256,256,0,stream>>>((float4*)dbl, 238336/4);
  k_mgemm<4,0,0,8><<<dim3(3,25,8),256,0,stream>>>(xc,768,0, x_proj_w,768,0, nullptr,0,0,
                                                  dbl,152,0, ROWS,152,768, 1.f);
  k_gemm<<<dim3(12,25),256,0,stream>>>(dbl,152,dt_proj_w,dt_proj_b,dtb,ROWS,768,24);
  k_scan1<<<32*192,256,0,stream>>>(dbl,dtb,xc,A_log,hpart,sdt);
  k_scan2<<<(BB*DI)/4,256,0,stream>>>(sdt,A_log,hpart);
  k_scan3<<<32*192,256,0,stream>>>(dbl,dtb,xc,xz,A_log,Dp,hpart,yb);
  // out_proj: split-K 4 (24 k-iters -> 6 each), atomic into x1 pre-initialized with x
  hipMemcpyAsync(x1, x, (size_t)602112*4, hipMemcpyDeviceToDevice, stream);
  k_mgemm<4,0,0,4><<<dim3(6,25,4),256,0,stream>>>(yb,768,0, out_proj_w,768,0, nullptr,0,0,
                                                  x1,384,0, ROWS,384,768, 1.f);

  // ---- einfft path (prep after mamba: overlaid regions now dead) ----
  k_tw<<<(2*784*1568+255)/256,256,0,stream>>>(Wcat,WT);
  k_prepw<<<(2*4*192*192+255)/256,256,0,stream>>>(cw1,cb1,cw2,cb2,W1c,W2c,b1c,b2c);
  k_lnT<<<ROWS,64,0,stream>>>(x1, ln2_w, ln2_b, lnT);
  // forward DFT-784: split-K 4 (25 k-iters -> 7,7,7,4), atomic into zeroed Ybuf
  k_zero4<<<(1204224/4+255)/256,256,0,stream>>>((float4*)Ybuf, 1204224/4);
  k_mgemm<4,1,0,4><<<dim3(6,25,8),256,0,stream>>>(Wcat,784,0, lnT,784,301056, nullptr,0,0,
                                                  Ybuf,384,602112, 1568,384,784, 1.f/56.f);
  // forward DFT-4 along nb -> tcat
  k_cfft4<<<(BB*NN*96+255)/256,256,0,stream>>>(Ybuf,tcat);
  // EinFFT layer 1 (relu)
  k_mgemm<2,0,1,1><<<dim3(3,25,4),256,0,stream>>>(tcat,768,192, W1c,192,36864, b1c,0,192,
                                                  o1cat,768,192, ROWS,192,192, 1.f);
  // EinFFT layer 2 (soft shrink)
  k_mgemm<3,0,1,1><<<dim3(3,25,4),256,0,stream>>>(o1cat,768,192, W2c,192,36864, b2c,0,192,
                                                  t2cat,768,192, ROWS,192,192, 1.f);
  // inverse DFT-4 -> YbufT[b][c][fcat]
  k_cifft4<<<(BB*NN*96+255)/256,256,0,stream>>>(t2cat,YbufT);
  // inverse DFT-784: split-K 7 (49 k-iters -> 7 each), atomic into d_out pre-initialized with x1
  hipMemcpyAsync(d_out, x1, (size_t)602112*4, hipMemcpyDeviceToDevice, stream);
  k_mgemm<4,1,0,7><<<dim3(6,13,14),256,0,stream>>>(WT,1568,0, YbufT,1568,602112, nullptr,0,0,
                                                   (float*)d_out,384,301056, 784,384,1568, 1.f/56.f);
}

// Round 12
// 249.442 us; speedup vs baseline: 6.8263x; 1.0318x over previous
//
#include <hip/hip_runtime.h>
#include <math.h>

#define BB 2
#define NN 784
#define CC 384
#define DI 768
#define DS 64
#define DTR 24
#define ROWS (BB*NN)   // 1568
#define NC 16
#define LC 49          // NC*LC == NN

typedef __attribute__((ext_vector_type(8))) short bf16x8;
typedef __attribute__((ext_vector_type(4))) float f32x4;

static __device__ inline short f2bf(float f){
  unsigned u = __float_as_uint(f);
  unsigned r = (u + 0x7fffu + ((u>>16)&1u)) >> 16;
  return (short)r;
}
static __device__ inline float bf2f(short v){
  return __uint_as_float(((unsigned)(unsigned short)v)<<16);
}
static __device__ inline float rdlane(float v, int t){
  return __uint_as_float(__builtin_amdgcn_readlane(__float_as_uint(v), t));
}
template<int CTRL>
static __device__ inline float qp_add(float x){
  int t = __builtin_amdgcn_update_dpp(0, __float_as_int(x), CTRL, 0xf, 0xf, false);
  return x + __int_as_float(t);
}
#define QP_XOR1 0xB1   // quad_perm [1,0,3,2]
#define QP_XOR2 0x4E   // quad_perm [2,3,0,1]
#define LOG2E 1.44269504088896f

// ---------------- zero-fill (float4) ----------------
__global__ void k_zero4(float4* __restrict__ p, int n4){
  int i = blockIdx.x*256 + threadIdx.x;
  if (i < n4) p[i] = make_float4(0.f,0.f,0.f,0.f);
}

// ---------------- LayerNorm (bf16 out): one wave per row of 384 ----------------
__global__ void k_ln(const float* __restrict__ x, const float* __restrict__ w,
                     const float* __restrict__ b, short* __restrict__ out, int rows){
  int row = blockIdx.x;
  if (row >= rows) return;
  int lane = threadIdx.x; // blockDim = 64
  const float* xr = x + (size_t)row*CC;
  float v[6]; float s = 0.f;
#pragma unroll
  for (int i=0;i<6;i++){ v[i] = xr[lane + 64*i]; s += v[i]; }
#pragma unroll
  for (int o=32;o;o>>=1) s += __shfl_xor(s,o);
  float mu = s * (1.f/CC);
  float vs = 0.f;
#pragma unroll
  for (int i=0;i<6;i++){ float d=v[i]-mu; vs += d*d; }
#pragma unroll
  for (int o=32;o;o>>=1) vs += __shfl_xor(vs,o);
  float rstd = rsqrtf(vs*(1.f/CC) + 1e-5f);
  short* orow = out + (size_t)row*CC;
#pragma unroll
  for (int i=0;i<6;i++){ int c = lane+64*i; orow[c] = f2bf((v[i]-mu)*rstd*w[c] + b[c]); }
}

// ---------------- LayerNorm transposed bf16 out: lnT[b][c][n] ----------------
__global__ void k_lnT(const float* __restrict__ x, const float* __restrict__ w,
                      const float* __restrict__ b, short* __restrict__ out){
  int row = blockIdx.x;      // b*784 + n
  if (row >= ROWS) return;
  int bb = row / NN, n = row % NN;
  int lane = threadIdx.x;
  const float* xr = x + (size_t)row*CC;
  float v[6]; float s = 0.f;
#pragma unroll
  for (int i=0;i<6;i++){ v[i] = xr[lane + 64*i]; s += v[i]; }
#pragma unroll
  for (int o=32;o;o>>=1) s += __shfl_xor(s,o);
  float mu = s * (1.f/CC);
  float vs = 0.f;
#pragma unroll
  for (int i=0;i<6;i++){ float d=v[i]-mu; vs += d*d; }
#pragma unroll
  for (int o=32;o;o>>=1) vs += __shfl_xor(vs,o);
  float rstd = rsqrtf(vs*(1.f/CC) + 1e-5f);
  short* ob = out + (size_t)bb*301056 + n;
#pragma unroll
  for (int i=0;i<6;i++){ int c = lane+64*i; ob[(size_t)c*NN] = f2bf((v[i]-mu)*rstd*w[c] + b[c]); }
}

// ---------------- bf16 MFMA GEMM, register double-buffered ----------------
// EPI 0: alpha*acc ; 1: alpha*acc + aux[row*ldaux+col] ; 2: relu(acc+aux[col]) ;
// 3: shrink(acc+aux[col],0.01) ; 4: atomicAdd(Y, alpha*acc)  [Y pre-initialized]
// ABF/BBF: operand already bf16 (lda/ldb/zs in elements of that type).
template<int EPI, int ABF, int BBF, int SPLITK>
__global__ __launch_bounds__(256) void k_mgemm(
    const void* __restrict__ Ap, int lda, long long Azs,
    const void* __restrict__ Bp, int ldb, long long Bzs,
    const float* __restrict__ aux, int ldaux, long long auxzs,
    float* __restrict__ Y, int ldo, long long Ozs,
    int M, int N, int K, float alpha)
{
  __shared__ __align__(16) short As[64*32];
  __shared__ __align__(16) short Bs[64*32];
  int bz = blockIdx.z;
  int z  = bz / SPLITK, ks = bz % SPLITK;
  if (EPI == 1 || EPI == 2 || EPI == 3) aux += (size_t)z*auxzs;
  Y += (size_t)z*Ozs;
  int nk = (K + 31) >> 5;
  int per = (nk + SPLITK - 1) / SPLITK;
  int kbeg = ks*per*32;
  int kend = kbeg + per*32; if (kend > K) kend = K;
  if (kend <= kbeg) return;
  int ntile = (kend - kbeg + 31) >> 5;
  int m0 = blockIdx.y*64, n0 = blockIdx.x*64;
  int t = threadIdx.x;
  int srow = t>>2, skg = t&3;
  int w = t>>6, lane = t&63;
  int wr = (w>>1)*32, wc = (w&1)*32;
  int l15 = lane&15, lh = lane>>4;
  f32x4 acc[2][2] = {};
  int sslot = skg ^ ((srow>>1)&3);
  int gmA = m0 + srow, gnB = n0 + srow;
  int gko = skg*8;

  // in-flight tile registers
  bf16x8 vA = {}, vB = {};
  float4 fA0, fA1, fB0, fB1;

  auto LOAD = [&](int k0){
    int gk = k0 + gko;
    if (ABF){
      bf16x8 v = {};
      if (gmA < M && gk < K) v = *(const bf16x8*)((const short*)Ap + (size_t)z*Azs + (size_t)gmA*lda + gk);
      vA = v;
    } else {
      fA0 = make_float4(0.f,0.f,0.f,0.f); fA1 = fA0;
      if (gmA < M && gk < K){
        const float* p = (const float*)Ap + (size_t)z*Azs + (size_t)gmA*lda + gk;
        fA0 = *(const float4*)p; fA1 = *(const float4*)(p+4);
      }
    }
    if (BBF){
      bf16x8 v = {};
      if (gnB < N && gk < K) v = *(const bf16x8*)((const short*)Bp + (size_t)z*Bzs + (size_t)gnB*ldb + gk);
      vB = v;
    } else {
      fB0 = make_float4(0.f,0.f,0.f,0.f); fB1 = fB0;
      if (gnB < N && gk < K){
        const float* p = (const float*)Bp + (size_t)z*Bzs + (size_t)gnB*ldb + gk;
        fB0 = *(const float4*)p; fB1 = *(const float4*)(p+4);
      }
    }
  };
  auto STORE = [&](){
    if (ABF) *(bf16x8*)(As + srow*32 + sslot*8) = vA;
    else {
      union { short s[8]; bf16x8 v; } pk;
      pk.s[0]=f2bf(fA0.x); pk.s[1]=f2bf(fA0.y); pk.s[2]=f2bf(fA0.z); pk.s[3]=f2bf(fA0.w);
      pk.s[4]=f2bf(fA1.x); pk.s[5]=f2bf(fA1.y); pk.s[6]=f2bf(fA1.z); pk.s[7]=f2bf(fA1.w);
      *(bf16x8*)(As + srow*32 + sslot*8) = pk.v;
    }
    if (BBF) *(bf16x8*)(Bs + srow*32 + sslot*8) = vB;
    else {
      union { short s[8]; bf16x8 v; } pk;
      pk.s[0]=f2bf(fB0.x); pk.s[1]=f2bf(fB0.y); pk.s[2]=f2bf(fB0.z); pk.s[3]=f2bf(fB0.w);
      pk.s[4]=f2bf(fB1.x); pk.s[5]=f2bf(fB1.y); pk.s[6]=f2bf(fB1.z); pk.s[7]=f2bf(fB1.w);
      *(bf16x8*)(Bs + srow*32 + sslot*8) = pk.v;
    }
  };

  LOAD(kbeg);
  for (int ti=0; ti<ntile; ++ti){
    STORE();
    __syncthreads();
    if (ti+1 < ntile) LOAD(kbeg + (ti+1)*32);   // in-flight during MFMA
    bf16x8 af[2], bfr[2];
#pragma unroll
    for (int mi=0; mi<2; mi++){
      int row = wr + mi*16 + l15;
      af[mi] = *(const bf16x8*)(As + row*32 + ((lh ^ ((row>>1)&3))<<3));
    }
#pragma unroll
    for (int ni=0; ni<2; ni++){
      int col = wc + ni*16 + l15;
      bfr[ni] = *(const bf16x8*)(Bs + col*32 + ((lh ^ ((col>>1)&3))<<3));
    }
#pragma unroll
    for (int mi=0; mi<2; mi++)
#pragma unroll
      for (int ni=0; ni<2; ni++)
        acc[mi][ni] = __builtin_amdgcn_mfma_f32_16x16x32_bf16(af[mi], bfr[ni], acc[mi][ni], 0, 0, 0);
    __syncthreads();
  }
  // ---- epilogue ----
#pragma unroll
  for (int mi=0; mi<2; mi++){
#pragma unroll
    for (int ni=0; ni<2; ni++){
      int col = n0 + wc + ni*16 + l15;
      if (col >= N) continue;
#pragma unroll
      for (int j=0; j<4; j++){
        int row = m0 + wr + mi*16 + lh*4 + j;
        if (row >= M) continue;
        float v = acc[mi][ni][j];
        if (EPI == 0){ Y[(size_t)row*ldo + col] = v*alpha; }
        else if (EPI == 1){ Y[(size_t)row*ldo + col] = v*alpha + aux[(size_t)row*ldaux + col]; }
        else if (EPI == 2){ v += aux[col]; Y[(size_t)row*ldo + col] = fmaxf(v, 0.f); }
        else if (EPI == 3){ v += aux[col]; Y[(size_t)row*ldo + col] = copysignf(fmaxf(fabsf(v)-0.01f, 0.f), v); }
        else { atomicAdd(&Y[(size_t)row*ldo + col], v*alpha); }
      }
    }
  }
}

// ---------------- fp32 GEMM (dt_proj only): Y = softplus(X@W^T + bias) ----------------
#define GBM 64
#define GBN 64
#define GBK 16
__global__ __launch_bounds__(256) void k_gemm(
    const float* __restrict__ X, int lda,
    const float* __restrict__ W,
    const float* __restrict__ bias,
    float* __restrict__ Y,
    int M, int N, int K)
{
  __shared__ float As[GBK][GBM+4];
  __shared__ float Bs[GBK][GBN+4];
  int m0 = blockIdx.y*GBM, n0 = blockIdx.x*GBN;
  int tid = threadIdx.x;
  int ty = tid>>4, tx = tid&15;
  float acc[4][4] = {{0.f}};
  for (int k0=0;k0<K;k0+=GBK){
#pragma unroll
    for (int l=0;l<4;l++){
      int e = tid + 256*l;
      int m = e>>4, kk = e&15;
      int gm = m0+m, gk = k0+kk;
      As[kk][m] = (gm<M && gk<K) ? X[(size_t)gm*lda+gk] : 0.f;
      int gn = n0+m;
      Bs[kk][m] = (gn<N && gk<K) ? W[(size_t)gn*K+gk] : 0.f;
    }
    __syncthreads();
#pragma unroll
    for (int kk=0;kk<GBK;kk++){
      float4 av = *(const float4*)&As[kk][ty*4];
      float4 bv = *(const float4*)&Bs[kk][tx*4];
      float a[4]={av.x,av.y,av.z,av.w}, b[4]={bv.x,bv.y,bv.z,bv.w};
#pragma unroll
      for (int i=0;i<4;i++)
#pragma unroll
        for (int j=0;j<4;j++) acc[i][j] += a[i]*b[j];
    }
    __syncthreads();
  }
#pragma unroll
  for (int i=0;i<4;i++){
    int gm = m0+ty*4+i; if (gm>=M) continue;
#pragma unroll
    for (int j=0;j<4;j++){
      int gn = n0+tx*4+j; if (gn>=N) continue;
      float v = acc[i][j] + bias[gn];
      v = (v>20.f)? v : log1pf(expf(v));
      Y[(size_t)gm*N+gn] = v;
    }
  }
}

// ---------------- causal depthwise conv1d + silu ----------------
__global__ void k_conv(const float* __restrict__ xz, const float* __restrict__ cw,
                       const float* __restrict__ cb, float* __restrict__ xc){
  int idx = blockIdx.x*256 + threadIdx.x;
  if (idx >= ROWS*DI) return;
  int d = idx % DI;
  int r = idx / DI;
  int b = r / NN, l = r % NN;
  float acc = cb[d];
#pragma unroll
  for (int t=0;t<4;t++){
    int ls = l-3+t;
    if (ls>=0) acc += cw[d*4+t] * xz[((size_t)(b*NN+ls))*1536 + d];
  }
  xc[(size_t)r*DI + d] = acc / (1.f + expf(-acc)); // silu
}

// ---------------- chunked scan pass 1 ----------------
__global__ __launch_bounds__(256) void k_scan1(
    const float* __restrict__ dbl, const float* __restrict__ dtb,
    const float* __restrict__ xc, const float* __restrict__ A_log,
    short* __restrict__ hpart, float* __restrict__ sdt)
{
  __shared__ float Sb[LC*64];
  int gx = blockIdx.x;                 // 32 * 192
  int bc = gx & 31, dgrp = gx >> 5;
  int b = bc >> 4, c = bc & 15;
  int wv = threadIdx.x >> 6, lane = threadIdx.x & 63;
  int d = dgrp*4 + wv;
  int t0 = c*LC;
  const float* dbr = dbl + ((size_t)(b*NN+t0))*152 + DTR;
  for (int i = threadIdx.x; i < LC*64; i += 256){
    int r = i >> 6, col = i & 63;
    Sb[i] = dbr[(size_t)r*152 + col];
  }
  __syncthreads();
  float A2 = -__expf(A_log[d*DS + lane]) * LOG2E;
  const float* dtp = dtb + ((size_t)(b*NN+t0))*DI + d;
  const float* up  = xc  + ((size_t)(b*NN+t0))*DI + d;
  float dt0v = (lane<LC) ? dtp[(size_t)lane*DI] : 0.f;
  float u0v  = (lane<LC) ? up[(size_t)lane*DI]  : 0.f;
  float du0v = dt0v * u0v;
  float h = 0.f;
  for (int tb=0; tb<LC; tb+=7){
    float e[7], f[7];
#pragma unroll
    for (int j=0;j<7;j++){
      int t = tb+j;
      float dt = rdlane(dt0v, t);
      float du = rdlane(du0v, t);
      e[j] = exp2f(dt*A2);
      f[j] = du*Sb[t*64 + lane];
    }
#pragma unroll
    for (int j=0;j<7;j++) h = h*e[j] + f[j];
  }
  int bd = b*DI + d;
  hpart[((size_t)bd*NC + c)*DS + lane] = f2bf(h);
  float s = dt0v;
#pragma unroll
  for (int o=32;o;o>>=1) s += __shfl_xor(s,o);
  if (lane==0) sdt[bd*NC + c] = s;
}

// ---------------- chunked scan pass 2 ----------------
__global__ __launch_bounds__(256) void k_scan2(
    const float* __restrict__ sdt, const float* __restrict__ A_log,
    short* __restrict__ hpart)
{
  int wid = (blockIdx.x*256 + threadIdx.x) >> 6;
  int lane = threadIdx.x & 63;
  if (wid >= BB*DI) return;
  int d = wid % DI;
  float A = -__expf(A_log[d*DS + lane]);
  short* hp = hpart + (size_t)wid*NC*DS + lane;
  const float* sp = sdt + wid*NC;
  float part[NC], pA[NC];
#pragma unroll
  for (int c=0;c<NC;c++){ part[c] = bf2f(hp[(size_t)c*DS]); pA[c] = __expf(A*sp[c]); }
  float h = 0.f;
#pragma unroll
  for (int c=0;c<NC;c++){
    hp[(size_t)c*DS] = f2bf(h);   // hin for chunk c
    h = h*pA[c] + part[c];
  }
}

// ---------------- chunked scan pass 3 ----------------
__global__ __launch_bounds__(256) void k_scan3(
    const float* __restrict__ dbl, const float* __restrict__ dtb,
    const float* __restrict__ xc, const float* __restrict__ xz,
    const float* __restrict__ A_log, const float* __restrict__ Dp,
    const short* __restrict__ hin, float* __restrict__ y)
{
  __shared__ float S[LC*128];          // interleaved {B,C}: S[t*128 + lane*2 + {0,1}]
  __shared__ float red[4][LC*17];
  int gx = blockIdx.x;
  int bc = gx & 31, dgrp = gx >> 5;
  int b = bc >> 4, c = bc & 15;
  int wv = threadIdx.x >> 6, lane = threadIdx.x & 63;
  int d = dgrp*4 + wv;
  int t0 = c*LC;
  const float* dbr = dbl + ((size_t)(b*NN+t0))*152 + DTR;
  for (int i = threadIdx.x; i < LC*128; i += 256){
    int r = i >> 7, col = i & 127;
    int ln = col & 63, which = col >> 6;
    S[r*128 + ln*2 + which] = dbr[(size_t)r*152 + col];
  }
  __syncthreads();
  float A2 = -__expf(A_log[d*DS + lane]) * LOG2E;
  float Dv = Dp[d];
  const float* dtp = dtb + ((size_t)(b*NN+t0))*DI + d;
  const float* up  = xc  + ((size_t)(b*NN+t0))*DI + d;
  const float* zp  = xz  + ((size_t)(b*NN+t0))*1536 + DI + d;
  float* yp = y + ((size_t)(b*NN+t0))*DI + d;
  float dt0v = (lane<LC) ? dtp[(size_t)lane*DI]  : 0.f;
  float u0v  = (lane<LC) ? up[(size_t)lane*DI]   : 0.f;
  float z0v  = (lane<LC) ? zp[(size_t)lane*1536] : 0.f;
  float du0v = dt0v * u0v;
  int bd = b*DI + d;
  float h = bf2f(hin[((size_t)bd*NC + c)*DS + lane]);
  float* rw = red[wv];
  int g = lane>>2;
  bool gl = (lane&3)==0;
  for (int tb=0; tb<LC; tb+=7){
    float e[7], f[7], Cv[7];
#pragma unroll
    for (int j=0;j<7;j++){
      int t = tb+j;
      float2 bcv = *(const float2*)&S[t*128 + lane*2];
      float dt = rdlane(dt0v, t);
      float du = rdlane(du0v, t);
      e[j]  = exp2f(dt*A2);
      f[j]  = du*bcv.x;
      Cv[j] = bcv.y;
    }
#pragma unroll
    for (int j=0;j<7;j++){
      h = h*e[j] + f[j];
      float p = h*Cv[j];
      p = qp_add<QP_XOR1>(p);
      p = qp_add<QP_XOR2>(p);
      if (gl) rw[(tb+j)*17 + g] = p;
    }
  }
  if (lane < LC){
    const float* rr = rw + lane*17;
    float a0 = rr[0]+rr[4]+rr[8] +rr[12];
    float a1 = rr[1]+rr[5]+rr[9] +rr[13];
    float a2 = rr[2]+rr[6]+rr[10]+rr[14];
    float a3 = rr[3]+rr[7]+rr[11]+rr[15];
    float yv = (a0+a1)+(a2+a3) + u0v*Dv;      // lane == t
    float z = z0v;
    yp[(size_t)lane*DI] = yv * (z/(1.f+__expf(-z)));
  }
}

// ---------------- merged prep: twiddles + EinFFT weights + Ybuf zero ----------------
__global__ void k_prep(short* __restrict__ Wcat, short* __restrict__ WT,
                       const float* __restrict__ cw1, const float* __restrict__ cb1,
                       const float* __restrict__ cw2, const float* __restrict__ cb2,
                       short* __restrict__ W1, short* __restrict__ W2,
                       float* __restrict__ b1, float* __restrict__ b2,
                       float4* __restrict__ Ybuf4){
  int idx = blockIdx.x*256+threadIdx.x;
  if (idx < 784*1568){
    int n = idx / 1568, f = idx % 1568;       // f fastest -> WT store coalesced
    int ff = (f<784)? f : f-784;
    int m = (int)(((long long)ff*(long long)n) % 784);
    float ang = 6.283185307179586f * (float)m / 784.f;
    float s, cval; sincosf(ang, &s, &cval);
    WT[(size_t)n*1568 + f] = f2bf((f<784)? cval : -s);
  } else if (idx < 2*784*1568){
    int r = idx - 784*1568;
    int f = r / 784, n = r % 784;             // n fastest -> Wcat store coalesced
    int ff = (f<784)? f : f-784;
    int m = (int)(((long long)ff*(long long)n) % 784);
    float ang = 6.283185307179586f * (float)m / 784.f;
    float s, cval; sincosf(ang, &s, &cval);
    Wcat[(size_t)f*784 + n] = f2bf((f<784)? cval : -s);
  }
  if (idx < 2*4*192*192){
    int l = idx / (4*192*192);
    int r = idx % (4*192*192);
    int d = r % 192; int j = (r/192) % 192; int bl = r/(192*192);
    int jj = j % 96, dd = d % 96;
    const float* cw = l ? cw2 : cw1;
    const float* w0 = cw + bl*9216;
    const float* w1 = cw + 4*9216 + bl*9216;
    float v;
    if (j < 96) v = (d < 96) ? w0[dd*96+jj] : -w1[dd*96+jj];
    else        v = (d < 96) ? w1[dd*96+jj] :  w0[dd*96+jj];
    (l ? W2 : W1)[r] = f2bf(v);
  }
  if (idx < 2*4*192){
    int l = idx / (4*192);
    int r = idx % (4*192);
    int j = r % 192; int bl = r/192;
    const float* cb = l ? cb2 : cb1;
    (l ? b2 : b1)[r] = (j<96) ? cb[bl*96 + j] : cb[384 + bl*96 + (j-96)];
  }
  if (idx < 301056) Ybuf4[idx] = make_float4(0.f,0.f,0.f,0.f);
}

// ---------------- forward length-4 DFT along nb -> tcat (bf16) ----------------
__global__ void k_cfft4(const float* __restrict__ Ybuf, short* __restrict__ tcat){
  int idx = blockIdx.x*256+threadIdx.x;
  if (idx >= BB*NN*96) return;
  int k = idx % 96; int r = idx / 96;
  int b = r / NN, f = r % NN;
  const float* fre = Ybuf + (size_t)b*602112 + (size_t)f*384;
  const float* fim = fre + 301056;
  float R0=fre[k], R1=fre[96+k], R2=fre[192+k], R3=fre[288+k];
  float I0=fim[k], I1=fim[96+k], I2=fim[192+k], I3=fim[288+k];
  short* tr = tcat + (size_t)r*768;
  tr[k]       = f2bf(R0+R1+R2+R3);  tr[96+k]    = f2bf(I0+I1+I2+I3);
  tr[192+k]   = f2bf(R0+I1-R2-I3);  tr[192+96+k]= f2bf(I0-R1-I2+R3);
  tr[384+k]   = f2bf(R0-R1+R2-R3);  tr[384+96+k]= f2bf(I0-I1+I2-I3);
  tr[576+k]   = f2bf(R0-I1-R2+I3);  tr[576+96+k]= f2bf(I0+R1-I2-R3);
}

// ---------------- inverse length-4 DFT -> YbufT[b][c][fcat] ----------------
__global__ void k_cifft4(const float* __restrict__ t2cat, float* __restrict__ YbufT){
  int idx = blockIdx.x*256+threadIdx.x;
  if (idx >= BB*NN*96) return;
  int f = idx % 784;
  int rest = idx / 784;
  int k = rest % 96;
  int b = rest / 96;
  const float* tr = t2cat + ((size_t)(b*NN+f))*768;
  float R0=tr[k],     I0=tr[96+k];
  float R1=tr[192+k], I1=tr[192+96+k];
  float R2=tr[384+k], I2=tr[384+96+k];
  float R3=tr[576+k], I3=tr[576+96+k];
  float* YT = YbufT + (size_t)b*602112;
  float gr[4], gi[4];
  gr[0]=R0+R1+R2+R3; gi[0]=I0+I1+I2+I3;
  gr[1]=R0-I1-R2+I3; gi[1]=I0+R1-I2-R3;
  gr[2]=R0-R1+R2-R3; gi[2]=I0-I1+I2-I3;
  gr[3]=R0+I1-R2-I3; gi[3]=I0-R1-I2+R3;
#pragma unroll
  for (int n=0;n<4;n++){
    int c = n*96 + k;
    YT[(size_t)c*1568 + f]       = gr[n];
    YT[(size_t)c*1568 + 784 + f] = gi[n];
  }
}

extern "C" void kernel_launch(void* const* d_in, const int* in_sizes, int n_in,
                              void* d_out, int out_size, void* d_ws, size_t ws_size,
                              hipStream_t stream){
  const float* x         = (const float*)d_in[0];
  const float* ln1_w     = (const float*)d_in[3];
  const float* ln1_b     = (const float*)d_in[4];
  const float* in_proj_w = (const float*)d_in[5];
  const float* conv_w    = (const float*)d_in[6];
  const float* conv_b    = (const float*)d_in[7];
  const float* x_proj_w  = (const float*)d_in[8];
  const float* dt_proj_w = (const float*)d_in[9];
  const float* dt_proj_b = (const float*)d_in[10];
  const float* A_log     = (const float*)d_in[11];
  const float* Dp        = (const float*)d_in[12];
  const float* out_proj_w= (const float*)d_in[13];
  const float* ln2_w     = (const float*)d_in[14];
  const float* ln2_b     = (const float*)d_in[15];
  const float* cw1       = (const float*)d_in[16];
  const float* cb1       = (const float*)d_in[17];
  const float* cw2       = (const float*)d_in[18];
  const float* cb2       = (const float*)d_in[19];

  float* ws = (float*)d_ws;
  // ---- phase A (mamba) ----
  short* lnb  = (short*)ws;          // bf16 ln1 out: 602112 shorts = floats [0, 301056)
  float* xz   = ws + 602112;         // [602112, 3010560)
  float* xc   = ws + 3010560;        // [3010560, 4214784)
  float* dbl  = ws + 4214784;        // [4214784, 4453120)
  float* dtb  = ws + 4453120;        // [4453120, 5657344)
  float* yb   = ws + 5657344;        // [5657344, 6861568)
  float* x1   = ws + 6861568;        // [6861568, 7463680)  persists to end
  short* hpart= (short*)(ws + 7463680); // bf16: floats [7463680, 8250112)
  float* sdt  = ws + 8250112;        // [8250112, 8274688)
  // ---- phase B (einfft), overlaid on regions dead by launch order ----
  short* Wcat = (short*)(ws + 602112);   // floats [602112, 1216768)
  short* lnT  = (short*)(ws + 1831424);  // 602112 shorts -> floats [1831424, 2132480)
  float* Ybuf = ws + 2433536;            // [2433536, 3637760)
  short* WT   = (short*)(ws + 4453120);  // floats [4453120, 5067776) over dead dtb
  short* tcat = (short*)(ws + 602112);   // 1204224 shorts -> floats [602112, 1204224) over dead Wcat
  float* o1cat= ws + 1806336;            // [1806336, 3010560)
  float* t2cat= ws + 3010560;            // [3010560, 4214784)
  float* YbufT= ws + 602112;             // [602112, 1806336)  over dead tcat
  short* W1c  = (short*)(ws + 7463680);  // floats [7463680, 7537408) over dead hpart
  short* W2c  = (short*)(ws + 7537408);  // floats [7537408, 7611136)
  float* b1c  = ws + 7611136;            // [7611136, 7611904)
  float* b2c  = ws + 7611904;            // [7611904, 7612672)

  // ---- mamba path ----
  k_ln<<<ROWS,64,0,stream>>>(x, ln1_w, ln1_b, lnb, ROWS);
  k_mgemm<0,1,0,1><<<dim3(24,25,1),256,0,stream>>>(lnb,384,0, in_proj_w,384,0, nullptr,0,0,
                                                   xz,1536,0, ROWS,1536,384, 1.f);
  k_conv<<<(ROWS*DI+255)/256,256,0,stream>>>(xz,conv_w,conv_b,xc);
  k_zero4<<<(238336/4+255)/256,256,0,stream>>>((float4*)dbl, 238336/4);
  k_mgemm<4,0,0,8><<<dim3(3,25,8),256,0,stream>>>(xc,768,0, x_proj_w,768,0, nullptr,0,0,
                                                  dbl,152,0, ROWS,152,768, 1.f);
  k_gemm<<<dim3(12,25),256,0,stream>>>(dbl,152,dt_proj_w,dt_proj_b,dtb,ROWS,768,24);
  k_scan1<<<32*192,256,0,stream>>>(dbl,dtb,xc,A_log,hpart,sdt);
  k_scan2<<<(BB*DI)/4,256,0,stream>>>(sdt,A_log,hpart);
  k_scan3<<<32*192,256,0,stream>>>(dbl,dtb,xc,xz,A_log,Dp,hpart,yb);
  hipMemcpyAsync(x1, x, (size_t)602112*4, hipMemcpyDeviceToDevice, stream);
  k_mgemm<4,0,0,4><<<dim3(6,25,4),256,0,stream>>>(yb,768,0, out_proj_w,768,0, nullptr,0,0,
                                                  x1,384,0, ROWS,384,768, 1.f);

  // ---- einfft path (prep after mamba: overlaid regions now dead) ----
  k_prep<<<(2*784*1568+255)/256,256,0,stream>>>(Wcat,WT,cw1,cb1,cw2,cb2,W1c,W2c,b1c,b2c,(float4*)Ybuf);
  k_lnT<<<ROWS,64,0,stream>>>(x1, ln2_w, ln2_b, lnT);
  // forward DFT-784: split-K 4, atomic into zeroed Ybuf (A=Wcat bf16, B=lnT bf16)
  k_mgemm<4,1,1,4><<<dim3(6,25,8),256,0,stream>>>(Wcat,784,0, lnT,784,301056, nullptr,0,0,
                                                  Ybuf,384,602112, 1568,384,784, 1.f/56.f);
  // forward DFT-4 along nb -> tcat (bf16)
  k_cfft4<<<(BB*NN*96+255)/256,256,0,stream>>>(Ybuf,tcat);
  // EinFFT layer 1 (relu), A=tcat bf16
  k_mgemm<2,1,1,1><<<dim3(3,25,4),256,0,stream>>>(tcat,768,192, W1c,192,36864, b1c,0,192,
                                                  o1cat,768,192, ROWS,192,192, 1.f);
  // EinFFT layer 2 (soft shrink)
  k_mgemm<3,0,1,1><<<dim3(3,25,4),256,0,stream>>>(o1cat,768,192, W2c,192,36864, b2c,0,192,
                                                  t2cat,768,192, ROWS,192,192, 1.f);
  // inverse DFT-4 -> YbufT[b][c][fcat]
  k_cifft4<<<(BB*NN*96+255)/256,256,0,stream>>>(t2cat,YbufT);
  hipMemcpyAsync(d_out, x1, (size_t)602112*4, hipMemcpyDeviceToDevice, stream);
  // inverse DFT-784: split-K 7, atomic into d_out (A=WT bf16)
  k_mgemm<4,1,0,7><<<dim3(6,13,14),256,0,stream>>>(WT,1568,0, YbufT,1568,602112, nullptr,0,0,
                                                   (float*)d_out,384,301056, 784,384,1568, 1.f/56.f);
}

// Round 13
// 236.078 us; speedup vs baseline: 7.2128x; 1.0566x over previous
//
#include <hip/hip_runtime.h>
#include <math.h>

#define BB 2
#define NN 784
#define CC 384
#define DI 768
#define DS 64
#define DTR 24
#define ROWS (BB*NN)   // 1568
#define NC 16
#define LC 49          // NC*LC == NN

typedef __attribute__((ext_vector_type(8))) short bf16x8;
typedef __attribute__((ext_vector_type(4))) float f32x4;

static __device__ inline short f2bf(float f){
  unsigned u = __float_as_uint(f);
  unsigned r = (u + 0x7fffu + ((u>>16)&1u)) >> 16;
  return (short)r;
}
static __device__ inline float bf2f(short v){
  return __uint_as_float(((unsigned)(unsigned short)v)<<16);
}
static __device__ inline float rdlane(float v, int t){
  return __uint_as_float(__builtin_amdgcn_readlane(__float_as_uint(v), t));
}
template<int CTRL>
static __device__ inline float qp_add(float x){
  int t = __builtin_amdgcn_update_dpp(0, __float_as_int(x), CTRL, 0xf, 0xf, false);
  return x + __int_as_float(t);
}
#define QP_XOR1 0xB1   // quad_perm [1,0,3,2]
#define QP_XOR2 0x4E   // quad_perm [2,3,0,1]

// ---------------- 784-entry sincos table ----------------
__global__ void k_tab(float* __restrict__ ct, float* __restrict__ st){
  int i = blockIdx.x*256 + threadIdx.x;
  if (i < 784){
    float ang = 6.283185307179586f * (float)i / 784.f;
    float s, c; sincosf(ang, &s, &c);
    ct[i] = c; st[i] = s;
  }
}

// ---------------- LayerNorm (bf16 out): one wave per row of 384 ----------------
__global__ void k_ln(const float* __restrict__ x, const float* __restrict__ w,
                     const float* __restrict__ b, short* __restrict__ out, int rows){
  int row = blockIdx.x;
  if (row >= rows) return;
  int lane = threadIdx.x; // blockDim = 64
  const float* xr = x + (size_t)row*CC;
  float v[6]; float s = 0.f;
#pragma unroll
  for (int i=0;i<6;i++){ v[i] = xr[lane + 64*i]; s += v[i]; }
#pragma unroll
  for (int o=32;o;o>>=1) s += __shfl_xor(s,o);
  float mu = s * (1.f/CC);
  float vs = 0.f;
#pragma unroll
  for (int i=0;i<6;i++){ float d=v[i]-mu; vs += d*d; }
#pragma unroll
  for (int o=32;o;o>>=1) vs += __shfl_xor(vs,o);
  float rstd = rsqrtf(vs*(1.f/CC) + 1e-5f);
  short* orow = out + (size_t)row*CC;
#pragma unroll
  for (int i=0;i<6;i++){ int c = lane+64*i; orow[c] = f2bf((v[i]-mu)*rstd*w[c] + b[c]); }
}

// ---------------- LayerNorm transposed bf16 out: lnT[b][c][n] ----------------
__global__ void k_lnT(const float* __restrict__ x, const float* __restrict__ w,
                      const float* __restrict__ b, short* __restrict__ out){
  int row = blockIdx.x;      // b*784 + n
  if (row >= ROWS) return;
  int bb = row / NN, n = row % NN;
  int lane = threadIdx.x;
  const float* xr = x + (size_t)row*CC;
  float v[6]; float s = 0.f;
#pragma unroll
  for (int i=0;i<6;i++){ v[i] = xr[lane + 64*i]; s += v[i]; }
#pragma unroll
  for (int o=32;o;o>>=1) s += __shfl_xor(s,o);
  float mu = s * (1.f/CC);
  float vs = 0.f;
#pragma unroll
  for (int i=0;i<6;i++){ float d=v[i]-mu; vs += d*d; }
#pragma unroll
  for (int o=32;o;o>>=1) vs += __shfl_xor(vs,o);
  float rstd = rsqrtf(vs*(1.f/CC) + 1e-5f);
  short* ob = out + (size_t)bb*301056 + n;
#pragma unroll
  for (int i=0;i<6;i++){ int c = lane+64*i; ob[(size_t)c*NN] = f2bf((v[i]-mu)*rstd*w[c] + b[c]); }
}

// ---------------- bf16 MFMA GEMM, register double-buffered ----------------
// EPI 0: alpha*acc ; 1: alpha*acc + aux[row*ldaux+col] ; 2: relu(acc+aux[col]) ;
// 3: shrink(acc+aux[col],0.01) ; 4: atomicAdd(Y, alpha*acc) ; 5: softplus(acc+aux[col])
template<int EPI, int ABF, int BBF, int SPLITK>
__global__ __launch_bounds__(256) void k_mgemm(
    const void* __restrict__ Ap, int lda, long long Azs,
    const void* __restrict__ Bp, int ldb, long long Bzs,
    const float* __restrict__ aux, int ldaux, long long auxzs,
    float* __restrict__ Y, int ldo, long long Ozs,
    int M, int N, int K, float alpha)
{
  __shared__ __align__(16) short As[64*32];
  __shared__ __align__(16) short Bs[64*32];
  int bz = blockIdx.z;
  int z  = bz / SPLITK, ks = bz % SPLITK;
  if (EPI == 1 || EPI == 2 || EPI == 3 || EPI == 5) aux += (size_t)z*auxzs;
  Y += (size_t)z*Ozs;
  int nk = (K + 31) >> 5;
  int per = (nk + SPLITK - 1) / SPLITK;
  int kbeg = ks*per*32;
  int kend = kbeg + per*32; if (kend > K) kend = K;
  if (kend <= kbeg) return;
  int ntile = (kend - kbeg + 31) >> 5;
  int m0 = blockIdx.y*64, n0 = blockIdx.x*64;
  int t = threadIdx.x;
  int srow = t>>2, skg = t&3;
  int w = t>>6, lane = t&63;
  int wr = (w>>1)*32, wc = (w&1)*32;
  int l15 = lane&15, lh = lane>>4;
  f32x4 acc[2][2] = {};
  int sslot = skg ^ ((srow>>1)&3);
  int gmA = m0 + srow, gnB = n0 + srow;
  int gko = skg*8;

  bf16x8 vA = {}, vB = {};
  float4 fA0, fA1, fB0, fB1;

  auto LOAD = [&](int k0){
    int gk = k0 + gko;
    if (ABF){
      bf16x8 v = {};
      if (gmA < M && gk < K) v = *(const bf16x8*)((const short*)Ap + (size_t)z*Azs + (size_t)gmA*lda + gk);
      vA = v;
    } else {
      fA0 = make_float4(0.f,0.f,0.f,0.f); fA1 = fA0;
      if (gmA < M && gk < K){
        const float* p = (const float*)Ap + (size_t)z*Azs + (size_t)gmA*lda + gk;
        fA0 = *(const float4*)p; fA1 = *(const float4*)(p+4);
      }
    }
    if (BBF){
      bf16x8 v = {};
      if (gnB < N && gk < K) v = *(const bf16x8*)((const short*)Bp + (size_t)z*Bzs + (size_t)gnB*ldb + gk);
      vB = v;
    } else {
      fB0 = make_float4(0.f,0.f,0.f,0.f); fB1 = fB0;
      if (gnB < N && gk < K){
        const float* p = (const float*)Bp + (size_t)z*Bzs + (size_t)gnB*ldb + gk;
        fB0 = *(const float4*)p; fB1 = *(const float4*)(p+4);
      }
    }
  };
  auto STORE = [&](){
    if (ABF) *(bf16x8*)(As + srow*32 + sslot*8) = vA;
    else {
      union { short s[8]; bf16x8 v; } pk;
      pk.s[0]=f2bf(fA0.x); pk.s[1]=f2bf(fA0.y); pk.s[2]=f2bf(fA0.z); pk.s[3]=f2bf(fA0.w);
      pk.s[4]=f2bf(fA1.x); pk.s[5]=f2bf(fA1.y); pk.s[6]=f2bf(fA1.z); pk.s[7]=f2bf(fA1.w);
      *(bf16x8*)(As + srow*32 + sslot*8) = pk.v;
    }
    if (BBF) *(bf16x8*)(Bs + srow*32 + sslot*8) = vB;
    else {
      union { short s[8]; bf16x8 v; } pk;
      pk.s[0]=f2bf(fB0.x); pk.s[1]=f2bf(fB0.y); pk.s[2]=f2bf(fB0.z); pk.s[3]=f2bf(fB0.w);
      pk.s[4]=f2bf(fB1.x); pk.s[5]=f2bf(fB1.y); pk.s[6]=f2bf(fB1.z); pk.s[7]=f2bf(fB1.w);
      *(bf16x8*)(Bs + srow*32 + sslot*8) = pk.v;
    }
  };

  LOAD(kbeg);
  for (int ti=0; ti<ntile; ++ti){
    STORE();
    __syncthreads();
    if (ti+1 < ntile) LOAD(kbeg + (ti+1)*32);   // in-flight during MFMA
    bf16x8 af[2], bfr[2];
#pragma unroll
    for (int mi=0; mi<2; mi++){
      int row = wr + mi*16 + l15;
      af[mi] = *(const bf16x8*)(As + row*32 + ((lh ^ ((row>>1)&3))<<3));
    }
#pragma unroll
    for (int ni=0; ni<2; ni++){
      int col = wc + ni*16 + l15;
      bfr[ni] = *(const bf16x8*)(Bs + col*32 + ((lh ^ ((col>>1)&3))<<3));
    }
#pragma unroll
    for (int mi=0; mi<2; mi++)
#pragma unroll
      for (int ni=0; ni<2; ni++)
        acc[mi][ni] = __builtin_amdgcn_mfma_f32_16x16x32_bf16(af[mi], bfr[ni], acc[mi][ni], 0, 0, 0);
    __syncthreads();
  }
  // ---- epilogue ----
#pragma unroll
  for (int mi=0; mi<2; mi++){
#pragma unroll
    for (int ni=0; ni<2; ni++){
      int col = n0 + wc + ni*16 + l15;
      if (col >= N) continue;
#pragma unroll
      for (int j=0; j<4; j++){
        int row = m0 + wr + mi*16 + lh*4 + j;
        if (row >= M) continue;
        float v = acc[mi][ni][j];
        if (EPI == 0){ Y[(size_t)row*ldo + col] = v*alpha; }
        else if (EPI == 1){ Y[(size_t)row*ldo + col] = v*alpha + aux[(size_t)row*ldaux + col]; }
        else if (EPI == 2){ v += aux[col]; Y[(size_t)row*ldo + col] = fmaxf(v, 0.f); }
        else if (EPI == 3){ v += aux[col]; Y[(size_t)row*ldo + col] = copysignf(fmaxf(fabsf(v)-0.01f, 0.f), v); }
        else if (EPI == 5){ v += aux[col]; Y[(size_t)row*ldo + col] = (v>20.f)? v : log1pf(expf(v)); }
        else { atomicAdd(&Y[(size_t)row*ldo + col], v*alpha); }
      }
    }
  }
}

// ---------------- causal depthwise conv1d + silu (+ dbl zero-fill) ----------------
__global__ void k_conv(const float* __restrict__ xz, const float* __restrict__ cw,
                       const float* __restrict__ cb, float* __restrict__ xc,
                       float4* __restrict__ dbl4){
  int idx = blockIdx.x*256 + threadIdx.x;
  if (idx < 238336/4) dbl4[idx] = make_float4(0.f,0.f,0.f,0.f);
  if (idx >= ROWS*DI) return;
  int d = idx % DI;
  int r = idx / DI;
  int b = r / NN, l = r % NN;
  float acc = cb[d];
#pragma unroll
  for (int t=0;t<4;t++){
    int ls = l-3+t;
    if (ls>=0) acc += cw[d*4+t] * xz[((size_t)(b*NN+ls))*1536 + d];
  }
  xc[(size_t)r*DI + d] = acc / (1.f + expf(-acc)); // silu
}

// ---------------- chunked scan pass 1 (round-11 proven body) ----------------
__global__ __launch_bounds__(256) void k_scan1(
    const float* __restrict__ dbl, const float* __restrict__ dtb,
    const float* __restrict__ xc, const float* __restrict__ A_log,
    short* __restrict__ hpart, float* __restrict__ sdt)
{
  __shared__ float Sb[LC*64];
  int gx = blockIdx.x;                 // 32 * 192
  int bc = gx & 31, dgrp = gx >> 5;
  int b = bc >> 4, c = bc & 15;
  int wv = threadIdx.x >> 6, lane = threadIdx.x & 63;
  int d = dgrp*4 + wv;
  int t0 = c*LC;
  const float* dbr = dbl + ((size_t)(b*NN+t0))*152 + DTR;
  for (int i = threadIdx.x; i < LC*64; i += 256){
    int r = i >> 6, col = i & 63;
    Sb[i] = dbr[(size_t)r*152 + col];
  }
  __syncthreads();
  float A = -__expf(A_log[d*DS + lane]);
  const float* dtp = dtb + ((size_t)(b*NN+t0))*DI + d;
  const float* up  = xc  + ((size_t)(b*NN+t0))*DI + d;
  float dt0v = (lane<LC) ? dtp[(size_t)lane*DI] : 0.f;
  float u0v  = (lane<LC) ? up[(size_t)lane*DI]  : 0.f;
  float h = 0.f;
  for (int tb=0; tb<LC; tb+=7){
    float e[7], f[7];
#pragma unroll
    for (int j=0;j<7;j++){
      int t = tb+j;
      float dt = rdlane(dt0v, t);
      float u  = rdlane(u0v, t);
      e[j] = __expf(dt*A);
      f[j] = (dt*u)*Sb[t*64 + lane];
    }
#pragma unroll
    for (int j=0;j<7;j++) h = h*e[j] + f[j];
  }
  int bd = b*DI + d;
  hpart[((size_t)bd*NC + c)*DS + lane] = f2bf(h);
  float s = dt0v;
#pragma unroll
  for (int o=32;o;o>>=1) s += __shfl_xor(s,o);
  if (lane==0) sdt[bd*NC + c] = s;
}

// ---------------- chunked scan pass 2 ----------------
__global__ __launch_bounds__(256) void k_scan2(
    const float* __restrict__ sdt, const float* __restrict__ A_log,
    short* __restrict__ hpart)
{
  int wid = (blockIdx.x*256 + threadIdx.x) >> 6;
  int lane = threadIdx.x & 63;
  if (wid >= BB*DI) return;
  int d = wid % DI;
  float A = -__expf(A_log[d*DS + lane]);
  short* hp = hpart + (size_t)wid*NC*DS + lane;
  const float* sp = sdt + wid*NC;
  float part[NC], pA[NC];
#pragma unroll
  for (int c=0;c<NC;c++){ part[c] = bf2f(hp[(size_t)c*DS]); pA[c] = __expf(A*sp[c]); }
  float h = 0.f;
#pragma unroll
  for (int c=0;c<NC;c++){
    hp[(size_t)c*DS] = f2bf(h);   // hin for chunk c
    h = h*pA[c] + part[c];
  }
}

// ---------------- chunked scan pass 3 (round-11 proven body) ----------------
__global__ __launch_bounds__(256) void k_scan3(
    const float* __restrict__ dbl, const float* __restrict__ dtb,
    const float* __restrict__ xc, const float* __restrict__ xz,
    const float* __restrict__ A_log, const float* __restrict__ Dp,
    const short* __restrict__ hin, float* __restrict__ y)
{
  __shared__ float S[LC*128];          // interleaved {B,C}: S[t*128 + lane*2 + {0,1}]
  __shared__ float red[4][LC*17];
  int gx = blockIdx.x;
  int bc = gx & 31, dgrp = gx >> 5;
  int b = bc >> 4, c = bc & 15;
  int wv = threadIdx.x >> 6, lane = threadIdx.x & 63;
  int d = dgrp*4 + wv;
  int t0 = c*LC;
  const float* dbr = dbl + ((size_t)(b*NN+t0))*152 + DTR;
  for (int i = threadIdx.x; i < LC*128; i += 256){
    int r = i >> 7, col = i & 127;
    int ln = col & 63, which = col >> 6;
    S[r*128 + ln*2 + which] = dbr[(size_t)r*152 + col];
  }
  __syncthreads();
  float A = -__expf(A_log[d*DS + lane]);
  float Dv = Dp[d];
  const float* dtp = dtb + ((size_t)(b*NN+t0))*DI + d;
  const float* up  = xc  + ((size_t)(b*NN+t0))*DI + d;
  const float* zp  = xz  + ((size_t)(b*NN+t0))*1536 + DI + d;
  float* yp = y + ((size_t)(b*NN+t0))*DI + d;
  float dt0v = (lane<LC) ? dtp[(size_t)lane*DI]  : 0.f;
  float u0v  = (lane<LC) ? up[(size_t)lane*DI]   : 0.f;
  float z0v  = (lane<LC) ? zp[(size_t)lane*1536] : 0.f;
  int bd = b*DI + d;
  float h = bf2f(hin[((size_t)bd*NC + c)*DS + lane]);
  float* rw = red[wv];
  int g = lane>>2;
  bool gl = (lane&3)==0;
  for (int tb=0; tb<LC; tb+=7){
    float e[7], f[7], Cv[7];
#pragma unroll
    for (int j=0;j<7;j++){
      int t = tb+j;
      float2 bcv = *(const float2*)&S[t*128 + lane*2];
      float dt = rdlane(dt0v, t);
      float u  = rdlane(u0v, t);
      e[j]  = __expf(dt*A);
      f[j]  = (dt*u)*bcv.x;
      Cv[j] = bcv.y;
    }
#pragma unroll
    for (int j=0;j<7;j++){
      h = h*e[j] + f[j];
      float p = h*Cv[j];
      p = qp_add<QP_XOR1>(p);
      p = qp_add<QP_XOR2>(p);
      if (gl) rw[(tb+j)*17 + g] = p;
    }
  }
  if (lane < LC){
    const float* rr = rw + lane*17;
    float a0 = rr[0]+rr[4]+rr[8] +rr[12];
    float a1 = rr[1]+rr[5]+rr[9] +rr[13];
    float a2 = rr[2]+rr[6]+rr[10]+rr[14];
    float a3 = rr[3]+rr[7]+rr[11]+rr[15];
    float yv = (a0+a1)+(a2+a3) + u0v*Dv;      // lane == t
    float z = z0v;
    yp[(size_t)lane*DI] = yv * (z/(1.f+__expf(-z)));
  }
}

// ---------------- merged prep: twiddles (LUT gather) + EinFFT weights + Ybuf zero ----------------
__global__ void k_prep(short* __restrict__ Wcat, short* __restrict__ WT,
                       const float* __restrict__ ct, const float* __restrict__ st,
                       const float* __restrict__ cw1, const float* __restrict__ cb1,
                       const float* __restrict__ cw2, const float* __restrict__ cb2,
                       short* __restrict__ W1, short* __restrict__ W2,
                       float* __restrict__ b1, float* __restrict__ b2,
                       float4* __restrict__ Ybuf4){
  int idx = blockIdx.x*256+threadIdx.x;
  if (idx < 784*1568){
    int n = idx / 1568, f = idx % 1568;       // f fastest -> WT store coalesced
    int ff = (f<784)? f : f-784;
    int m = (ff*n) % 784;
    WT[(size_t)n*1568 + f] = f2bf((f<784)? ct[m] : -st[m]);
  } else if (idx < 2*784*1568){
    int r = idx - 784*1568;
    int f = r / 784, n = r % 784;             // n fastest -> Wcat store coalesced
    int ff = (f<784)? f : f-784;
    int m = (ff*n) % 784;
    Wcat[(size_t)f*784 + n] = f2bf((f<784)? ct[m] : -st[m]);
  }
  if (idx < 2*4*192*192){
    int l = idx / (4*192*192);
    int r = idx % (4*192*192);
    int d = r % 192; int j = (r/192) % 192; int bl = r/(192*192);
    int jj = j % 96, dd = d % 96;
    const float* cw = l ? cw2 : cw1;
    const float* w0 = cw + bl*9216;
    const float* w1 = cw + 4*9216 + bl*9216;
    float v;
    if (j < 96) v = (d < 96) ? w0[dd*96+jj] : -w1[dd*96+jj];
    else        v = (d < 96) ? w1[dd*96+jj] :  w0[dd*96+jj];
    (l ? W2 : W1)[r] = f2bf(v);
  }
  if (idx < 2*4*192){
    int l = idx / (4*192);
    int r = idx % (4*192);
    int j = r % 192; int bl = r/192;
    const float* cb = l ? cb2 : cb1;
    (l ? b2 : b1)[r] = (j<96) ? cb[bl*96 + j] : cb[384 + bl*96 + (j-96)];
  }
  if (idx < 301056) Ybuf4[idx] = make_float4(0.f,0.f,0.f,0.f);
}

// ---------------- forward length-4 DFT along nb -> tcat (bf16) ----------------
__global__ void k_cfft4(const float* __restrict__ Ybuf, short* __restrict__ tcat){
  int idx = blockIdx.x*256+threadIdx.x;
  if (idx >= BB*NN*96) return;
  int k = idx % 96; int r = idx / 96;
  int b = r / NN, f = r % NN;
  const float* fre = Ybuf + (size_t)b*602112 + (size_t)f*384;
  const float* fim = fre + 301056;
  float R0=fre[k], R1=fre[96+k], R2=fre[192+k], R3=fre[288+k];
  float I0=fim[k], I1=fim[96+k], I2=fim[192+k], I3=fim[288+k];
  short* tr = tcat + (size_t)r*768;
  tr[k]       = f2bf(R0+R1+R2+R3);  tr[96+k]    = f2bf(I0+I1+I2+I3);
  tr[192+k]   = f2bf(R0+I1-R2-I3);  tr[192+96+k]= f2bf(I0-R1-I2+R3);
  tr[384+k]   = f2bf(R0-R1+R2-R3);  tr[384+96+k]= f2bf(I0-I1+I2-I3);
  tr[576+k]   = f2bf(R0-I1-R2+I3);  tr[576+96+k]= f2bf(I0+R1-I2-R3);
}

// ---------------- inverse length-4 DFT -> YbufT[b][c][fcat] ----------------
__global__ void k_cifft4(const float* __restrict__ t2cat, float* __restrict__ YbufT){
  int idx = blockIdx.x*256+threadIdx.x;
  if (idx >= BB*NN*96) return;
  int f = idx % 784;
  int rest = idx / 784;
  int k = rest % 96;
  int b = rest / 96;
  const float* tr = t2cat + ((size_t)(b*NN+f))*768;
  float R0=tr[k],     I0=tr[96+k];
  float R1=tr[192+k], I1=tr[192+96+k];
  float R2=tr[384+k], I2=tr[384+96+k];
  float R3=tr[576+k], I3=tr[576+96+k];
  float* YT = YbufT + (size_t)b*602112;
  float gr[4], gi[4];
  gr[0]=R0+R1+R2+R3; gi[0]=I0+I1+I2+I3;
  gr[1]=R0-I1-R2+I3; gi[1]=I0+R1-I2-R3;
  gr[2]=R0-R1+R2-R3; gi[2]=I0-I1+I2-I3;
  gr[3]=R0+I1-R2-I3; gi[3]=I0-R1-I2+R3;
#pragma unroll
  for (int n=0;n<4;n++){
    int c = n*96 + k;
    YT[(size_t)c*1568 + f]       = gr[n];
    YT[(size_t)c*1568 + 784 + f] = gi[n];
  }
}

extern "C" void kernel_launch(void* const* d_in, const int* in_sizes, int n_in,
                              void* d_out, int out_size, void* d_ws, size_t ws_size,
                              hipStream_t stream){
  const float* x         = (const float*)d_in[0];
  const float* ln1_w     = (const float*)d_in[3];
  const float* ln1_b     = (const float*)d_in[4];
  const float* in_proj_w = (const float*)d_in[5];
  const float* conv_w    = (const float*)d_in[6];
  const float* conv_b    = (const float*)d_in[7];
  const float* x_proj_w  = (const float*)d_in[8];
  const float* dt_proj_w = (const float*)d_in[9];
  const float* dt_proj_b = (const float*)d_in[10];
  const float* A_log     = (const float*)d_in[11];
  const float* Dp        = (const float*)d_in[12];
  const float* out_proj_w= (const float*)d_in[13];
  const float* ln2_w     = (const float*)d_in[14];
  const float* ln2_b     = (const float*)d_in[15];
  const float* cw1       = (const float*)d_in[16];
  const float* cb1       = (const float*)d_in[17];
  const float* cw2       = (const float*)d_in[18];
  const float* cb2       = (const float*)d_in[19];

  float* ws = (float*)d_ws;
  // ---- phase A (mamba) ----
  short* lnb  = (short*)ws;          // bf16 ln1 out: floats [0, 301056)
  float* xz   = ws + 602112;         // [602112, 3010560)
  float* xc   = ws + 3010560;        // [3010560, 4214784)
  float* dbl  = ws + 4214784;        // [4214784, 4453120)
  float* dtb  = ws + 4453120;        // [4453120, 5657344)
  float* yb   = ws + 5657344;        // [5657344, 6861568)
  float* x1   = ws + 6861568;        // [6861568, 7463680)  persists to end
  short* hpart= (short*)(ws + 7463680); // bf16: floats [7463680, 8250112)
  float* sdt  = ws + 8250112;        // [8250112, 8274688)
  float* ctab = ws + 8274688;        // [8274688, 8275472)
  float* stab = ws + 8275472;        // [8275472, 8276256)
  // ---- phase B (einfft), overlaid on regions dead by launch order ----
  short* Wcat = (short*)(ws + 602112);   // floats [602112, 1216768)
  short* lnT  = (short*)(ws + 1831424);  // floats [1831424, 2132480)
  float* Ybuf = ws + 2433536;            // [2433536, 3637760)
  short* WT   = (short*)(ws + 4453120);  // floats [4453120, 5067776) over dead dtb
  short* tcat = (short*)(ws + 602112);   // floats [602112, 1204224) over dead Wcat
  float* o1cat= ws + 1806336;            // [1806336, 3010560)
  float* t2cat= ws + 3010560;            // [3010560, 4214784)
  float* YbufT= ws + 602112;             // [602112, 1806336)  over dead tcat
  short* W1c  = (short*)(ws + 7463680);  // floats [7463680, 7537408) over dead hpart
  short* W2c  = (short*)(ws + 7537408);  // floats [7537408, 7611136)
  float* b1c  = ws + 7611136;            // [7611136, 7611904)
  float* b2c  = ws + 7611904;            // [7611904, 7612672)

  // ---- independent tiny prep ----
  k_tab<<<4,256,0,stream>>>(ctab, stab);
  hipMemcpyAsync(x1, x, (size_t)602112*4, hipMemcpyDeviceToDevice, stream);

  // ---- mamba path ----
  k_ln<<<ROWS,64,0,stream>>>(x, ln1_w, ln1_b, lnb, ROWS);
  k_mgemm<0,1,0,1><<<dim3(24,25,1),256,0,stream>>>(lnb,384,0, in_proj_w,384,0, nullptr,0,0,
                                                   xz,1536,0, ROWS,1536,384, 1.f);
  k_conv<<<(ROWS*DI+255)/256,256,0,stream>>>(xz,conv_w,conv_b,xc,(float4*)dbl);
  k_mgemm<4,0,0,8><<<dim3(3,25,8),256,0,stream>>>(xc,768,0, x_proj_w,768,0, nullptr,0,0,
                                                  dbl,152,0, ROWS,152,768, 1.f);
  // dt_proj: MFMA, single zero-padded k-tile (K=24), softplus+bias epilogue
  k_mgemm<5,0,0,1><<<dim3(12,25,1),256,0,stream>>>(dbl,152,0, dt_proj_w,24,0, dt_proj_b,0,0,
                                                   dtb,768,0, ROWS,768,24, 1.f);
  k_scan1<<<32*192,256,0,stream>>>(dbl,dtb,xc,A_log,hpart,sdt);
  k_scan2<<<(BB*DI)/4,256,0,stream>>>(sdt,A_log,hpart);
  k_scan3<<<32*192,256,0,stream>>>(dbl,dtb,xc,xz,A_log,Dp,hpart,yb);
  k_mgemm<4,0,0,4><<<dim3(6,25,4),256,0,stream>>>(yb,768,0, out_proj_w,768,0, nullptr,0,0,
                                                  x1,384,0, ROWS,384,768, 1.f);

  // ---- einfft path (prep after mamba: overlaid regions now dead) ----
  k_prep<<<(2*784*1568+255)/256,256,0,stream>>>(Wcat,WT,ctab,stab,cw1,cb1,cw2,cb2,W1c,W2c,b1c,b2c,(float4*)Ybuf);
  k_lnT<<<ROWS,64,0,stream>>>(x1, ln2_w, ln2_b, lnT);
  // forward DFT-784: split-K 4, atomic into zeroed Ybuf (A=Wcat bf16, B=lnT bf16)
  k_mgemm<4,1,1,4><<<dim3(6,25,8),256,0,stream>>>(Wcat,784,0, lnT,784,301056, nullptr,0,0,
                                                  Ybuf,384,602112, 1568,384,784, 1.f/56.f);
  // forward DFT-4 along nb -> tcat (bf16)
  k_cfft4<<<(BB*NN*96+255)/256,256,0,stream>>>(Ybuf,tcat);
  // EinFFT layer 1 (relu), A=tcat bf16
  k_mgemm<2,1,1,1><<<dim3(3,25,4),256,0,stream>>>(tcat,768,192, W1c,192,36864, b1c,0,192,
                                                  o1cat,768,192, ROWS,192,192, 1.f);
  // EinFFT layer 2 (soft shrink)
  k_mgemm<3,0,1,1><<<dim3(3,25,4),256,0,stream>>>(o1cat,768,192, W2c,192,36864, b2c,0,192,
                                                  t2cat,768,192, ROWS,192,192, 1.f);
  // inverse DFT-4 -> YbufT[b][c][fcat]
  k_cifft4<<<(BB*NN*96+255)/256,256,0,stream>>>(t2cat,YbufT);
  hipMemcpyAsync(d_out, x1, (size_t)602112*4, hipMemcpyDeviceToDevice, stream);
  // inverse DFT-784: split-K 7, atomic into d_out (A=WT bf16)
  k_mgemm<4,1,0,7><<<dim3(6,13,14),256,0,stream>>>(WT,1568,0, YbufT,1568,602112, nullptr,0,0,
                                                   (float*)d_out,384,301056, 784,384,1568, 1.f/56.f);
}